// Round 12
// baseline (117.526 us; speedup 1.0000x reference)
//
#include <hip/hip_runtime.h>
#include <math.h>

#define B_ 2
#define C_ 32
#define D_ 32
#define H_ 32
#define W_ 64
#define HW_ (H_*W_)         // 2048
#define DHW_ (D_*H_*W_)     // 65536
#define CDHW_ (C_*DHW_)     // 2097152
#define NSP_ DHW_           // spatial points per batch
#define BN_N_ (B_*DHW_)     // 131072
#define BORDER 1e-3
#define RS 516              // padded LDS ring stride (floats)

// ws layout: Mw @0 (16MB), Mh @16MB, Md @32MB, reduction @48MB:
// npart[512] double2 @ +256, spart[32][2048] float2 @ +256+16384. All written before read.
#define MH_OFF  (16u<<20)
#define MD_OFF  (32u<<20)
#define RED_OFF (48u<<20)

// ---------------- threshold stats: involution-halved (only d<16; norm[p]==norm[pf] exactly) ----------------
__global__ __launch_bounds__(256) void k_norm(const float* __restrict__ x, double2* __restrict__ npart) {
    int tid = blockIdx.x * 256 + threadIdx.x;       // 131072 threads
    int ln = threadIdx.x & 63;
    int half = ln >> 5, lp = ln & 31;
    int ph = (tid >> 6) * 32 + lp;                  // 0..65535 half-space points (2x lane coverage)
    int b = ph >> 15;
    int rem = ph & 32767;                           // d<16
    int pp = rem;                                   // (d<<11)|(h<<6)|w with d in 0..15
    int d = pp >> 11, h = (pp >> 6) & 31, w = pp & 63;
    int pf = ((d ^ 16) << 11) | ((h ^ 16) << 6) | (w ^ 32);
    const float* xb = x + (size_t)b * CDHW_ + (size_t)half * 16 * DHW_;
    double s = 0.0;
#pragma unroll
    for (int c = 0; c < 16; ++c) {
        float a  = xb[c * DHW_ + pp];
        float bb = xb[c * DHW_ + pf];
        s += fabs((double)a - (double)bb);
    }
    double st = s + __shfl_xor(s, 32, 64);          // full 32-ch sum (both halves hold it)
    double s2 = st * st;
    for (int off = 32; off; off >>= 1) {
        st += __shfl_down(st, off, 64);
        s2 += __shfl_down(s2, off, 64);
    }
    __shared__ double ls[4], ls2[4];
    int wv = threadIdx.x >> 6;
    if (ln == 0) { ls[wv] = st; ls2[wv] = s2; }
    __syncthreads();
    if (threadIdx.x == 0) {
        // 2-lane duplication == involution doubling -> no 0.5 factor
        double2 o;
        o.x = (ls[0] + ls[1]) + (ls[2] + ls[3]);
        o.y = (ls2[0] + ls2[1]) + (ls2[2] + ls2[3]);
        npart[blockIdx.x] = o;                      // blocks 0..255 -> b=0, 256..511 -> b=1
    }
}

// ---------------- per-block redundant thr reduce + f32 gate bounds ----------------
__device__ __forceinline__ void thr_reduce(const double2* __restrict__ npart, double* thrs, float* fb,
                                           double* ls, double* lq, int t) {
    {
        double s = 0.0, q = 0.0;
#pragma unroll
        for (int i = 0; i < 2; ++i) {
            double2 v = npart[t * 2 + i];
            s += v.x; q += v.y;
        }
        for (int off = 32; off; off >>= 1) {
            s += __shfl_down(s, off, 64);
            q += __shfl_down(q, off, 64);
        }
        if ((t & 63) == 0) { ls[t >> 6] = s; lq[t >> 6] = q; }
    }
    __syncthreads();
    if (t < 2) {
        double sum = ls[2 * t] + ls[2 * t + 1];
        double sq  = lq[2 * t] + lq[2 * t + 1];
        double n = (double)NSP_;
        double mean = sum / n;
        double var = (sq - sum * sum / n) / (n - 1.0);   // ddof=1
        if (var < 0.0) var = 0.0;
        double thrv = mean - sqrt(var);
        thrs[t] = thrv;
        fb[t * 4 + 0] = (float)(thrv - BORDER * 1.01);
        fb[t * 4 + 1] = (float)(thrv + BORDER * 1.01);
        fb[t * 4 + 2] = (float)thrv;
    }
    __syncthreads();
}

__device__ __forceinline__ float dist16(const float* col, const float* nb) {
    float d0 = 0.f, d1 = 0.f, d2 = 0.f, d3 = 0.f;
#pragma unroll
    for (int c = 0; c < 16; c += 4) {
        d0 += fabsf(col[c+0] - nb[c+0]);
        d1 += fabsf(col[c+1] - nb[c+1]);
        d2 += fabsf(col[c+2] - nb[c+2]);
        d3 += fabsf(col[c+3] - nb[c+3]);
    }
    return (d0 + d1) + (d2 + d3);
}

// H/D ring body. 256 threads, 8 rings (one parity). Rolled s-loops (unroll blew VGPR in r10).
template<int AS, int FS>
__device__ __forceinline__ void hd_ring(const float* __restrict__ x, float* __restrict__ M,
                                        const double* thrs, const float* fb, float* L, int local, int t) {
    int par = local & 1, wt = (local >> 1) & 7, F = (local >> 4) & 31, b = local >> 9;
    int w0 = wt * 8;
    double thr = thrs[b];
    float tlo = fb[b*4], thi = fb[b*4+1], tmf = fb[b*4+2];
    const float* xb = x + (size_t)b * CDHW_ + (size_t)F * FS + w0;
#pragma unroll
    for (int it = 0; it < 4; ++it) {
        int f = it * 256 + t;                        // 0..1023 float4s
        int c = f >> 5, rem = f & 31, j = rem >> 1, wq = rem & 1;
        float4 v = *(const float4*)(xb + (size_t)c * DHW_ + (size_t)(2 * j + par) * AS + wq * 4);
        int sl = (((c >> 2) ^ (j & 7)) << 2) + (c & 3);
        int rb = (wq * 4) * RS + j * 32 + sl;
        L[rb] = v.x; L[rb + RS] = v.y; L[rb + 2*RS] = v.z; L[rb + 3*RS] = v.w;
    }
    __syncthreads();
    int ln = t & 63, wave = t >> 6;
    int pos = ln >> 2, c2 = ln & 3;
    int wl = wave * 2 + (c2 >> 1), half = c2 & 1;
    const float* Lr = L + wl * RS;
    int qb = half * 4;
    float col[16], Mv[16], nb[16];
#pragma unroll
    for (int k = 0; k < 4; ++k) {
        float4 cv = *(const float4*)(Lr + pos * 32 + (((qb + k) ^ (pos & 7)) << 2));
        col[4*k] = cv.x; col[4*k+1] = cv.y; col[4*k+2] = cv.z; col[4*k+3] = cv.w;
    }
#pragma unroll
    for (int c = 0; c < 16; ++c) Mv[c] = col[c];
    unsigned mymask = 0;
#pragma unroll 1
    for (int s = 1; s <= 8; ++s) {
        int jj = (pos - s) & 15;
#pragma unroll
        for (int k = 0; k < 4; ++k) {
            float4 nv = *(const float4*)(Lr + jj * 32 + (((qb + k) ^ (jj & 7)) << 2));
            nb[4*k] = nv.x; nb[4*k+1] = nv.y; nb[4*k+2] = nv.z; nb[4*k+3] = nv.w;
        }
        float dh = dist16(col, nb);
        float ds = dh + __shfl_xor(dh, 1, 64);       // half partner = lane^1
        bool border = (ds >= tlo) & (ds <= thi);
        bool cmp;
        if (__ballot(border)) {                      // rare exact path
            double d64h = 0.0;
#pragma unroll
            for (int c = 0; c < 16; ++c) d64h += fabs((double)col[c] - (double)nb[c]);
            double other = __shfl_xor(d64h, 1, 64);
            cmp = (d64h + other) < thr;
        } else {
            cmp = ds < tmf;
        }
        mymask |= (unsigned)cmp << s;
#pragma unroll
        for (int c = 0; c < 16; ++c) Mv[c] = (cmp && nb[c] > Mv[c]) ? nb[c] : Mv[c];
    }
#pragma unroll 1
    for (int s = 9; s <= 15; ++s) {
        int jj = (pos - s) & 15;
        int pl = jj * 4 + c2;                        // partner lane
        int cr = (__shfl((int)mymask, pl, 64) >> (16 - s)) & 1;
#pragma unroll
        for (int k = 0; k < 4; ++k) {
            float4 nv = *(const float4*)(Lr + jj * 32 + (((qb + k) ^ (jj & 7)) << 2));
            nb[4*k] = nv.x; nb[4*k+1] = nv.y; nb[4*k+2] = nv.z; nb[4*k+3] = nv.w;
        }
        bool cmpr = (cr != 0);
#pragma unroll
        for (int c = 0; c < 16; ++c) Mv[c] = (cmpr && nb[c] > Mv[c]) ? nb[c] : Mv[c];
    }
    size_t p = (size_t)F * FS + (size_t)(2 * pos + par) * AS + w0 + wl;
    float* mp = M + ((size_t)b * 65536 + p) * 32 + half * 16;
#pragma unroll
    for (int k = 0; k < 4; ++k) {
        float4 o; o.x = Mv[4*k]; o.y = Mv[4*k+1]; o.z = Mv[4*k+2]; o.w = Mv[4*k+3];
        *(float4*)(mp + 4 * k) = o;
    }
}

// ---------------- unified passes kernel: blk<1024 -> W, <2048 -> H, else D ----------------
__global__ __launch_bounds__(256) void k_passes(const float* __restrict__ x, const double2* __restrict__ npart,
                                                float* __restrict__ Mw, float* __restrict__ Mh,
                                                float* __restrict__ Md) {
    __shared__ __align__(16) float L[4128];
    __shared__ double ls[4], lq[4], thrs[2];
    __shared__ float fb[8];
    int t = threadIdx.x;
    thr_reduce(npart, thrs, fb, ls, lq, t);
    int blk = blockIdx.x;
    if (blk < 1024) {
        // ---- W-axis: 4 rings (2 lines x 2 parities); one wave per ring ----
#pragma unroll
        for (int it = 0; it < 4; ++it) {
            int f = it * 256 + t;
            int ll = f >> 9;
            int l = blk * 2 + ll;
            int c = (f >> 4) & 31, wq = f & 15;
            const float* lb = x + (size_t)(l >> 10) * CDHW_ + ((l >> 5) & 31) * HW_ + (l & 31) * W_;
            float4 v = *(const float4*)(lb + (size_t)c * DHW_ + wq * 4);
            int cq = c >> 2, cr = c & 3;
            const float* ve = (const float*)&v;
#pragma unroll
            for (int e = 0; e < 4; ++e) {
                int wv2 = wq * 4 + e;
                int p = wv2 >> 1, par = wv2 & 1;
                L[(ll * 2 + par) * 1024 + p * 32 + (((cq ^ (p & 7)) << 2) | cr)] = ve[e];
            }
        }
        __syncthreads();
        int ring = t >> 6, ln = t & 63;
        int pos = ln >> 1, half = ln & 1;
        int ll = ring >> 1, par = ring & 1;
        int l = blk * 2 + ll;
        int b = l >> 10, d = (l >> 5) & 31, h = l & 31;
        double thr = thrs[b];
        float tlo = fb[b*4], thi = fb[b*4+1], tmf = fb[b*4+2];
        const float* Lr = L + ring * 1024;
        int qb = half * 4;
        float col[16], Mv[16], nb[16];
#pragma unroll
        for (int k = 0; k < 4; ++k) {
            float4 cv = *(const float4*)(Lr + pos * 32 + (((qb + k) ^ (pos & 7)) << 2));
            col[4*k] = cv.x; col[4*k+1] = cv.y; col[4*k+2] = cv.z; col[4*k+3] = cv.w;
        }
#pragma unroll
        for (int c = 0; c < 16; ++c) Mv[c] = col[c];
#pragma unroll 1
        for (int s = 1; s <= 15; ++s) {
            int jf = (pos - s) & 31;
#pragma unroll
            for (int k = 0; k < 4; ++k) {
                float4 nv = *(const float4*)(Lr + jf * 32 + (((qb + k) ^ (jf & 7)) << 2));
                nb[4*k] = nv.x; nb[4*k+1] = nv.y; nb[4*k+2] = nv.z; nb[4*k+3] = nv.w;
            }
            float dh = dist16(col, nb);
            float ds = dh + __shfl_xor(dh, 1, 64);
            bool border = (ds >= tlo) & (ds <= thi);
            bool cmp;
            if (__ballot(border)) {
                double d64h = 0.0;
#pragma unroll
                for (int c = 0; c < 16; ++c) d64h += fabs((double)col[c] - (double)nb[c]);
                double other = __shfl_xor(d64h, 1, 64);
                cmp = (d64h + other) < thr;
            } else {
                cmp = ds < tmf;
            }
#pragma unroll
            for (int c = 0; c < 16; ++c) Mv[c] = (cmp && nb[c] > Mv[c]) ? nb[c] : Mv[c];
            int cr2 = __shfl(cmp ? 1 : 0, ((pos + s) & 31) * 2 + half, 64);
            int jr = (pos + s) & 31;
#pragma unroll
            for (int k = 0; k < 4; ++k) {
                float4 nv = *(const float4*)(Lr + jr * 32 + (((qb + k) ^ (jr & 7)) << 2));
                nb[4*k] = nv.x; nb[4*k+1] = nv.y; nb[4*k+2] = nv.z; nb[4*k+3] = nv.w;
            }
            bool cmpr = (cr2 != 0);
#pragma unroll
            for (int c = 0; c < 16; ++c) Mv[c] = (cmpr && nb[c] > Mv[c]) ? nb[c] : Mv[c];
        }
        {   // s = 16 self-paired
            int jj = (pos + 16) & 31;
#pragma unroll
            for (int k = 0; k < 4; ++k) {
                float4 nv = *(const float4*)(Lr + jj * 32 + (((qb + k) ^ (jj & 7)) << 2));
                nb[4*k] = nv.x; nb[4*k+1] = nv.y; nb[4*k+2] = nv.z; nb[4*k+3] = nv.w;
            }
            float dh = dist16(col, nb);
            float ds = dh + __shfl_xor(dh, 1, 64);
            bool border = (ds >= tlo) & (ds <= thi);
            bool cmp;
            if (__ballot(border)) {
                double d64h = 0.0;
#pragma unroll
                for (int c = 0; c < 16; ++c) d64h += fabs((double)col[c] - (double)nb[c]);
                double other = __shfl_xor(d64h, 1, 64);
                cmp = (d64h + other) < thr;
            } else {
                cmp = ds < tmf;
            }
#pragma unroll
            for (int c = 0; c < 16; ++c) Mv[c] = (cmp && nb[c] > Mv[c]) ? nb[c] : Mv[c];
        }
        size_t ppt = (size_t)d * HW_ + h * W_ + 2 * pos + par;
        float* mp = Mw + ((size_t)b * 65536 + ppt) * 32 + half * 16;
#pragma unroll
        for (int k = 0; k < 4; ++k) {
            float4 o; o.x = Mv[4*k]; o.y = Mv[4*k+1]; o.z = Mv[4*k+2]; o.w = Mv[4*k+3];
            *(float4*)(mp + 4 * k) = o;
        }
    } else if (blk < 2048) {
        hd_ring<W_, HW_>(x, Mh, thrs, fb, L, blk - 1024, t);   // H pass (F = d)
    } else {
        hd_ring<HW_, W_>(x, Md, thrs, fb, L, blk - 2048, t);   // D pass (F = h)
    }
}

// ---------------- conv (64->32) + fused BN partial stats ----------------
__global__ __launch_bounds__(256, 4) void k_conv(const float* __restrict__ x,
                                                 const float* __restrict__ Mw, const float* __restrict__ Mh,
                                                 const float* __restrict__ Md,
                                                 const float* __restrict__ w, const float* __restrict__ bias,
                                                 float* __restrict__ y, float2* __restrict__ spart) {
    int t = threadIdx.x;
    int blk = blockIdx.x;                            // 0..2047
    int b = blk >> 10;
    int p0 = (blk & 1023) * 64;
    int og = __builtin_amdgcn_readfirstlane(t >> 6);
    int pl = t & 63;
    const float* xb = x + (size_t)b * CDHW_ + p0 + pl;
    size_t moff = ((size_t)b * 65536 + p0 + pl) * 32;
    const float4* mw = (const float4*)(Mw + moff);
    const float4* mh = (const float4*)(Mh + moff);
    const float4* md = (const float4*)(Md + moff);
    const float* wo = w + og * 512;
    const float* bo = bias + og * 8;
    float a[8], xv[32];
#pragma unroll
    for (int k = 0; k < 8; ++k) a[k] = bo[k];
#pragma unroll
    for (int c = 0; c < 32; c += 4) {
        xv[c+0] = xb[(size_t)(c+0) * DHW_];
        xv[c+1] = xb[(size_t)(c+1) * DHW_];
        xv[c+2] = xb[(size_t)(c+2) * DHW_];
        xv[c+3] = xb[(size_t)(c+3) * DHW_];
#pragma unroll
        for (int k = 0; k < 8; ++k) {
            a[k] = fmaf(wo[k*64 + c+0], xv[c+0], a[k]);
            a[k] = fmaf(wo[k*64 + c+1], xv[c+1], a[k]);
            a[k] = fmaf(wo[k*64 + c+2], xv[c+2], a[k]);
            a[k] = fmaf(wo[k*64 + c+3], xv[c+3], a[k]);
        }
    }
#pragma unroll
    for (int q = 0; q < 8; ++q) {
        float4 vw = mw[q], vh = mh[q], vd = md[q];
        float z0 = fmaxf(fmaxf(fmaxf(vw.x, vh.x), vd.x) - xv[4*q+0], 0.f);
        float z1 = fmaxf(fmaxf(fmaxf(vw.y, vh.y), vd.y) - xv[4*q+1], 0.f);
        float z2 = fmaxf(fmaxf(fmaxf(vw.z, vh.z), vd.z) - xv[4*q+2], 0.f);
        float z3 = fmaxf(fmaxf(fmaxf(vw.w, vh.w), vd.w) - xv[4*q+3], 0.f);
#pragma unroll
        for (int k = 0; k < 8; ++k) {
            a[k] = fmaf(wo[k*64 + 32 + q*4 + 0], z0, a[k]);
            a[k] = fmaf(wo[k*64 + 32 + q*4 + 1], z1, a[k]);
            a[k] = fmaf(wo[k*64 + 32 + q*4 + 2], z2, a[k]);
            a[k] = fmaf(wo[k*64 + 32 + q*4 + 3], z3, a[k]);
        }
    }
    float* yb = y + (size_t)b * CDHW_ + p0 + pl;
#pragma unroll
    for (int k = 0; k < 8; ++k) {
        yb[(size_t)(og * 8 + k) * DHW_] = a[k];
        float s = a[k], q = a[k] * a[k];
        for (int off = 32; off; off >>= 1) {
            s += __shfl_down(s, off, 64);
            q += __shfl_down(q, off, 64);
        }
        if (pl == 0) spart[(og * 8 + k) * 2048 + blk] = make_float2(s, q);
    }
}

// ---------------- BN finalize + exact GELU, in-place ----------------
__global__ __launch_bounds__(256) void k_out(float* __restrict__ y, const float2* __restrict__ spart,
                                             const float* __restrict__ gamma, const float* __restrict__ beta) {
    int t = threadIdx.x;
    int o = (blockIdx.x >> 6) & 31;                  // block-uniform channel
    __shared__ double ls[4], lq[4];
    __shared__ float bnp[2];
    {
        const float2* sp = spart + o * 2048;
        double s = 0.0, q = 0.0;
#pragma unroll
        for (int i = 0; i < 8; ++i) {
            float2 v = sp[i * 256 + t];
            s += (double)v.x; q += (double)v.y;
        }
        for (int off = 32; off; off >>= 1) {
            s += __shfl_down(s, off, 64);
            q += __shfl_down(q, off, 64);
        }
        if ((t & 63) == 0) { ls[t >> 6] = s; lq[t >> 6] = q; }
    }
    __syncthreads();
    if (t == 0) {
        double sm = (ls[0] + ls[1]) + (ls[2] + ls[3]);
        double sq = (lq[0] + lq[1]) + (lq[2] + lq[3]);
        double mu = sm / (double)BN_N_;
        double var = sq / (double)BN_N_ - mu * mu;
        bnp[0] = (float)mu;
        bnp[1] = (float)(1.0 / sqrt(var + 1e-5));
    }
    __syncthreads();
    float mu_f = bnp[0], rstd = bnp[1];
    float g = gamma[o], be = beta[o];
    int idx = blockIdx.x * 256 + t;                  // over 1,048,576 float4
    float4 v = ((const float4*)y)[idx];
    float* vv = (float*)&v;
#pragma unroll
    for (int j = 0; j < 4; ++j) {
        float tt = (vv[j] - mu_f) * rstd * g + be;
        vv[j] = 0.5f * tt * (1.f + erff(tt * 0.70710678118654752f));
    }
    ((float4*)y)[idx] = v;
}

extern "C" void kernel_launch(void* const* d_in, const int* in_sizes, int n_in,
                              void* d_out, int out_size, void* d_ws, size_t ws_size,
                              hipStream_t stream) {
    const float* x     = (const float*)d_in[0];
    const float* w     = (const float*)d_in[1];
    const float* bias  = (const float*)d_in[2];
    const float* gamma = (const float*)d_in[3];
    const float* beta  = (const float*)d_in[4];
    float* out = (float*)d_out;
    float* Mw = (float*)d_ws;
    float* Mh = (float*)((char*)d_ws + MH_OFF);
    float* Md = (float*)((char*)d_ws + MD_OFF);
    double2* npart = (double2*)((char*)d_ws + RED_OFF + 256);
    float2*  spart = (float2*)((char*)d_ws + RED_OFF + 256 + 16384);

    k_norm  <<<512, 256, 0, stream>>>(x, npart);
    k_passes<<<3072, 256, 0, stream>>>(x, npart, Mw, Mh, Md);
    k_conv  <<<2048, 256, 0, stream>>>(x, Mw, Mh, Md, w, bias, out, spart);
    k_out   <<<4096, 256, 0, stream>>>(out, spart, gamma, beta);
}

// Round 13
// 103.699 us; speedup vs baseline: 1.1333x; 1.1333x over previous
//
#include <hip/hip_runtime.h>
#include <hip/hip_fp16.h>
#include <math.h>

#define B_ 2
#define C_ 32
#define D_ 32
#define H_ 32
#define W_ 64
#define HW_ (H_*W_)         // 2048
#define DHW_ (D_*H_*W_)     // 65536
#define CDHW_ (C_*DHW_)     // 2097152
#define NSP_ DHW_           // spatial points per batch
#define BN_N_ (B_*DHW_)     // 131072
#define BORDER 1e-3
#define RS 516              // padded LDS ring stride (floats)

// ws layout (fp16 M): Mw @0 (8MB), Mh @8MB, Md @16MB  — each [b][p][c] __half.
// reduction @48MB: npart[512] double2 @ +256, spart[32][2048] float2 @ +256+16384.
#define MH_OFF  (8u<<20)
#define MD_OFF  (16u<<20)
#define RED_OFF (48u<<20)

// ---------------- threshold stats: involution-halved (only d<16; norm[p]==norm[pf] exactly) ----------------
__global__ __launch_bounds__(256) void k_norm(const float* __restrict__ x, double2* __restrict__ npart) {
    int tid = blockIdx.x * 256 + threadIdx.x;       // 131072 threads
    int ln = threadIdx.x & 63;
    int hf = ln >> 5, lp = ln & 31;
    int ph = (tid >> 6) * 32 + lp;                  // 0..65535 half-space points (2x lane coverage)
    int b = ph >> 15;
    int pp = ph & 32767;                            // (d<<11)|(h<<6)|w with d in 0..15
    int d = pp >> 11, h = (pp >> 6) & 31, w = pp & 63;
    int pf = ((d ^ 16) << 11) | ((h ^ 16) << 6) | (w ^ 32);
    const float* xb = x + (size_t)b * CDHW_ + (size_t)hf * 16 * DHW_;
    double s = 0.0;
#pragma unroll
    for (int c = 0; c < 16; ++c) {
        float a  = xb[c * DHW_ + pp];
        float bb = xb[c * DHW_ + pf];
        s += fabs((double)a - (double)bb);
    }
    double st = s + __shfl_xor(s, 32, 64);          // full 32-ch sum (both halves hold it)
    double s2 = st * st;
    for (int off = 32; off; off >>= 1) {
        st += __shfl_down(st, off, 64);
        s2 += __shfl_down(s2, off, 64);
    }
    __shared__ double ls[4], ls2[4];
    int wv = threadIdx.x >> 6;
    if (ln == 0) { ls[wv] = st; ls2[wv] = s2; }
    __syncthreads();
    if (threadIdx.x == 0) {
        double2 o;                                   // 2-lane dup == involution doubling
        o.x = (ls[0] + ls[1]) + (ls[2] + ls[3]);
        o.y = (ls2[0] + ls2[1]) + (ls2[2] + ls2[3]);
        npart[blockIdx.x] = o;
    }
}

// ---------------- per-block redundant thr reduce + f32 gate bounds ----------------
__device__ __forceinline__ void thr_reduce(const double2* __restrict__ npart, double* thrs, float* fb,
                                           double* ls, double* lq, int t) {
    {
        double s = 0.0, q = 0.0;
#pragma unroll
        for (int i = 0; i < 2; ++i) {
            double2 v = npart[t * 2 + i];
            s += v.x; q += v.y;
        }
        for (int off = 32; off; off >>= 1) {
            s += __shfl_down(s, off, 64);
            q += __shfl_down(q, off, 64);
        }
        if ((t & 63) == 0) { ls[t >> 6] = s; lq[t >> 6] = q; }
    }
    __syncthreads();
    if (t < 2) {
        double sum = ls[2 * t] + ls[2 * t + 1];
        double sq  = lq[2 * t] + lq[2 * t + 1];
        double n = (double)NSP_;
        double mean = sum / n;
        double var = (sq - sum * sum / n) / (n - 1.0);   // ddof=1
        if (var < 0.0) var = 0.0;
        double thrv = mean - sqrt(var);
        thrs[t] = thrv;
        fb[t * 4 + 0] = (float)(thrv - BORDER * 1.01);
        fb[t * 4 + 1] = (float)(thrv + BORDER * 1.01);
        fb[t * 4 + 2] = (float)thrv;
    }
    __syncthreads();
}

__device__ __forceinline__ float dist16(const float* col, const float* nb) {
    float d0 = 0.f, d1 = 0.f, d2 = 0.f, d3 = 0.f;
#pragma unroll
    for (int c = 0; c < 16; c += 4) {
        d0 += fabsf(col[c+0] - nb[c+0]);
        d1 += fabsf(col[c+1] - nb[c+1]);
        d2 += fabsf(col[c+2] - nb[c+2]);
        d3 += fabsf(col[c+3] - nb[c+3]);
    }
    return (d0 + d1) + (d2 + d3);
}

__device__ __forceinline__ void store_m16(__half* mp, const float* Mv) {
    __half2 tmp[8];
#pragma unroll
    for (int k = 0; k < 8; ++k) tmp[k] = __floats2half2_rn(Mv[2*k], Mv[2*k+1]);
    *(int4*)mp       = *(int4*)&tmp[0];
    *(int4*)(mp + 8) = *(int4*)&tmp[4];
}

// H/D ring body. 256 threads, 8 rings (one parity). Rolled s-loops (unroll blew VGPR in r10).
template<int AS, int FS>
__device__ __forceinline__ void hd_ring(const float* __restrict__ x, __half* __restrict__ M,
                                        const double* thrs, const float* fb, float* L, int local, int t) {
    int par = local & 1, wt = (local >> 1) & 7, F = (local >> 4) & 31, b = local >> 9;
    int w0 = wt * 8;
    double thr = thrs[b];
    float tlo = fb[b*4], thi = fb[b*4+1], tmf = fb[b*4+2];
    const float* xb = x + (size_t)b * CDHW_ + (size_t)F * FS + w0;
#pragma unroll
    for (int it = 0; it < 4; ++it) {
        int f = it * 256 + t;                        // 0..1023 float4s
        int c = f >> 5, rem = f & 31, j = rem >> 1, wq = rem & 1;
        float4 v = *(const float4*)(xb + (size_t)c * DHW_ + (size_t)(2 * j + par) * AS + wq * 4);
        int sl = (((c >> 2) ^ (j & 7)) << 2) + (c & 3);
        int rb = (wq * 4) * RS + j * 32 + sl;
        L[rb] = v.x; L[rb + RS] = v.y; L[rb + 2*RS] = v.z; L[rb + 3*RS] = v.w;
    }
    __syncthreads();
    int ln = t & 63, wave = t >> 6;
    int pos = ln >> 2, c2 = ln & 3;
    int wl = wave * 2 + (c2 >> 1), hf = c2 & 1;
    const float* Lr = L + wl * RS;
    int qb = hf * 4;
    float col[16], Mv[16], nb[16];
#pragma unroll
    for (int k = 0; k < 4; ++k) {
        float4 cv = *(const float4*)(Lr + pos * 32 + (((qb + k) ^ (pos & 7)) << 2));
        col[4*k] = cv.x; col[4*k+1] = cv.y; col[4*k+2] = cv.z; col[4*k+3] = cv.w;
    }
#pragma unroll
    for (int c = 0; c < 16; ++c) Mv[c] = col[c];
    unsigned mymask = 0;
#pragma unroll 1
    for (int s = 1; s <= 8; ++s) {
        int jj = (pos - s) & 15;
#pragma unroll
        for (int k = 0; k < 4; ++k) {
            float4 nv = *(const float4*)(Lr + jj * 32 + (((qb + k) ^ (jj & 7)) << 2));
            nb[4*k] = nv.x; nb[4*k+1] = nv.y; nb[4*k+2] = nv.z; nb[4*k+3] = nv.w;
        }
        float dh = dist16(col, nb);
        float ds = dh + __shfl_xor(dh, 1, 64);       // half partner = lane^1
        bool border = (ds >= tlo) & (ds <= thi);
        bool cmp;
        if (__ballot(border)) {                      // rare exact path
            double d64h = 0.0;
#pragma unroll
            for (int c = 0; c < 16; ++c) d64h += fabs((double)col[c] - (double)nb[c]);
            double other = __shfl_xor(d64h, 1, 64);
            cmp = (d64h + other) < thr;
        } else {
            cmp = ds < tmf;
        }
        mymask |= (unsigned)cmp << s;
#pragma unroll
        for (int c = 0; c < 16; ++c) Mv[c] = (cmp && nb[c] > Mv[c]) ? nb[c] : Mv[c];
    }
#pragma unroll 1
    for (int s = 9; s <= 15; ++s) {
        int jj = (pos - s) & 15;
        int pl = jj * 4 + c2;                        // partner lane
        int cr = (__shfl((int)mymask, pl, 64) >> (16 - s)) & 1;
#pragma unroll
        for (int k = 0; k < 4; ++k) {
            float4 nv = *(const float4*)(Lr + jj * 32 + (((qb + k) ^ (jj & 7)) << 2));
            nb[4*k] = nv.x; nb[4*k+1] = nv.y; nb[4*k+2] = nv.z; nb[4*k+3] = nv.w;
        }
        bool cmpr = (cr != 0);
#pragma unroll
        for (int c = 0; c < 16; ++c) Mv[c] = (cmpr && nb[c] > Mv[c]) ? nb[c] : Mv[c];
    }
    size_t p = (size_t)F * FS + (size_t)(2 * pos + par) * AS + w0 + wl;
    store_m16(M + ((size_t)b * 65536 + p) * 32 + hf * 16, Mv);
}

// ---------------- unified passes kernel: logical blk<1024 -> W, <2048 -> H, else D ----------------
__global__ __launch_bounds__(256) void k_passes(const float* __restrict__ x, const double2* __restrict__ npart,
                                                __half* __restrict__ Mw, __half* __restrict__ Mh,
                                                __half* __restrict__ Md) {
    __shared__ __align__(16) float L[4128];
    __shared__ double ls[4], lq[4], thrs[2];
    __shared__ float fb[8];
    int t = threadIdx.x;
    thr_reduce(npart, thrs, fb, ls, lq, t);
    int blk = (blockIdx.x & 7) * 384 + (blockIdx.x >> 3);   // bijective XCD swizzle (3072 = 8*384)
    if (blk < 1024) {
        // ---- W-axis: 4 rings (2 lines x 2 parities); one wave per ring ----
#pragma unroll
        for (int it = 0; it < 4; ++it) {
            int f = it * 256 + t;
            int ll = f >> 9;
            int l = blk * 2 + ll;
            int c = (f >> 4) & 31, wq = f & 15;
            const float* lb = x + (size_t)(l >> 10) * CDHW_ + ((l >> 5) & 31) * HW_ + (l & 31) * W_;
            float4 v = *(const float4*)(lb + (size_t)c * DHW_ + wq * 4);
            int cq = c >> 2, cr = c & 3;
            const float* ve = (const float*)&v;
#pragma unroll
            for (int e = 0; e < 4; ++e) {
                int wv2 = wq * 4 + e;
                int p = wv2 >> 1, par = wv2 & 1;
                L[(ll * 2 + par) * 1024 + p * 32 + (((cq ^ (p & 7)) << 2) | cr)] = ve[e];
            }
        }
        __syncthreads();
        int ring = t >> 6, ln = t & 63;
        int pos = ln >> 1, hf = ln & 1;
        int ll = ring >> 1, par = ring & 1;
        int l = blk * 2 + ll;
        int b = l >> 10, d = (l >> 5) & 31, h = l & 31;
        double thr = thrs[b];
        float tlo = fb[b*4], thi = fb[b*4+1], tmf = fb[b*4+2];
        const float* Lr = L + ring * 1024;
        int qb = hf * 4;
        float col[16], Mv[16], nb[16];
#pragma unroll
        for (int k = 0; k < 4; ++k) {
            float4 cv = *(const float4*)(Lr + pos * 32 + (((qb + k) ^ (pos & 7)) << 2));
            col[4*k] = cv.x; col[4*k+1] = cv.y; col[4*k+2] = cv.z; col[4*k+3] = cv.w;
        }
#pragma unroll
        for (int c = 0; c < 16; ++c) Mv[c] = col[c];
#pragma unroll 1
        for (int s = 1; s <= 15; ++s) {
            int jf = (pos - s) & 31;
#pragma unroll
            for (int k = 0; k < 4; ++k) {
                float4 nv = *(const float4*)(Lr + jf * 32 + (((qb + k) ^ (jf & 7)) << 2));
                nb[4*k] = nv.x; nb[4*k+1] = nv.y; nb[4*k+2] = nv.z; nb[4*k+3] = nv.w;
            }
            float dh = dist16(col, nb);
            float ds = dh + __shfl_xor(dh, 1, 64);
            bool border = (ds >= tlo) & (ds <= thi);
            bool cmp;
            if (__ballot(border)) {
                double d64h = 0.0;
#pragma unroll
                for (int c = 0; c < 16; ++c) d64h += fabs((double)col[c] - (double)nb[c]);
                double other = __shfl_xor(d64h, 1, 64);
                cmp = (d64h + other) < thr;
            } else {
                cmp = ds < tmf;
            }
#pragma unroll
            for (int c = 0; c < 16; ++c) Mv[c] = (cmp && nb[c] > Mv[c]) ? nb[c] : Mv[c];
            int cr2 = __shfl(cmp ? 1 : 0, ((pos + s) & 31) * 2 + hf, 64);
            int jr = (pos + s) & 31;
#pragma unroll
            for (int k = 0; k < 4; ++k) {
                float4 nv = *(const float4*)(Lr + jr * 32 + (((qb + k) ^ (jr & 7)) << 2));
                nb[4*k] = nv.x; nb[4*k+1] = nv.y; nb[4*k+2] = nv.z; nb[4*k+3] = nv.w;
            }
            bool cmpr = (cr2 != 0);
#pragma unroll
            for (int c = 0; c < 16; ++c) Mv[c] = (cmpr && nb[c] > Mv[c]) ? nb[c] : Mv[c];
        }
        {   // s = 16 self-paired
            int jj = (pos + 16) & 31;
#pragma unroll
            for (int k = 0; k < 4; ++k) {
                float4 nv = *(const float4*)(Lr + jj * 32 + (((qb + k) ^ (jj & 7)) << 2));
                nb[4*k] = nv.x; nb[4*k+1] = nv.y; nb[4*k+2] = nv.z; nb[4*k+3] = nv.w;
            }
            float dh = dist16(col, nb);
            float ds = dh + __shfl_xor(dh, 1, 64);
            bool border = (ds >= tlo) & (ds <= thi);
            bool cmp;
            if (__ballot(border)) {
                double d64h = 0.0;
#pragma unroll
                for (int c = 0; c < 16; ++c) d64h += fabs((double)col[c] - (double)nb[c]);
                double other = __shfl_xor(d64h, 1, 64);
                cmp = (d64h + other) < thr;
            } else {
                cmp = ds < tmf;
            }
#pragma unroll
            for (int c = 0; c < 16; ++c) Mv[c] = (cmp && nb[c] > Mv[c]) ? nb[c] : Mv[c];
        }
        size_t ppt = (size_t)d * HW_ + h * W_ + 2 * pos + par;
        store_m16(Mw + ((size_t)b * 65536 + ppt) * 32 + hf * 16, Mv);
    } else if (blk < 2048) {
        hd_ring<W_, HW_>(x, Mh, thrs, fb, L, blk - 1024, t);   // H pass (F = d)
    } else {
        hd_ring<HW_, W_>(x, Md, thrs, fb, L, blk - 2048, t);   // D pass (F = h)
    }
}

// ---------------- conv (64->32) + fused BN partial stats; fp16 M, max3 inline ----------------
__global__ __launch_bounds__(256, 4) void k_conv(const float* __restrict__ x,
                                                 const __half* __restrict__ Mw, const __half* __restrict__ Mh,
                                                 const __half* __restrict__ Md,
                                                 const float* __restrict__ w, const float* __restrict__ bias,
                                                 float* __restrict__ y, float2* __restrict__ spart) {
    int t = threadIdx.x;
    int blk = (blockIdx.x & 7) * 256 + (blockIdx.x >> 3);   // bijective XCD swizzle (2048 = 8*256)
    int b = blk >> 10;
    int p0 = (blk & 1023) * 64;
    int og = __builtin_amdgcn_readfirstlane(t >> 6);
    int pl = t & 63;
    const float* xb = x + (size_t)b * CDHW_ + p0 + pl;
    size_t moff = ((size_t)b * 65536 + p0 + pl) * 32;
    const int4* mw4 = (const int4*)(Mw + moff);
    const int4* mh4 = (const int4*)(Mh + moff);
    const int4* md4 = (const int4*)(Md + moff);
    const float* wo = w + og * 512;
    const float* bo = bias + og * 8;
    float a[8], xv[32];
#pragma unroll
    for (int k = 0; k < 8; ++k) a[k] = bo[k];
#pragma unroll
    for (int c = 0; c < 32; c += 4) {
        xv[c+0] = xb[(size_t)(c+0) * DHW_];
        xv[c+1] = xb[(size_t)(c+1) * DHW_];
        xv[c+2] = xb[(size_t)(c+2) * DHW_];
        xv[c+3] = xb[(size_t)(c+3) * DHW_];
#pragma unroll
        for (int k = 0; k < 8; ++k) {
            a[k] = fmaf(wo[k*64 + c+0], xv[c+0], a[k]);
            a[k] = fmaf(wo[k*64 + c+1], xv[c+1], a[k]);
            a[k] = fmaf(wo[k*64 + c+2], xv[c+2], a[k]);
            a[k] = fmaf(wo[k*64 + c+3], xv[c+3], a[k]);
        }
    }
#pragma unroll
    for (int i = 0; i < 4; ++i) {                    // 8 channels per int4 (fp16-packed)
        int4 aw = mw4[i], ah = mh4[i], ad = md4[i];
        const __half2* hw = (const __half2*)&aw;
        const __half2* hh = (const __half2*)&ah;
        const __half2* hd = (const __half2*)&ad;
#pragma unroll
        for (int j = 0; j < 4; ++j) {
            float2 fw = __half22float2(hw[j]);
            float2 fh = __half22float2(hh[j]);
            float2 fd = __half22float2(hd[j]);
            int c = i * 8 + j * 2;
            float z0 = fmaxf(fmaxf(fmaxf(fw.x, fh.x), fd.x) - xv[c+0], 0.f);
            float z1 = fmaxf(fmaxf(fmaxf(fw.y, fh.y), fd.y) - xv[c+1], 0.f);
#pragma unroll
            for (int k = 0; k < 8; ++k) {
                a[k] = fmaf(wo[k*64 + 32 + c+0], z0, a[k]);
                a[k] = fmaf(wo[k*64 + 32 + c+1], z1, a[k]);
            }
        }
    }
    float* yb = y + (size_t)b * CDHW_ + p0 + pl;
#pragma unroll
    for (int k = 0; k < 8; ++k) {
        yb[(size_t)(og * 8 + k) * DHW_] = a[k];
        float s = a[k], q = a[k] * a[k];
        for (int off = 32; off; off >>= 1) {
            s += __shfl_down(s, off, 64);
            q += __shfl_down(q, off, 64);
        }
        if (pl == 0) spart[(og * 8 + k) * 2048 + blk] = make_float2(s, q);
    }
}

// ---------------- BN finalize + exact GELU, in-place ----------------
__global__ __launch_bounds__(256) void k_out(float* __restrict__ y, const float2* __restrict__ spart,
                                             const float* __restrict__ gamma, const float* __restrict__ beta) {
    int t = threadIdx.x;
    int o = (blockIdx.x >> 6) & 31;                  // block-uniform channel
    __shared__ double ls[4], lq[4];
    __shared__ float bnp[2];
    {
        const float2* sp = spart + o * 2048;
        double s = 0.0, q = 0.0;
#pragma unroll
        for (int i = 0; i < 8; ++i) {
            float2 v = sp[i * 256 + t];
            s += (double)v.x; q += (double)v.y;
        }
        for (int off = 32; off; off >>= 1) {
            s += __shfl_down(s, off, 64);
            q += __shfl_down(q, off, 64);
        }
        if ((t & 63) == 0) { ls[t >> 6] = s; lq[t >> 6] = q; }
    }
    __syncthreads();
    if (t == 0) {
        double sm = (ls[0] + ls[1]) + (ls[2] + ls[3]);
        double sq = (lq[0] + lq[1]) + (lq[2] + lq[3]);
        double mu = sm / (double)BN_N_;
        double var = sq / (double)BN_N_ - mu * mu;
        bnp[0] = (float)mu;
        bnp[1] = (float)(1.0 / sqrt(var + 1e-5));
    }
    __syncthreads();
    float mu_f = bnp[0], rstd = bnp[1];
    float g = gamma[o], be = beta[o];
    int idx = blockIdx.x * 256 + t;                  // over 1,048,576 float4
    float4 v = ((const float4*)y)[idx];
    float* vv = (float*)&v;
#pragma unroll
    for (int j = 0; j < 4; ++j) {
        float tt = (vv[j] - mu_f) * rstd * g + be;
        vv[j] = 0.5f * tt * (1.f + erff(tt * 0.70710678118654752f));
    }
    ((float4*)y)[idx] = v;
}

extern "C" void kernel_launch(void* const* d_in, const int* in_sizes, int n_in,
                              void* d_out, int out_size, void* d_ws, size_t ws_size,
                              hipStream_t stream) {
    const float* x     = (const float*)d_in[0];
    const float* w     = (const float*)d_in[1];
    const float* bias  = (const float*)d_in[2];
    const float* gamma = (const float*)d_in[3];
    const float* beta  = (const float*)d_in[4];
    float* out = (float*)d_out;
    __half* Mw = (__half*)d_ws;
    __half* Mh = (__half*)((char*)d_ws + MH_OFF);
    __half* Md = (__half*)((char*)d_ws + MD_OFF);
    double2* npart = (double2*)((char*)d_ws + RED_OFF + 256);
    float2*  spart = (float2*)((char*)d_ws + RED_OFF + 256 + 16384);

    k_norm  <<<512, 256, 0, stream>>>(x, npart);
    k_passes<<<3072, 256, 0, stream>>>(x, npart, Mw, Mh, Md);
    k_conv  <<<2048, 256, 0, stream>>>(x, Mw, Mh, Md, w, bias, out, spart);
    k_out   <<<4096, 256, 0, stream>>>(out, spart, gamma, beta);
}

// Round 14
// 101.952 us; speedup vs baseline: 1.1528x; 1.0171x over previous
//
#include <hip/hip_runtime.h>
#include <hip/hip_fp16.h>
#include <math.h>

#define B_ 2
#define C_ 32
#define D_ 32
#define H_ 32
#define W_ 64
#define HW_ (H_*W_)         // 2048
#define DHW_ (D_*H_*W_)     // 65536
#define CDHW_ (C_*DHW_)     // 2097152
#define NSP_ DHW_           // spatial points per batch
#define BN_N_ (B_*DHW_)     // 131072
#define BORDER 1e-3
#define RS 516              // padded LDS ring stride (floats)

// ws layout (fp16 M): Mw @0 (8MB), Mh @8MB, Md @16MB  — each [b][p][c] __half.
// reduction @48MB: npart[512] double2 @ +256, spart[32][2048] float2 @ +256+16384.
#define MH_OFF  (8u<<20)
#define MD_OFF  (16u<<20)
#define RED_OFF (48u<<20)

// ---------------- threshold stats: involution-halved (only d<16; norm[p]==norm[pf] exactly) ----------------
__global__ __launch_bounds__(256) void k_norm(const float* __restrict__ x, double2* __restrict__ npart) {
    int tid = blockIdx.x * 256 + threadIdx.x;       // 131072 threads
    int ln = threadIdx.x & 63;
    int hf = ln >> 5, lp = ln & 31;
    int ph = (tid >> 6) * 32 + lp;                  // 0..65535 half-space points (2x lane coverage)
    int b = ph >> 15;
    int pp = ph & 32767;                            // (d<<11)|(h<<6)|w with d in 0..15
    int d = pp >> 11, h = (pp >> 6) & 31, w = pp & 63;
    int pf = ((d ^ 16) << 11) | ((h ^ 16) << 6) | (w ^ 32);
    const float* xb = x + (size_t)b * CDHW_ + (size_t)hf * 16 * DHW_;
    double s = 0.0;
#pragma unroll
    for (int c = 0; c < 16; ++c) {
        float a  = xb[c * DHW_ + pp];
        float bb = xb[c * DHW_ + pf];
        s += fabs((double)a - (double)bb);
    }
    double st = s + __shfl_xor(s, 32, 64);          // full 32-ch sum (both halves hold it)
    double s2 = st * st;
    for (int off = 32; off; off >>= 1) {
        st += __shfl_down(st, off, 64);
        s2 += __shfl_down(s2, off, 64);
    }
    __shared__ double ls[4], ls2[4];
    int wv = threadIdx.x >> 6;
    if (ln == 0) { ls[wv] = st; ls2[wv] = s2; }
    __syncthreads();
    if (threadIdx.x == 0) {
        double2 o;                                   // 2-lane dup == involution doubling
        o.x = (ls[0] + ls[1]) + (ls[2] + ls[3]);
        o.y = (ls2[0] + ls2[1]) + (ls2[2] + ls2[3]);
        npart[blockIdx.x] = o;
    }
}

// ---------------- per-block redundant thr reduce + f32 gate bounds ----------------
__device__ __forceinline__ void thr_reduce(const double2* __restrict__ npart, double* thrs, float* fb,
                                           double* ls, double* lq, int t) {
    {
        double s = 0.0, q = 0.0;
#pragma unroll
        for (int i = 0; i < 2; ++i) {
            double2 v = npart[t * 2 + i];
            s += v.x; q += v.y;
        }
        for (int off = 32; off; off >>= 1) {
            s += __shfl_down(s, off, 64);
            q += __shfl_down(q, off, 64);
        }
        if ((t & 63) == 0) { ls[t >> 6] = s; lq[t >> 6] = q; }
    }
    __syncthreads();
    if (t < 2) {
        double sum = ls[2 * t] + ls[2 * t + 1];
        double sq  = lq[2 * t] + lq[2 * t + 1];
        double n = (double)NSP_;
        double mean = sum / n;
        double var = (sq - sum * sum / n) / (n - 1.0);   // ddof=1
        if (var < 0.0) var = 0.0;
        double thrv = mean - sqrt(var);
        thrs[t] = thrv;
        fb[t * 4 + 0] = (float)(thrv - BORDER * 1.01);
        fb[t * 4 + 1] = (float)(thrv + BORDER * 1.01);
        fb[t * 4 + 2] = (float)thrv;
    }
    __syncthreads();
}

__device__ __forceinline__ float dist16(const float* col, const float* nb) {
    float d0 = 0.f, d1 = 0.f, d2 = 0.f, d3 = 0.f;
#pragma unroll
    for (int c = 0; c < 16; c += 4) {
        d0 += fabsf(col[c+0] - nb[c+0]);
        d1 += fabsf(col[c+1] - nb[c+1]);
        d2 += fabsf(col[c+2] - nb[c+2]);
        d3 += fabsf(col[c+3] - nb[c+3]);
    }
    return (d0 + d1) + (d2 + d3);
}

__device__ __forceinline__ void store_m16(__half* mp, const float* Mv) {
    __half2 tmp[8];
#pragma unroll
    for (int k = 0; k < 8; ++k) tmp[k] = __floats2half2_rn(Mv[2*k], Mv[2*k+1]);
    *(int4*)mp       = *(int4*)&tmp[0];
    *(int4*)(mp + 8) = *(int4*)&tmp[4];
}

// H/D ring body. 256 threads, 8 rings (one parity). Rolled s-loops; reverse merges LAZY
// (only for selected shifts — selection density ~16%, so most loads/merges are skipped).
template<int AS, int FS>
__device__ __forceinline__ void hd_ring(const float* __restrict__ x, __half* __restrict__ M,
                                        const double* thrs, const float* fb, float* L, int local, int t) {
    int par = local & 1, wt = (local >> 1) & 7, F = (local >> 4) & 31, b = local >> 9;
    int w0 = wt * 8;
    double thr = thrs[b];
    float tlo = fb[b*4], thi = fb[b*4+1], tmf = fb[b*4+2];
    const float* xb = x + (size_t)b * CDHW_ + (size_t)F * FS + w0;
#pragma unroll
    for (int it = 0; it < 4; ++it) {
        int f = it * 256 + t;                        // 0..1023 float4s
        int c = f >> 5, rem = f & 31, j = rem >> 1, wq = rem & 1;
        float4 v = *(const float4*)(xb + (size_t)c * DHW_ + (size_t)(2 * j + par) * AS + wq * 4);
        int sl = (((c >> 2) ^ (j & 7)) << 2) + (c & 3);
        int rb = (wq * 4) * RS + j * 32 + sl;
        L[rb] = v.x; L[rb + RS] = v.y; L[rb + 2*RS] = v.z; L[rb + 3*RS] = v.w;
    }
    __syncthreads();
    int ln = t & 63, wave = t >> 6;
    int pos = ln >> 2, c2 = ln & 3;
    int wl = wave * 2 + (c2 >> 1), hf = c2 & 1;
    const float* Lr = L + wl * RS;
    int qb = hf * 4;
    float col[16], Mv[16], nb[16];
#pragma unroll
    for (int k = 0; k < 4; ++k) {
        float4 cv = *(const float4*)(Lr + pos * 32 + (((qb + k) ^ (pos & 7)) << 2));
        col[4*k] = cv.x; col[4*k+1] = cv.y; col[4*k+2] = cv.z; col[4*k+3] = cv.w;
    }
#pragma unroll
    for (int c = 0; c < 16; ++c) Mv[c] = col[c];
    unsigned mymask = 0;
#pragma unroll 1
    for (int s = 1; s <= 8; ++s) {                   // forward: dist + gate + inline merge
        int jj = (pos - s) & 15;
#pragma unroll
        for (int k = 0; k < 4; ++k) {
            float4 nv = *(const float4*)(Lr + jj * 32 + (((qb + k) ^ (jj & 7)) << 2));
            nb[4*k] = nv.x; nb[4*k+1] = nv.y; nb[4*k+2] = nv.z; nb[4*k+3] = nv.w;
        }
        float dh = dist16(col, nb);
        float ds = dh + __shfl_xor(dh, 1, 64);       // half partner = lane^1
        bool border = (ds >= tlo) & (ds <= thi);
        bool cmp;
        if (__ballot(border)) {                      // rare exact path
            double d64h = 0.0;
#pragma unroll
            for (int c = 0; c < 16; ++c) d64h += fabs((double)col[c] - (double)nb[c]);
            double other = __shfl_xor(d64h, 1, 64);
            cmp = (d64h + other) < thr;
        } else {
            cmp = ds < tmf;
        }
        mymask |= (unsigned)cmp << s;
#pragma unroll
        for (int c = 0; c < 16; ++c) Mv[c] = (cmp && nb[c] > Mv[c]) ? nb[c] : Mv[c];
    }
    // reverse: gather partner bits (1 shuffle each), then lazy merge of SELECTED shifts only
    unsigned rmask = 0;
#pragma unroll 1
    for (int s = 9; s <= 15; ++s) {
        int jj = (pos - s) & 15;
        int pl = jj * 4 + c2;                        // partner lane (same wl/half, pos-s)
        rmask |= (unsigned)((__shfl((int)mymask, pl, 64) >> (16 - s)) & 1) << s;
    }
    while (rmask) {
        int s = __ffs(rmask) - 1;
        rmask &= rmask - 1;
        int jj = (pos - s) & 15;
#pragma unroll
        for (int k = 0; k < 4; ++k) {
            float4 nv = *(const float4*)(Lr + jj * 32 + (((qb + k) ^ (jj & 7)) << 2));
            nb[4*k] = nv.x; nb[4*k+1] = nv.y; nb[4*k+2] = nv.z; nb[4*k+3] = nv.w;
        }
#pragma unroll
        for (int c = 0; c < 16; ++c) Mv[c] = fmaxf(Mv[c], nb[c]);
    }
    size_t p = (size_t)F * FS + (size_t)(2 * pos + par) * AS + w0 + wl;
    store_m16(M + ((size_t)b * 65536 + p) * 32 + hf * 16, Mv);
}

// ---------------- unified passes kernel: logical blk<1024 -> W, <2048 -> H, else D ----------------
__global__ __launch_bounds__(256) void k_passes(const float* __restrict__ x, const double2* __restrict__ npart,
                                                __half* __restrict__ Mw, __half* __restrict__ Mh,
                                                __half* __restrict__ Md) {
    __shared__ __align__(16) float L[4128];
    __shared__ double ls[4], lq[4], thrs[2];
    __shared__ float fb[8];
    int t = threadIdx.x;
    thr_reduce(npart, thrs, fb, ls, lq, t);
    int blk = (blockIdx.x & 7) * 384 + (blockIdx.x >> 3);   // bijective XCD swizzle (3072 = 8*384)
    if (blk < 1024) {
        // ---- W-axis: 4 rings (2 lines x 2 parities); one wave per ring ----
#pragma unroll
        for (int it = 0; it < 4; ++it) {
            int f = it * 256 + t;
            int ll = f >> 9;
            int l = blk * 2 + ll;
            int c = (f >> 4) & 31, wq = f & 15;
            const float* lb = x + (size_t)(l >> 10) * CDHW_ + ((l >> 5) & 31) * HW_ + (l & 31) * W_;
            float4 v = *(const float4*)(lb + (size_t)c * DHW_ + wq * 4);
            int cq = c >> 2, cr = c & 3;
            const float* ve = (const float*)&v;
#pragma unroll
            for (int e = 0; e < 4; ++e) {
                int wv2 = wq * 4 + e;
                int p = wv2 >> 1, par = wv2 & 1;
                L[(ll * 2 + par) * 1024 + p * 32 + (((cq ^ (p & 7)) << 2) | cr)] = ve[e];
            }
        }
        __syncthreads();
        int ring = t >> 6, ln = t & 63;
        int pos = ln >> 1, hf = ln & 1;
        int ll = ring >> 1, par = ring & 1;
        int l = blk * 2 + ll;
        int b = l >> 10, d = (l >> 5) & 31, h = l & 31;
        double thr = thrs[b];
        float tlo = fb[b*4], thi = fb[b*4+1], tmf = fb[b*4+2];
        const float* Lr = L + ring * 1024;
        int qb = hf * 4;
        float col[16], Mv[16], nb[16];
#pragma unroll
        for (int k = 0; k < 4; ++k) {
            float4 cv = *(const float4*)(Lr + pos * 32 + (((qb + k) ^ (pos & 7)) << 2));
            col[4*k] = cv.x; col[4*k+1] = cv.y; col[4*k+2] = cv.z; col[4*k+3] = cv.w;
        }
#pragma unroll
        for (int c = 0; c < 16; ++c) Mv[c] = col[c];
        unsigned fmaskw = 0;
#pragma unroll 1
        for (int s = 1; s <= 15; ++s) {              // forward: dist + gate + inline merge
            int jf = (pos - s) & 31;
#pragma unroll
            for (int k = 0; k < 4; ++k) {
                float4 nv = *(const float4*)(Lr + jf * 32 + (((qb + k) ^ (jf & 7)) << 2));
                nb[4*k] = nv.x; nb[4*k+1] = nv.y; nb[4*k+2] = nv.z; nb[4*k+3] = nv.w;
            }
            float dh = dist16(col, nb);
            float ds = dh + __shfl_xor(dh, 1, 64);
            bool border = (ds >= tlo) & (ds <= thi);
            bool cmp;
            if (__ballot(border)) {
                double d64h = 0.0;
#pragma unroll
                for (int c = 0; c < 16; ++c) d64h += fabs((double)col[c] - (double)nb[c]);
                double other = __shfl_xor(d64h, 1, 64);
                cmp = (d64h + other) < thr;
            } else {
                cmp = ds < tmf;
            }
            fmaskw |= (unsigned)cmp << s;
#pragma unroll
            for (int c = 0; c < 16; ++c) Mv[c] = (cmp && nb[c] > Mv[c]) ? nb[c] : Mv[c];
        }
        {   // s = 16 self-paired (inline)
            int jj = (pos + 16) & 31;
#pragma unroll
            for (int k = 0; k < 4; ++k) {
                float4 nv = *(const float4*)(Lr + jj * 32 + (((qb + k) ^ (jj & 7)) << 2));
                nb[4*k] = nv.x; nb[4*k+1] = nv.y; nb[4*k+2] = nv.z; nb[4*k+3] = nv.w;
            }
            float dh = dist16(col, nb);
            float ds = dh + __shfl_xor(dh, 1, 64);
            bool border = (ds >= tlo) & (ds <= thi);
            bool cmp;
            if (__ballot(border)) {
                double d64h = 0.0;
#pragma unroll
                for (int c = 0; c < 16; ++c) d64h += fabs((double)col[c] - (double)nb[c]);
                double other = __shfl_xor(d64h, 1, 64);
                cmp = (d64h + other) < thr;
            } else {
                cmp = ds < tmf;
            }
#pragma unroll
            for (int c = 0; c < 16; ++c) Mv[c] = (cmp && nb[c] > Mv[c]) ? nb[c] : Mv[c];
        }
        // reverse shifts rs = 32 - s (s=1..15): gather partner bits, lazy merge selected only
        unsigned rmask = 0;
#pragma unroll 1
        for (int s = 1; s <= 15; ++s) {
            int pl2 = (((pos + s) & 31) << 1) + hf;  // partner lane (same half, pos+s)
            rmask |= (unsigned)((__shfl((int)fmaskw, pl2, 64) >> s) & 1) << (32 - s);
        }
        while (rmask) {
            int s = __ffs(rmask) - 1;                // s in 17..31
            rmask &= rmask - 1;
            int jj = (pos - s) & 31;
#pragma unroll
            for (int k = 0; k < 4; ++k) {
                float4 nv = *(const float4*)(Lr + jj * 32 + (((qb + k) ^ (jj & 7)) << 2));
                nb[4*k] = nv.x; nb[4*k+1] = nv.y; nb[4*k+2] = nv.z; nb[4*k+3] = nv.w;
            }
#pragma unroll
            for (int c = 0; c < 16; ++c) Mv[c] = fmaxf(Mv[c], nb[c]);
        }
        size_t ppt = (size_t)d * HW_ + h * W_ + 2 * pos + par;
        store_m16(Mw + ((size_t)b * 65536 + ppt) * 32 + hf * 16, Mv);
    } else if (blk < 2048) {
        hd_ring<W_, HW_>(x, Mh, thrs, fb, L, blk - 1024, t);   // H pass (F = d)
    } else {
        hd_ring<HW_, W_>(x, Md, thrs, fb, L, blk - 2048, t);   // D pass (F = h)
    }
}

// ---------------- conv (64->32) + fused BN partial stats; fp16 M, max3 inline ----------------
__global__ __launch_bounds__(256, 4) void k_conv(const float* __restrict__ x,
                                                 const __half* __restrict__ Mw, const __half* __restrict__ Mh,
                                                 const __half* __restrict__ Md,
                                                 const float* __restrict__ w, const float* __restrict__ bias,
                                                 float* __restrict__ y, float2* __restrict__ spart) {
    int t = threadIdx.x;
    int blk = (blockIdx.x & 7) * 256 + (blockIdx.x >> 3);   // bijective XCD swizzle (2048 = 8*256)
    int b = blk >> 10;
    int p0 = (blk & 1023) * 64;
    int og = __builtin_amdgcn_readfirstlane(t >> 6);
    int pl = t & 63;
    const float* xb = x + (size_t)b * CDHW_ + p0 + pl;
    size_t moff = ((size_t)b * 65536 + p0 + pl) * 32;
    const int4* mw4 = (const int4*)(Mw + moff);
    const int4* mh4 = (const int4*)(Mh + moff);
    const int4* md4 = (const int4*)(Md + moff);
    const float* wo = w + og * 512;
    const float* bo = bias + og * 8;
    float a[8], xv[32];
#pragma unroll
    for (int k = 0; k < 8; ++k) a[k] = bo[k];
#pragma unroll
    for (int c = 0; c < 32; c += 4) {
        xv[c+0] = xb[(size_t)(c+0) * DHW_];
        xv[c+1] = xb[(size_t)(c+1) * DHW_];
        xv[c+2] = xb[(size_t)(c+2) * DHW_];
        xv[c+3] = xb[(size_t)(c+3) * DHW_];
#pragma unroll
        for (int k = 0; k < 8; ++k) {
            a[k] = fmaf(wo[k*64 + c+0], xv[c+0], a[k]);
            a[k] = fmaf(wo[k*64 + c+1], xv[c+1], a[k]);
            a[k] = fmaf(wo[k*64 + c+2], xv[c+2], a[k]);
            a[k] = fmaf(wo[k*64 + c+3], xv[c+3], a[k]);
        }
    }
#pragma unroll
    for (int i = 0; i < 4; ++i) {                    // 8 channels per int4 (fp16-packed)
        int4 aw = mw4[i], ah = mh4[i], ad = md4[i];
        const __half2* hw = (const __half2*)&aw;
        const __half2* hh = (const __half2*)&ah;
        const __half2* hd = (const __half2*)&ad;
#pragma unroll
        for (int j = 0; j < 4; ++j) {
            float2 fw = __half22float2(hw[j]);
            float2 fh = __half22float2(hh[j]);
            float2 fd = __half22float2(hd[j]);
            int c = i * 8 + j * 2;
            float z0 = fmaxf(fmaxf(fmaxf(fw.x, fh.x), fd.x) - xv[c+0], 0.f);
            float z1 = fmaxf(fmaxf(fmaxf(fw.y, fh.y), fd.y) - xv[c+1], 0.f);
#pragma unroll
            for (int k = 0; k < 8; ++k) {
                a[k] = fmaf(wo[k*64 + 32 + c+0], z0, a[k]);
                a[k] = fmaf(wo[k*64 + 32 + c+1], z1, a[k]);
            }
        }
    }
    float* yb = y + (size_t)b * CDHW_ + p0 + pl;
#pragma unroll
    for (int k = 0; k < 8; ++k) {
        yb[(size_t)(og * 8 + k) * DHW_] = a[k];
        float s = a[k], q = a[k] * a[k];
        for (int off = 32; off; off >>= 1) {
            s += __shfl_down(s, off, 64);
            q += __shfl_down(q, off, 64);
        }
        if (pl == 0) spart[(og * 8 + k) * 2048 + blk] = make_float2(s, q);
    }
}

// ---------------- BN finalize + exact GELU, in-place ----------------
__global__ __launch_bounds__(256) void k_out(float* __restrict__ y, const float2* __restrict__ spart,
                                             const float* __restrict__ gamma, const float* __restrict__ beta) {
    int t = threadIdx.x;
    int o = (blockIdx.x >> 6) & 31;                  // block-uniform channel
    __shared__ double ls[4], lq[4];
    __shared__ float bnp[2];
    {
        const float2* sp = spart + o * 2048;
        double s = 0.0, q = 0.0;
#pragma unroll
        for (int i = 0; i < 8; ++i) {
            float2 v = sp[i * 256 + t];
            s += (double)v.x; q += (double)v.y;
        }
        for (int off = 32; off; off >>= 1) {
            s += __shfl_down(s, off, 64);
            q += __shfl_down(q, off, 64);
        }
        if ((t & 63) == 0) { ls[t >> 6] = s; lq[t >> 6] = q; }
    }
    __syncthreads();
    if (t == 0) {
        double sm = (ls[0] + ls[1]) + (ls[2] + ls[3]);
        double sq = (lq[0] + lq[1]) + (lq[2] + lq[3]);
        double mu = sm / (double)BN_N_;
        double var = sq / (double)BN_N_ - mu * mu;
        bnp[0] = (float)mu;
        bnp[1] = (float)(1.0 / sqrt(var + 1e-5));
    }
    __syncthreads();
    float mu_f = bnp[0], rstd = bnp[1];
    float g = gamma[o], be = beta[o];
    int idx = blockIdx.x * 256 + t;                  // over 1,048,576 float4
    float4 v = ((const float4*)y)[idx];
    float* vv = (float*)&v;
#pragma unroll
    for (int j = 0; j < 4; ++j) {
        float tt = (vv[j] - mu_f) * rstd * g + be;
        vv[j] = 0.5f * tt * (1.f + erff(tt * 0.70710678118654752f));
    }
    ((float4*)y)[idx] = v;
}

extern "C" void kernel_launch(void* const* d_in, const int* in_sizes, int n_in,
                              void* d_out, int out_size, void* d_ws, size_t ws_size,
                              hipStream_t stream) {
    const float* x     = (const float*)d_in[0];
    const float* w     = (const float*)d_in[1];
    const float* bias  = (const float*)d_in[2];
    const float* gamma = (const float*)d_in[3];
    const float* beta  = (const float*)d_in[4];
    float* out = (float*)d_out;
    __half* Mw = (__half*)d_ws;
    __half* Mh = (__half*)((char*)d_ws + MH_OFF);
    __half* Md = (__half*)((char*)d_ws + MD_OFF);
    double2* npart = (double2*)((char*)d_ws + RED_OFF + 256);
    float2*  spart = (float2*)((char*)d_ws + RED_OFF + 256 + 16384);

    k_norm  <<<512, 256, 0, stream>>>(x, npart);
    k_passes<<<3072, 256, 0, stream>>>(x, npart, Mw, Mh, Md);
    k_conv  <<<2048, 256, 0, stream>>>(x, Mw, Mh, Md, w, bias, out, spart);
    k_out   <<<4096, 256, 0, stream>>>(out, spart, gamma, beta);
}

// Round 15
// 100.335 us; speedup vs baseline: 1.1713x; 1.0161x over previous
//
#include <hip/hip_runtime.h>
#include <hip/hip_fp16.h>
#include <math.h>

#define B_ 2
#define C_ 32
#define D_ 32
#define H_ 32
#define W_ 64
#define HW_ (H_*W_)         // 2048
#define DHW_ (D_*H_*W_)     // 65536
#define CDHW_ (C_*DHW_)     // 2097152
#define NSP_ DHW_           // spatial points per batch
#define BN_N_ (B_*DHW_)     // 131072
#define BORDER 1e-3
#define RS 516              // padded LDS ring stride (floats)

// ws layout (fp16 M): Mw @0 (8MB), Mh @8MB, Md @16MB  — each [b][p][c] __half.
// reduction @48MB: npart[512] double2 @ +256, spart[32][2048] float2 @ +256+16384.
#define MH_OFF  (8u<<20)
#define MD_OFF  (16u<<20)
#define RED_OFF (48u<<20)

// ---------------- threshold stats: involution-halved (only d<16; norm[p]==norm[pf] exactly) ----------------
__global__ __launch_bounds__(256) void k_norm(const float* __restrict__ x, double2* __restrict__ npart) {
    int tid = blockIdx.x * 256 + threadIdx.x;       // 131072 threads
    int ln = threadIdx.x & 63;
    int hf = ln >> 5, lp = ln & 31;
    int ph = (tid >> 6) * 32 + lp;                  // 0..65535 half-space points (2x lane coverage)
    int b = ph >> 15;
    int pp = ph & 32767;                            // (d<<11)|(h<<6)|w with d in 0..15
    int d = pp >> 11, h = (pp >> 6) & 31, w = pp & 63;
    int pf = ((d ^ 16) << 11) | ((h ^ 16) << 6) | (w ^ 32);
    const float* xb = x + (size_t)b * CDHW_ + (size_t)hf * 16 * DHW_;
    double s = 0.0;
#pragma unroll
    for (int c = 0; c < 16; ++c) {
        float a  = xb[c * DHW_ + pp];
        float bb = xb[c * DHW_ + pf];
        s += fabs((double)a - (double)bb);
    }
    double st = s + __shfl_xor(s, 32, 64);          // full 32-ch sum (both halves hold it)
    double s2 = st * st;
    for (int off = 32; off; off >>= 1) {
        st += __shfl_down(st, off, 64);
        s2 += __shfl_down(s2, off, 64);
    }
    __shared__ double ls[4], ls2[4];
    int wv = threadIdx.x >> 6;
    if (ln == 0) { ls[wv] = st; ls2[wv] = s2; }
    __syncthreads();
    if (threadIdx.x == 0) {
        double2 o;                                   // 2-lane dup == involution doubling
        o.x = (ls[0] + ls[1]) + (ls[2] + ls[3]);
        o.y = (ls2[0] + ls2[1]) + (ls2[2] + ls2[3]);
        npart[blockIdx.x] = o;
    }
}

// ---------------- per-block redundant thr reduce + f32 gate bounds ----------------
__device__ __forceinline__ void thr_reduce(const double2* __restrict__ npart, double* thrs, float* fb,
                                           double* ls, double* lq, int t) {
    {
        double s = 0.0, q = 0.0;
#pragma unroll
        for (int i = 0; i < 2; ++i) {
            double2 v = npart[t * 2 + i];
            s += v.x; q += v.y;
        }
        for (int off = 32; off; off >>= 1) {
            s += __shfl_down(s, off, 64);
            q += __shfl_down(q, off, 64);
        }
        if ((t & 63) == 0) { ls[t >> 6] = s; lq[t >> 6] = q; }
    }
    __syncthreads();
    if (t < 2) {
        double sum = ls[2 * t] + ls[2 * t + 1];
        double sq  = lq[2 * t] + lq[2 * t + 1];
        double n = (double)NSP_;
        double mean = sum / n;
        double var = (sq - sum * sum / n) / (n - 1.0);   // ddof=1
        if (var < 0.0) var = 0.0;
        double thrv = mean - sqrt(var);
        thrs[t] = thrv;
        fb[t * 4 + 0] = (float)(thrv - BORDER * 1.01);
        fb[t * 4 + 1] = (float)(thrv + BORDER * 1.01);
        fb[t * 4 + 2] = (float)thrv;
    }
    __syncthreads();
}

__device__ __forceinline__ float dist16(const float* col, const float* nb) {
    float d0 = 0.f, d1 = 0.f, d2 = 0.f, d3 = 0.f;
#pragma unroll
    for (int c = 0; c < 16; c += 4) {
        d0 += fabsf(col[c+0] - nb[c+0]);
        d1 += fabsf(col[c+1] - nb[c+1]);
        d2 += fabsf(col[c+2] - nb[c+2]);
        d3 += fabsf(col[c+3] - nb[c+3]);
    }
    return (d0 + d1) + (d2 + d3);
}

__device__ __forceinline__ void store_m16(__half* mp, const float* Mv) {
    __half2 tmp[8];
#pragma unroll
    for (int k = 0; k < 8; ++k) tmp[k] = __floats2half2_rn(Mv[2*k], Mv[2*k+1]);
    *(int4*)mp       = *(int4*)&tmp[0];
    *(int4*)(mp + 8) = *(int4*)&tmp[4];
}

#define LOAD_NB(LRP, JJ) \
    { _Pragma("unroll") for (int k = 0; k < 4; ++k) { \
        float4 nv = *(const float4*)((LRP) + (JJ) * 32 + (((qb + k) ^ ((JJ) & 7)) << 2)); \
        nb[4*k] = nv.x; nb[4*k+1] = nv.y; nb[4*k+2] = nv.z; nb[4*k+3] = nv.w; } }

// H/D ring body. 256 threads, 8 rings (one parity). Forward loop is dist+mask ONLY;
// border fixup (wave-uniform, rare) and ALL merges are deferred; merges lazy over
// selected shifts (~16% density). Decisions bit-identical; fmax commutative.
template<int AS, int FS>
__device__ __forceinline__ void hd_ring(const float* __restrict__ x, __half* __restrict__ M,
                                        const double* thrs, const float* fb, float* L, int local, int t) {
    int par = local & 1, wt = (local >> 1) & 7, F = (local >> 4) & 31, b = local >> 9;
    int w0 = wt * 8;
    double thr = thrs[b];
    float tlo = fb[b*4], thi = fb[b*4+1], tmf = fb[b*4+2];
    const float* xb = x + (size_t)b * CDHW_ + (size_t)F * FS + w0;
#pragma unroll
    for (int it = 0; it < 4; ++it) {
        int f = it * 256 + t;                        // 0..1023 float4s
        int c = f >> 5, rem = f & 31, j = rem >> 1, wq = rem & 1;
        float4 v = *(const float4*)(xb + (size_t)c * DHW_ + (size_t)(2 * j + par) * AS + wq * 4);
        int sl = (((c >> 2) ^ (j & 7)) << 2) + (c & 3);
        int rb = (wq * 4) * RS + j * 32 + sl;
        L[rb] = v.x; L[rb + RS] = v.y; L[rb + 2*RS] = v.z; L[rb + 3*RS] = v.w;
    }
    __syncthreads();
    int ln = t & 63, wave = t >> 6;
    int pos = ln >> 2, c2 = ln & 3;
    int wl = wave * 2 + (c2 >> 1), hf = c2 & 1;
    const float* Lr = L + wl * RS;
    int qb = hf * 4;
    float col[16], nb[16];
#pragma unroll
    for (int k = 0; k < 4; ++k) {
        float4 cv = *(const float4*)(Lr + pos * 32 + (((qb + k) ^ (pos & 7)) << 2));
        col[4*k] = cv.x; col[4*k+1] = cv.y; col[4*k+2] = cv.z; col[4*k+3] = cv.w;
    }
    unsigned fmask = 0, bmask = 0;
#pragma unroll 1
    for (int s = 1; s <= 8; ++s) {                   // forward: dist + mask bits only
        int jj = (pos - s) & 15;
        LOAD_NB(Lr, jj);
        float dh = dist16(col, nb);
        float ds = dh + __shfl_xor(dh, 1, 64);       // same value in both paired lanes
        fmask |= (unsigned)(ds < tmf) << s;
        bmask |= (unsigned)((ds >= tlo) & (ds <= thi)) << s;
    }
    if (__ballot(bmask != 0)) {                      // rare fp64 fixup, wave-uniform
#pragma unroll 1
        for (int s = 1; s <= 8; ++s) {
            if (__ballot((bmask >> s) & 1)) {
                int jj = (pos - s) & 15;
                LOAD_NB(Lr, jj);
                double d64h = 0.0;
#pragma unroll
                for (int c = 0; c < 16; ++c) d64h += fabs((double)col[c] - (double)nb[c]);
                double other = __shfl_xor(d64h, 1, 64);
                unsigned cc = (unsigned)((d64h + other) < thr);
                if ((bmask >> s) & 1) fmask = (fmask & ~(1u << s)) | (cc << s);
            }
        }
    }
    unsigned rmask = 0;                              // reverse bits from partner (after fixup)
#pragma unroll 1
    for (int s = 9; s <= 15; ++s) {
        int jj = (pos - s) & 15;
        int pl = jj * 4 + c2;                        // partner lane (same wl/half, pos-s)
        rmask |= (unsigned)((__shfl((int)fmask, pl, 64) >> (16 - s)) & 1) << s;
    }
    float Mv[16];
#pragma unroll
    for (int c = 0; c < 16; ++c) Mv[c] = col[c];
    unsigned allm = (fmask & 0x1FEu) | rmask;        // bits 1..8 fwd, 9..15 rev
    while (allm) {                                   // lazy merge of SELECTED shifts only
        int s = __ffs(allm) - 1;
        allm &= allm - 1;
        int jj = (pos - s) & 15;
        LOAD_NB(Lr, jj);
#pragma unroll
        for (int c = 0; c < 16; ++c) Mv[c] = fmaxf(Mv[c], nb[c]);
    }
    size_t p = (size_t)F * FS + (size_t)(2 * pos + par) * AS + w0 + wl;
    store_m16(M + ((size_t)b * 65536 + p) * 32 + hf * 16, Mv);
}

// ---------------- unified passes kernel: logical blk<1024 -> W, <2048 -> H, else D ----------------
__global__ __launch_bounds__(256) void k_passes(const float* __restrict__ x, const double2* __restrict__ npart,
                                                __half* __restrict__ Mw, __half* __restrict__ Mh,
                                                __half* __restrict__ Md) {
    __shared__ __align__(16) float L[4128];
    __shared__ double ls[4], lq[4], thrs[2];
    __shared__ float fb[8];
    int t = threadIdx.x;
    thr_reduce(npart, thrs, fb, ls, lq, t);
    int blk = (blockIdx.x & 7) * 384 + (blockIdx.x >> 3);   // bijective XCD swizzle (3072 = 8*384)
    if (blk < 1024) {
        // ---- W-axis: 4 rings (2 lines x 2 parities); one wave per ring ----
#pragma unroll
        for (int it = 0; it < 4; ++it) {
            int f = it * 256 + t;
            int ll = f >> 9;
            int l = blk * 2 + ll;
            int c = (f >> 4) & 31, wq = f & 15;
            const float* lb = x + (size_t)(l >> 10) * CDHW_ + ((l >> 5) & 31) * HW_ + (l & 31) * W_;
            float4 v = *(const float4*)(lb + (size_t)c * DHW_ + wq * 4);
            int cq = c >> 2, cr = c & 3;
            const float* ve = (const float*)&v;
#pragma unroll
            for (int e = 0; e < 4; ++e) {
                int wv2 = wq * 4 + e;
                int p = wv2 >> 1, par = wv2 & 1;
                L[(ll * 2 + par) * 1024 + p * 32 + (((cq ^ (p & 7)) << 2) | cr)] = ve[e];
            }
        }
        __syncthreads();
        int ring = t >> 6, ln = t & 63;
        int pos = ln >> 1, hf = ln & 1;
        int ll = ring >> 1, par = ring & 1;
        int l = blk * 2 + ll;
        int b = l >> 10, d = (l >> 5) & 31, h = l & 31;
        double thr = thrs[b];
        float tlo = fb[b*4], thi = fb[b*4+1], tmf = fb[b*4+2];
        const float* Lr = L + ring * 1024;
        int qb = hf * 4;
        float col[16], nb[16];
#pragma unroll
        for (int k = 0; k < 4; ++k) {
            float4 cv = *(const float4*)(Lr + pos * 32 + (((qb + k) ^ (pos & 7)) << 2));
            col[4*k] = cv.x; col[4*k+1] = cv.y; col[4*k+2] = cv.z; col[4*k+3] = cv.w;
        }
        unsigned fmask = 0, bmask = 0;
#pragma unroll 1
        for (int s = 1; s <= 16; ++s) {              // forward (incl s=16 self-pair): dist + mask only
            int jf = (pos - s) & 31;
            LOAD_NB(Lr, jf);
            float dh = dist16(col, nb);
            float ds = dh + __shfl_xor(dh, 1, 64);   // half partner = ln^1, same value both lanes
            fmask |= (unsigned)(ds < tmf) << s;
            bmask |= (unsigned)((ds >= tlo) & (ds <= thi)) << s;
        }
        if (__ballot(bmask != 0)) {                  // rare fp64 fixup, wave-uniform
#pragma unroll 1
            for (int s = 1; s <= 16; ++s) {
                if (__ballot((bmask >> s) & 1)) {
                    int jf = (pos - s) & 31;
                    LOAD_NB(Lr, jf);
                    double d64h = 0.0;
#pragma unroll
                    for (int c = 0; c < 16; ++c) d64h += fabs((double)col[c] - (double)nb[c]);
                    double other = __shfl_xor(d64h, 1, 64);
                    unsigned cc = (unsigned)((d64h + other) < thr);
                    if ((bmask >> s) & 1) fmask = (fmask & ~(1u << s)) | (cc << s);
                }
            }
        }
        unsigned rmask = 0;                          // reverse rs=32-s from partner's bit s
#pragma unroll 1
        for (int s = 1; s <= 15; ++s) {
            int pl2 = (((pos + s) & 31) << 1) + hf;  // partner lane (same half, pos+s)
            rmask |= (unsigned)((__shfl((int)fmask, pl2, 64) >> s) & 1) << (32 - s);
        }
        float Mv[16];
#pragma unroll
        for (int c = 0; c < 16; ++c) Mv[c] = col[c];
        unsigned allm = (fmask & 0x1FFFEu) | rmask;  // bits 1..16 fwd, 17..31 rev
        while (allm) {                               // lazy merge of SELECTED shifts only
            int s = __ffs(allm) - 1;
            allm &= allm - 1;
            int jj = (pos - s) & 31;
            LOAD_NB(Lr, jj);
#pragma unroll
            for (int c = 0; c < 16; ++c) Mv[c] = fmaxf(Mv[c], nb[c]);
        }
        size_t ppt = (size_t)d * HW_ + h * W_ + 2 * pos + par;
        store_m16(Mw + ((size_t)b * 65536 + ppt) * 32 + hf * 16, Mv);
    } else if (blk < 2048) {
        hd_ring<W_, HW_>(x, Mh, thrs, fb, L, blk - 1024, t);   // H pass (F = d)
    } else {
        hd_ring<HW_, W_>(x, Md, thrs, fb, L, blk - 2048, t);   // D pass (F = h)
    }
}

// ---------------- conv (64->32) + fused BN partial stats; fp16 M, max3 inline ----------------
__global__ __launch_bounds__(256, 4) void k_conv(const float* __restrict__ x,
                                                 const __half* __restrict__ Mw, const __half* __restrict__ Mh,
                                                 const __half* __restrict__ Md,
                                                 const float* __restrict__ w, const float* __restrict__ bias,
                                                 float* __restrict__ y, float2* __restrict__ spart) {
    int t = threadIdx.x;
    int blk = (blockIdx.x & 7) * 256 + (blockIdx.x >> 3);   // bijective XCD swizzle (2048 = 8*256)
    int b = blk >> 10;
    int p0 = (blk & 1023) * 64;
    int og = __builtin_amdgcn_readfirstlane(t >> 6);
    int pl = t & 63;
    const float* xb = x + (size_t)b * CDHW_ + p0 + pl;
    size_t moff = ((size_t)b * 65536 + p0 + pl) * 32;
    const int4* mw4 = (const int4*)(Mw + moff);
    const int4* mh4 = (const int4*)(Mh + moff);
    const int4* md4 = (const int4*)(Md + moff);
    const float* wo = w + og * 512;
    const float* bo = bias + og * 8;
    float a[8], xv[32];
#pragma unroll
    for (int k = 0; k < 8; ++k) a[k] = bo[k];
#pragma unroll
    for (int c = 0; c < 32; c += 4) {
        xv[c+0] = xb[(size_t)(c+0) * DHW_];
        xv[c+1] = xb[(size_t)(c+1) * DHW_];
        xv[c+2] = xb[(size_t)(c+2) * DHW_];
        xv[c+3] = xb[(size_t)(c+3) * DHW_];
#pragma unroll
        for (int k = 0; k < 8; ++k) {
            a[k] = fmaf(wo[k*64 + c+0], xv[c+0], a[k]);
            a[k] = fmaf(wo[k*64 + c+1], xv[c+1], a[k]);
            a[k] = fmaf(wo[k*64 + c+2], xv[c+2], a[k]);
            a[k] = fmaf(wo[k*64 + c+3], xv[c+3], a[k]);
        }
    }
#pragma unroll
    for (int i = 0; i < 4; ++i) {                    // 8 channels per int4 (fp16-packed)
        int4 aw = mw4[i], ah = mh4[i], ad = md4[i];
        const __half2* hw = (const __half2*)&aw;
        const __half2* hh = (const __half2*)&ah;
        const __half2* hd = (const __half2*)&ad;
#pragma unroll
        for (int j = 0; j < 4; ++j) {
            float2 fw = __half22float2(hw[j]);
            float2 fh = __half22float2(hh[j]);
            float2 fd = __half22float2(hd[j]);
            int c = i * 8 + j * 2;
            float z0 = fmaxf(fmaxf(fmaxf(fw.x, fh.x), fd.x) - xv[c+0], 0.f);
            float z1 = fmaxf(fmaxf(fmaxf(fw.y, fh.y), fd.y) - xv[c+1], 0.f);
#pragma unroll
            for (int k = 0; k < 8; ++k) {
                a[k] = fmaf(wo[k*64 + 32 + c+0], z0, a[k]);
                a[k] = fmaf(wo[k*64 + 32 + c+1], z1, a[k]);
            }
        }
    }
    float* yb = y + (size_t)b * CDHW_ + p0 + pl;
#pragma unroll
    for (int k = 0; k < 8; ++k) {
        yb[(size_t)(og * 8 + k) * DHW_] = a[k];
        float s = a[k], q = a[k] * a[k];
        for (int off = 32; off; off >>= 1) {
            s += __shfl_down(s, off, 64);
            q += __shfl_down(q, off, 64);
        }
        if (pl == 0) spart[(og * 8 + k) * 2048 + blk] = make_float2(s, q);
    }
}

// ---------------- BN finalize + exact GELU, in-place ----------------
__global__ __launch_bounds__(256) void k_out(float* __restrict__ y, const float2* __restrict__ spart,
                                             const float* __restrict__ gamma, const float* __restrict__ beta) {
    int t = threadIdx.x;
    int o = (blockIdx.x >> 6) & 31;                  // block-uniform channel
    __shared__ double ls[4], lq[4];
    __shared__ float bnp[2];
    {
        const float2* sp = spart + o * 2048;
        double s = 0.0, q = 0.0;
#pragma unroll
        for (int i = 0; i < 8; ++i) {
            float2 v = sp[i * 256 + t];
            s += (double)v.x; q += (double)v.y;
        }
        for (int off = 32; off; off >>= 1) {
            s += __shfl_down(s, off, 64);
            q += __shfl_down(q, off, 64);
        }
        if ((t & 63) == 0) { ls[t >> 6] = s; lq[t >> 6] = q; }
    }
    __syncthreads();
    if (t == 0) {
        double sm = (ls[0] + ls[1]) + (ls[2] + ls[3]);
        double sq = (lq[0] + lq[1]) + (lq[2] + lq[3]);
        double mu = sm / (double)BN_N_;
        double var = sq / (double)BN_N_ - mu * mu;
        bnp[0] = (float)mu;
        bnp[1] = (float)(1.0 / sqrt(var + 1e-5));
    }
    __syncthreads();
    float mu_f = bnp[0], rstd = bnp[1];
    float g = gamma[o], be = beta[o];
    int idx = blockIdx.x * 256 + t;                  // over 1,048,576 float4
    float4 v = ((const float4*)y)[idx];
    float* vv = (float*)&v;
#pragma unroll
    for (int j = 0; j < 4; ++j) {
        float tt = (vv[j] - mu_f) * rstd * g + be;
        vv[j] = 0.5f * tt * (1.f + erff(tt * 0.70710678118654752f));
    }
    ((float4*)y)[idx] = v;
}

extern "C" void kernel_launch(void* const* d_in, const int* in_sizes, int n_in,
                              void* d_out, int out_size, void* d_ws, size_t ws_size,
                              hipStream_t stream) {
    const float* x     = (const float*)d_in[0];
    const float* w     = (const float*)d_in[1];
    const float* bias  = (const float*)d_in[2];
    const float* gamma = (const float*)d_in[3];
    const float* beta  = (const float*)d_in[4];
    float* out = (float*)d_out;
    __half* Mw = (__half*)d_ws;
    __half* Mh = (__half*)((char*)d_ws + MH_OFF);
    __half* Md = (__half*)((char*)d_ws + MD_OFF);
    double2* npart = (double2*)((char*)d_ws + RED_OFF + 256);
    float2*  spart = (float2*)((char*)d_ws + RED_OFF + 256 + 16384);

    k_norm  <<<512, 256, 0, stream>>>(x, npart);
    k_passes<<<3072, 256, 0, stream>>>(x, npart, Mw, Mh, Md);
    k_conv  <<<2048, 256, 0, stream>>>(x, Mw, Mh, Md, w, bias, out, spart);
    k_out   <<<4096, 256, 0, stream>>>(out, spart, gamma, beta);
}

// Round 16
// 98.962 us; speedup vs baseline: 1.1876x; 1.0139x over previous
//
#include <hip/hip_runtime.h>
#include <hip/hip_fp16.h>
#include <math.h>

#define B_ 2
#define C_ 32
#define D_ 32
#define H_ 32
#define W_ 64
#define HW_ (H_*W_)         // 2048
#define DHW_ (D_*H_*W_)     // 65536
#define CDHW_ (C_*DHW_)     // 2097152
#define NSP_ DHW_           // spatial points per batch
#define BN_N_ (B_*DHW_)     // 131072
#define BORDER 1e-3
#define RS 516              // padded LDS ring stride (floats)

// ws layout (fp16 M): Mw @0 (8MB), Mh @8MB, Md @16MB  — each [b][p][c] __half.
// reduction @48MB: npart[512] double2 @ +256, spart[32][2048] float2 @ +256+16384.
#define MH_OFF  (8u<<20)
#define MD_OFF  (16u<<20)
#define RED_OFF (48u<<20)

// lane^1 exchange on the VALU (DPP quad_perm [1,0,3,2]) — no LDS pipe, no latency.
__device__ __forceinline__ float xor1_f(float v) {
#if __has_builtin(__builtin_amdgcn_mov_dpp)
    return __int_as_float(__builtin_amdgcn_mov_dpp(__float_as_int(v), 0xB1, 0xF, 0xF, true));
#else
    return __shfl_xor(v, 1, 64);
#endif
}

// ---------------- threshold stats: involution-halved (only d<16; norm[p]==norm[pf] exactly) ----------------
__global__ __launch_bounds__(256) void k_norm(const float* __restrict__ x, double2* __restrict__ npart) {
    int tid = blockIdx.x * 256 + threadIdx.x;       // 131072 threads
    int ln = threadIdx.x & 63;
    int hf = ln >> 5, lp = ln & 31;
    int ph = (tid >> 6) * 32 + lp;                  // 0..65535 half-space points (2x lane coverage)
    int b = ph >> 15;
    int pp = ph & 32767;                            // (d<<11)|(h<<6)|w with d in 0..15
    int d = pp >> 11, h = (pp >> 6) & 31, w = pp & 63;
    int pf = ((d ^ 16) << 11) | ((h ^ 16) << 6) | (w ^ 32);
    const float* xb = x + (size_t)b * CDHW_ + (size_t)hf * 16 * DHW_;
    double s = 0.0;
#pragma unroll
    for (int c = 0; c < 16; ++c) {
        float a  = xb[c * DHW_ + pp];
        float bb = xb[c * DHW_ + pf];
        s += fabs((double)a - (double)bb);
    }
    double st = s + __shfl_xor(s, 32, 64);          // full 32-ch sum (both halves hold it)
    double s2 = st * st;
    for (int off = 32; off; off >>= 1) {
        st += __shfl_down(st, off, 64);
        s2 += __shfl_down(s2, off, 64);
    }
    __shared__ double ls[4], ls2[4];
    int wv = threadIdx.x >> 6;
    if (ln == 0) { ls[wv] = st; ls2[wv] = s2; }
    __syncthreads();
    if (threadIdx.x == 0) {
        double2 o;                                   // 2-lane dup == involution doubling
        o.x = (ls[0] + ls[1]) + (ls[2] + ls[3]);
        o.y = (ls2[0] + ls2[1]) + (ls2[2] + ls2[3]);
        npart[blockIdx.x] = o;
    }
}

// ---------------- per-block redundant thr reduce + f32 gate bounds ----------------
__device__ __forceinline__ void thr_reduce(const double2* __restrict__ npart, double* thrs, float* fb,
                                           double* ls, double* lq, int t) {
    {
        double s = 0.0, q = 0.0;
#pragma unroll
        for (int i = 0; i < 2; ++i) {
            double2 v = npart[t * 2 + i];
            s += v.x; q += v.y;
        }
        for (int off = 32; off; off >>= 1) {
            s += __shfl_down(s, off, 64);
            q += __shfl_down(q, off, 64);
        }
        if ((t & 63) == 0) { ls[t >> 6] = s; lq[t >> 6] = q; }
    }
    __syncthreads();
    if (t < 2) {
        double sum = ls[2 * t] + ls[2 * t + 1];
        double sq  = lq[2 * t] + lq[2 * t + 1];
        double n = (double)NSP_;
        double mean = sum / n;
        double var = (sq - sum * sum / n) / (n - 1.0);   // ddof=1
        if (var < 0.0) var = 0.0;
        double thrv = mean - sqrt(var);
        thrs[t] = thrv;
        fb[t * 4 + 0] = (float)(thrv - BORDER * 1.01);
        fb[t * 4 + 1] = (float)(thrv + BORDER * 1.01);
        fb[t * 4 + 2] = (float)thrv;
    }
    __syncthreads();
}

__device__ __forceinline__ float dist16(const float* col, const float* nb) {
    float d0 = 0.f, d1 = 0.f, d2 = 0.f, d3 = 0.f;
#pragma unroll
    for (int c = 0; c < 16; c += 4) {
        d0 += fabsf(col[c+0] - nb[c+0]);
        d1 += fabsf(col[c+1] - nb[c+1]);
        d2 += fabsf(col[c+2] - nb[c+2]);
        d3 += fabsf(col[c+3] - nb[c+3]);
    }
    return (d0 + d1) + (d2 + d3);
}

__device__ __forceinline__ void store_m16(__half* mp, const float* Mv) {
    __half2 tmp[8];
#pragma unroll
    for (int k = 0; k < 8; ++k) tmp[k] = __floats2half2_rn(Mv[2*k], Mv[2*k+1]);
    *(int4*)mp       = *(int4*)&tmp[0];
    *(int4*)(mp + 8) = *(int4*)&tmp[4];
}

#define LOAD_NB(LRP, JJ) \
    { _Pragma("unroll") for (int k = 0; k < 4; ++k) { \
        float4 nv = *(const float4*)((LRP) + (JJ) * 32 + (((qb + k) ^ ((JJ) & 7)) << 2)); \
        nb[4*k] = nv.x; nb[4*k+1] = nv.y; nb[4*k+2] = nv.z; nb[4*k+3] = nv.w; } }

// H/D ring body. 256 threads, 8 rings (one parity). Forward loop: dist+mask only,
// DPP for lane^1 sum; partner bits gathered via ballot (no bpermute); merges lazy.
template<int AS, int FS>
__device__ __forceinline__ void hd_ring(const float* __restrict__ x, __half* __restrict__ M,
                                        const double* thrs, const float* fb, float* L, int local, int t) {
    int par = local & 1, wt = (local >> 1) & 7, F = (local >> 4) & 31, b = local >> 9;
    int w0 = wt * 8;
    double thr = thrs[b];
    float tlo = fb[b*4], thi = fb[b*4+1], tmf = fb[b*4+2];
    const float* xb = x + (size_t)b * CDHW_ + (size_t)F * FS + w0;
#pragma unroll
    for (int it = 0; it < 4; ++it) {
        int f = it * 256 + t;                        // 0..1023 float4s
        int c = f >> 5, rem = f & 31, j = rem >> 1, wq = rem & 1;
        float4 v = *(const float4*)(xb + (size_t)c * DHW_ + (size_t)(2 * j + par) * AS + wq * 4);
        int sl = (((c >> 2) ^ (j & 7)) << 2) + (c & 3);
        int rb = (wq * 4) * RS + j * 32 + sl;
        L[rb] = v.x; L[rb + RS] = v.y; L[rb + 2*RS] = v.z; L[rb + 3*RS] = v.w;
    }
    __syncthreads();
    int ln = t & 63, wave = t >> 6;
    int pos = ln >> 2, c2 = ln & 3;
    int wl = wave * 2 + (c2 >> 1), hf = c2 & 1;
    const float* Lr = L + wl * RS;
    int qb = hf * 4;
    float col[16], nb[16];
#pragma unroll
    for (int k = 0; k < 4; ++k) {
        float4 cv = *(const float4*)(Lr + pos * 32 + (((qb + k) ^ (pos & 7)) << 2));
        col[4*k] = cv.x; col[4*k+1] = cv.y; col[4*k+2] = cv.z; col[4*k+3] = cv.w;
    }
    unsigned fmask = 0, bmask = 0;
#pragma unroll 1
    for (int s = 1; s <= 8; ++s) {                   // forward: dist + mask bits only
        int jj = (pos - s) & 15;
        LOAD_NB(Lr, jj);
        float dh = dist16(col, nb);
        float ds = dh + xor1_f(dh);                  // DPP lane^1 — same value both paired lanes
        fmask |= (unsigned)(ds < tmf) << s;
        bmask |= (unsigned)((ds >= tlo) & (ds <= thi)) << s;
    }
    if (__ballot(bmask != 0)) {                      // rare fp64 fixup, wave-uniform
#pragma unroll 1
        for (int s = 1; s <= 8; ++s) {
            if (__ballot((bmask >> s) & 1)) {
                int jj = (pos - s) & 15;
                LOAD_NB(Lr, jj);
                double d64h = 0.0;
#pragma unroll
                for (int c = 0; c < 16; ++c) d64h += fabs((double)col[c] - (double)nb[c]);
                double other = __shfl_xor(d64h, 1, 64);
                unsigned cc = (unsigned)((d64h + other) < thr);
                if ((bmask >> s) & 1) fmask = (fmask & ~(1u << s)) | (cc << s);
            }
        }
    }
    unsigned rmask = 0;                              // reverse bits via ballot (no bpermute)
#pragma unroll 1
    for (int s = 9; s <= 15; ++s) {
        int kbit = 16 - s;
        unsigned long long bal = __ballot((fmask >> kbit) & 1);
        int pl = ((pos - s) & 15) * 4 + c2;          // partner lane (same wl/half, pos-s)
        rmask |= (unsigned)((bal >> pl) & 1ull) << s;
    }
    float Mv[16];
#pragma unroll
    for (int c = 0; c < 16; ++c) Mv[c] = col[c];
    unsigned allm = (fmask & 0x1FEu) | rmask;        // bits 1..8 fwd, 9..15 rev
    while (allm) {                                   // lazy merge of SELECTED shifts only
        int s = __ffs(allm) - 1;
        allm &= allm - 1;
        int jj = (pos - s) & 15;
        LOAD_NB(Lr, jj);
#pragma unroll
        for (int c = 0; c < 16; ++c) Mv[c] = fmaxf(Mv[c], nb[c]);
    }
    size_t p = (size_t)F * FS + (size_t)(2 * pos + par) * AS + w0 + wl;
    store_m16(M + ((size_t)b * 65536 + p) * 32 + hf * 16, Mv);
}

// ---------------- unified passes kernel: logical blk<1024 -> W, <2048 -> H, else D ----------------
__global__ __launch_bounds__(256) void k_passes(const float* __restrict__ x, const double2* __restrict__ npart,
                                                __half* __restrict__ Mw, __half* __restrict__ Mh,
                                                __half* __restrict__ Md) {
    __shared__ __align__(16) float L[4128];
    __shared__ double ls[4], lq[4], thrs[2];
    __shared__ float fb[8];
    int t = threadIdx.x;
    thr_reduce(npart, thrs, fb, ls, lq, t);
    int blk = (blockIdx.x & 7) * 384 + (blockIdx.x >> 3);   // bijective XCD swizzle (3072 = 8*384)
    if (blk < 1024) {
        // ---- W-axis: 4 rings (2 lines x 2 parities); one wave per ring ----
#pragma unroll
        for (int it = 0; it < 4; ++it) {
            int f = it * 256 + t;
            int ll = f >> 9;
            int l = blk * 2 + ll;
            int c = (f >> 4) & 31, wq = f & 15;
            const float* lb = x + (size_t)(l >> 10) * CDHW_ + ((l >> 5) & 31) * HW_ + (l & 31) * W_;
            float4 v = *(const float4*)(lb + (size_t)c * DHW_ + wq * 4);
            int cq = c >> 2, cr = c & 3;
            const float* ve = (const float*)&v;
#pragma unroll
            for (int e = 0; e < 4; ++e) {
                int wv2 = wq * 4 + e;
                int p = wv2 >> 1, par = wv2 & 1;
                L[(ll * 2 + par) * 1024 + p * 32 + (((cq ^ (p & 7)) << 2) | cr)] = ve[e];
            }
        }
        __syncthreads();
        int ring = t >> 6, ln = t & 63;
        int pos = ln >> 1, hf = ln & 1;
        int ll = ring >> 1, par = ring & 1;
        int l = blk * 2 + ll;
        int b = l >> 10, d = (l >> 5) & 31, h = l & 31;
        double thr = thrs[b];
        float tlo = fb[b*4], thi = fb[b*4+1], tmf = fb[b*4+2];
        const float* Lr = L + ring * 1024;
        int qb = hf * 4;
        float col[16], nb[16];
#pragma unroll
        for (int k = 0; k < 4; ++k) {
            float4 cv = *(const float4*)(Lr + pos * 32 + (((qb + k) ^ (pos & 7)) << 2));
            col[4*k] = cv.x; col[4*k+1] = cv.y; col[4*k+2] = cv.z; col[4*k+3] = cv.w;
        }
        unsigned fmask = 0, bmask = 0;
#pragma unroll 1
        for (int s = 1; s <= 16; ++s) {              // forward (incl s=16 self-pair): dist + mask only
            int jf = (pos - s) & 31;
            LOAD_NB(Lr, jf);
            float dh = dist16(col, nb);
            float ds = dh + xor1_f(dh);              // DPP lane^1 (= ln^1 half partner)
            fmask |= (unsigned)(ds < tmf) << s;
            bmask |= (unsigned)((ds >= tlo) & (ds <= thi)) << s;
        }
        if (__ballot(bmask != 0)) {                  // rare fp64 fixup, wave-uniform
#pragma unroll 1
            for (int s = 1; s <= 16; ++s) {
                if (__ballot((bmask >> s) & 1)) {
                    int jf = (pos - s) & 31;
                    LOAD_NB(Lr, jf);
                    double d64h = 0.0;
#pragma unroll
                    for (int c = 0; c < 16; ++c) d64h += fabs((double)col[c] - (double)nb[c]);
                    double other = __shfl_xor(d64h, 1, 64);
                    unsigned cc = (unsigned)((d64h + other) < thr);
                    if ((bmask >> s) & 1) fmask = (fmask & ~(1u << s)) | (cc << s);
                }
            }
        }
        unsigned rmask = 0;                          // reverse rs=32-s via ballot (no bpermute)
#pragma unroll 1
        for (int s = 1; s <= 15; ++s) {
            unsigned long long bal = __ballot((fmask >> s) & 1);
            int pl2 = (((pos + s) & 31) << 1) + hf;  // partner lane (same half, pos+s)
            rmask |= (unsigned)((bal >> pl2) & 1ull) << (32 - s);
        }
        float Mv[16];
#pragma unroll
        for (int c = 0; c < 16; ++c) Mv[c] = col[c];
        unsigned allm = (fmask & 0x1FFFEu) | rmask;  // bits 1..16 fwd, 17..31 rev
        while (allm) {                               // lazy merge of SELECTED shifts only
            int s = __ffs(allm) - 1;
            allm &= allm - 1;
            int jj = (pos - s) & 31;
            LOAD_NB(Lr, jj);
#pragma unroll
            for (int c = 0; c < 16; ++c) Mv[c] = fmaxf(Mv[c], nb[c]);
        }
        size_t ppt = (size_t)d * HW_ + h * W_ + 2 * pos + par;
        store_m16(Mw + ((size_t)b * 65536 + ppt) * 32 + hf * 16, Mv);
    } else if (blk < 2048) {
        hd_ring<W_, HW_>(x, Mh, thrs, fb, L, blk - 1024, t);   // H pass (F = d)
    } else {
        hd_ring<HW_, W_>(x, Md, thrs, fb, L, blk - 2048, t);   // D pass (F = h)
    }
}

// ---------------- conv (64->32) + fused BN partial stats; fp16 M, max3 inline ----------------
__global__ __launch_bounds__(256, 4) void k_conv(const float* __restrict__ x,
                                                 const __half* __restrict__ Mw, const __half* __restrict__ Mh,
                                                 const __half* __restrict__ Md,
                                                 const float* __restrict__ w, const float* __restrict__ bias,
                                                 float* __restrict__ y, float2* __restrict__ spart) {
    int t = threadIdx.x;
    int blk = (blockIdx.x & 7) * 256 + (blockIdx.x >> 3);   // bijective XCD swizzle (2048 = 8*256)
    int b = blk >> 10;
    int p0 = (blk & 1023) * 64;
    int og = __builtin_amdgcn_readfirstlane(t >> 6);
    int pl = t & 63;
    const float* xb = x + (size_t)b * CDHW_ + p0 + pl;
    size_t moff = ((size_t)b * 65536 + p0 + pl) * 32;
    const int4* mw4 = (const int4*)(Mw + moff);
    const int4* mh4 = (const int4*)(Mh + moff);
    const int4* md4 = (const int4*)(Md + moff);
    const float* wo = w + og * 512;
    const float* bo = bias + og * 8;
    float a[8], xv[32];
#pragma unroll
    for (int k = 0; k < 8; ++k) a[k] = bo[k];
#pragma unroll
    for (int c = 0; c < 32; c += 4) {
        xv[c+0] = xb[(size_t)(c+0) * DHW_];
        xv[c+1] = xb[(size_t)(c+1) * DHW_];
        xv[c+2] = xb[(size_t)(c+2) * DHW_];
        xv[c+3] = xb[(size_t)(c+3) * DHW_];
#pragma unroll
        for (int k = 0; k < 8; ++k) {
            a[k] = fmaf(wo[k*64 + c+0], xv[c+0], a[k]);
            a[k] = fmaf(wo[k*64 + c+1], xv[c+1], a[k]);
            a[k] = fmaf(wo[k*64 + c+2], xv[c+2], a[k]);
            a[k] = fmaf(wo[k*64 + c+3], xv[c+3], a[k]);
        }
    }
#pragma unroll
    for (int i = 0; i < 4; ++i) {                    // 8 channels per int4 (fp16-packed)
        int4 aw = mw4[i], ah = mh4[i], ad = md4[i];
        const __half2* hw = (const __half2*)&aw;
        const __half2* hh = (const __half2*)&ah;
        const __half2* hd = (const __half2*)&ad;
#pragma unroll
        for (int j = 0; j < 4; ++j) {
            float2 fw = __half22float2(hw[j]);
            float2 fh = __half22float2(hh[j]);
            float2 fd = __half22float2(hd[j]);
            int c = i * 8 + j * 2;
            float z0 = fmaxf(fmaxf(fmaxf(fw.x, fh.x), fd.x) - xv[c+0], 0.f);
            float z1 = fmaxf(fmaxf(fmaxf(fw.y, fh.y), fd.y) - xv[c+1], 0.f);
#pragma unroll
            for (int k = 0; k < 8; ++k) {
                a[k] = fmaf(wo[k*64 + 32 + c+0], z0, a[k]);
                a[k] = fmaf(wo[k*64 + 32 + c+1], z1, a[k]);
            }
        }
    }
    float* yb = y + (size_t)b * CDHW_ + p0 + pl;
#pragma unroll
    for (int k = 0; k < 8; ++k) {
        yb[(size_t)(og * 8 + k) * DHW_] = a[k];
        float s = a[k], q = a[k] * a[k];
        for (int off = 32; off; off >>= 1) {
            s += __shfl_down(s, off, 64);
            q += __shfl_down(q, off, 64);
        }
        if (pl == 0) spart[(og * 8 + k) * 2048 + blk] = make_float2(s, q);
    }
}

// ---------------- BN finalize + exact GELU, in-place ----------------
__global__ __launch_bounds__(256) void k_out(float* __restrict__ y, const float2* __restrict__ spart,
                                             const float* __restrict__ gamma, const float* __restrict__ beta) {
    int t = threadIdx.x;
    int o = (blockIdx.x >> 6) & 31;                  // block-uniform channel
    __shared__ double ls[4], lq[4];
    __shared__ float bnp[2];
    {
        const float2* sp = spart + o * 2048;
        double s = 0.0, q = 0.0;
#pragma unroll
        for (int i = 0; i < 8; ++i) {
            float2 v = sp[i * 256 + t];
            s += (double)v.x; q += (double)v.y;
        }
        for (int off = 32; off; off >>= 1) {
            s += __shfl_down(s, off, 64);
            q += __shfl_down(q, off, 64);
        }
        if ((t & 63) == 0) { ls[t >> 6] = s; lq[t >> 6] = q; }
    }
    __syncthreads();
    if (t == 0) {
        double sm = (ls[0] + ls[1]) + (ls[2] + ls[3]);
        double sq = (lq[0] + lq[1]) + (lq[2] + lq[3]);
        double mu = sm / (double)BN_N_;
        double var = sq / (double)BN_N_ - mu * mu;
        bnp[0] = (float)mu;
        bnp[1] = (float)(1.0 / sqrt(var + 1e-5));
    }
    __syncthreads();
    float mu_f = bnp[0], rstd = bnp[1];
    float g = gamma[o], be = beta[o];
    int idx = blockIdx.x * 256 + t;                  // over 1,048,576 float4
    float4 v = ((const float4*)y)[idx];
    float* vv = (float*)&v;
#pragma unroll
    for (int j = 0; j < 4; ++j) {
        float tt = (vv[j] - mu_f) * rstd * g + be;
        vv[j] = 0.5f * tt * (1.f + erff(tt * 0.70710678118654752f));
    }
    ((float4*)y)[idx] = v;
}

extern "C" void kernel_launch(void* const* d_in, const int* in_sizes, int n_in,
                              void* d_out, int out_size, void* d_ws, size_t ws_size,
                              hipStream_t stream) {
    const float* x     = (const float*)d_in[0];
    const float* w     = (const float*)d_in[1];
    const float* bias  = (const float*)d_in[2];
    const float* gamma = (const float*)d_in[3];
    const float* beta  = (const float*)d_in[4];
    float* out = (float*)d_out;
    __half* Mw = (__half*)d_ws;
    __half* Mh = (__half*)((char*)d_ws + MH_OFF);
    __half* Md = (__half*)((char*)d_ws + MD_OFF);
    double2* npart = (double2*)((char*)d_ws + RED_OFF + 256);
    float2*  spart = (float2*)((char*)d_ws + RED_OFF + 256 + 16384);

    k_norm  <<<512, 256, 0, stream>>>(x, npart);
    k_passes<<<3072, 256, 0, stream>>>(x, npart, Mw, Mh, Md);
    k_conv  <<<2048, 256, 0, stream>>>(x, Mw, Mh, Md, w, bias, out, spart);
    k_out   <<<4096, 256, 0, stream>>>(out, spart, gamma, beta);
}

// Round 17
// 93.235 us; speedup vs baseline: 1.2605x; 1.0614x over previous
//
#include <hip/hip_runtime.h>
#include <hip/hip_fp16.h>
#include <math.h>

#define B_ 2
#define C_ 32
#define D_ 32
#define H_ 32
#define W_ 64
#define HW_ (H_*W_)         // 2048
#define DHW_ (D_*H_*W_)     // 65536
#define CDHW_ (C_*DHW_)     // 2097152
#define NSP_ DHW_           // spatial points per batch
#define BN_N_ (B_*DHW_)     // 131072
#define BORDER 1e-3
#define RS 516              // padded LDS ring stride (floats)

// ws layout (fp16 M): Mw @0 (8MB), Mh @8MB, Md @16MB  — each [b][p][c] __half.
// reduction @48MB: npart[512] double2 @ +256, spart[32][2048] float2 @ +256+16384.
#define MH_OFF  (8u<<20)
#define MD_OFF  (16u<<20)
#define RED_OFF (48u<<20)

// lane^1 exchange on the VALU (DPP quad_perm [1,0,3,2]) — no LDS pipe, no latency.
__device__ __forceinline__ float xor1_f(float v) {
#if __has_builtin(__builtin_amdgcn_mov_dpp)
    return __int_as_float(__builtin_amdgcn_mov_dpp(__float_as_int(v), 0xB1, 0xF, 0xF, true));
#else
    return __shfl_xor(v, 1, 64);
#endif
}

// ---------------- threshold stats: involution-halved (only d<16; norm[p]==norm[pf] exactly) ----------------
__global__ __launch_bounds__(256) void k_norm(const float* __restrict__ x, double2* __restrict__ npart) {
    int tid = blockIdx.x * 256 + threadIdx.x;       // 131072 threads
    int ln = threadIdx.x & 63;
    int hf = ln >> 5, lp = ln & 31;
    int ph = (tid >> 6) * 32 + lp;                  // 0..65535 half-space points (2x lane coverage)
    int b = ph >> 15;
    int pp = ph & 32767;                            // (d<<11)|(h<<6)|w with d in 0..15
    int d = pp >> 11, h = (pp >> 6) & 31, w = pp & 63;
    int pf = ((d ^ 16) << 11) | ((h ^ 16) << 6) | (w ^ 32);
    const float* xb = x + (size_t)b * CDHW_ + (size_t)hf * 16 * DHW_;
    double s = 0.0;
#pragma unroll
    for (int c = 0; c < 16; ++c) {
        float a  = xb[c * DHW_ + pp];
        float bb = xb[c * DHW_ + pf];
        s += fabs((double)a - (double)bb);
    }
    double st = s + __shfl_xor(s, 32, 64);          // full 32-ch sum (both halves hold it)
    double s2 = st * st;
    for (int off = 32; off; off >>= 1) {
        st += __shfl_down(st, off, 64);
        s2 += __shfl_down(s2, off, 64);
    }
    __shared__ double ls[4], ls2[4];
    int wv = threadIdx.x >> 6;
    if (ln == 0) { ls[wv] = st; ls2[wv] = s2; }
    __syncthreads();
    if (threadIdx.x == 0) {
        double2 o;                                   // 2-lane dup == involution doubling
        o.x = (ls[0] + ls[1]) + (ls[2] + ls[3]);
        o.y = (ls2[0] + ls2[1]) + (ls2[2] + ls2[3]);
        npart[blockIdx.x] = o;
    }
}

// ---------------- per-block redundant thr reduce + f32 gate bounds ----------------
__device__ __forceinline__ void thr_reduce(const double2* __restrict__ npart, double* thrs, float* fb,
                                           double* ls, double* lq, int t) {
    {
        double s = 0.0, q = 0.0;
#pragma unroll
        for (int i = 0; i < 2; ++i) {
            double2 v = npart[t * 2 + i];
            s += v.x; q += v.y;
        }
        for (int off = 32; off; off >>= 1) {
            s += __shfl_down(s, off, 64);
            q += __shfl_down(q, off, 64);
        }
        if ((t & 63) == 0) { ls[t >> 6] = s; lq[t >> 6] = q; }
    }
    __syncthreads();
    if (t < 2) {
        double sum = ls[2 * t] + ls[2 * t + 1];
        double sq  = lq[2 * t] + lq[2 * t + 1];
        double n = (double)NSP_;
        double mean = sum / n;
        double var = (sq - sum * sum / n) / (n - 1.0);   // ddof=1
        if (var < 0.0) var = 0.0;
        double thrv = mean - sqrt(var);
        thrs[t] = thrv;
        fb[t * 4 + 0] = (float)(thrv - BORDER * 1.01);
        fb[t * 4 + 1] = (float)(thrv + BORDER * 1.01);
        fb[t * 4 + 2] = (float)thrv;
    }
    __syncthreads();
}

__device__ __forceinline__ float dist16(const float* col, const float* nb) {
    float d0 = 0.f, d1 = 0.f, d2 = 0.f, d3 = 0.f;
#pragma unroll
    for (int c = 0; c < 16; c += 4) {
        d0 += fabsf(col[c+0] - nb[c+0]);
        d1 += fabsf(col[c+1] - nb[c+1]);
        d2 += fabsf(col[c+2] - nb[c+2]);
        d3 += fabsf(col[c+3] - nb[c+3]);
    }
    return (d0 + d1) + (d2 + d3);
}

__device__ __forceinline__ void store_m16(__half* mp, const float* Mv) {
    __half2 tmp[8];
#pragma unroll
    for (int k = 0; k < 8; ++k) tmp[k] = __floats2half2_rn(Mv[2*k], Mv[2*k+1]);
    *(int4*)mp       = *(int4*)&tmp[0];
    *(int4*)(mp + 8) = *(int4*)&tmp[4];
}

#define LOAD_NB(LRP, JJ) \
    { _Pragma("unroll") for (int k = 0; k < 4; ++k) { \
        float4 nv = *(const float4*)((LRP) + (JJ) * 32 + (((qb + k) ^ ((JJ) & 7)) << 2)); \
        nb[4*k] = nv.x; nb[4*k+1] = nv.y; nb[4*k+2] = nv.z; nb[4*k+3] = nv.w; } }

// W-pass hash: include high pos bits so pos, pos+8, pos+16, pos+24 get distinct slots.
#define WSLOT(JJ) (((JJ) + ((JJ) >> 3)) & 7)
#define LOAD_NBW(LRP, JJ) \
    { _Pragma("unroll") for (int k = 0; k < 4; ++k) { \
        float4 nv = *(const float4*)((LRP) + (JJ) * 32 + (((qb + k) ^ WSLOT(JJ)) << 2)); \
        nb[4*k] = nv.x; nb[4*k+1] = nv.y; nb[4*k+2] = nv.z; nb[4*k+3] = nv.w; } }

// H/D ring body. 256 threads, 8 rings (one parity). Forward loop: dist+mask only,
// DPP for lane^1 sum; partner bits gathered via ballot; merges lazy.
template<int AS, int FS>
__device__ __forceinline__ void hd_ring(const float* __restrict__ x, __half* __restrict__ M,
                                        const double* thrs, const float* fb, float* L, int local, int t) {
    int par = local & 1, wt = (local >> 1) & 7, F = (local >> 4) & 31, b = local >> 9;
    int w0 = wt * 8;
    double thr = thrs[b];
    float tlo = fb[b*4], thi = fb[b*4+1], tmf = fb[b*4+2];
    const float* xb = x + (size_t)b * CDHW_ + (size_t)F * FS + w0;
#pragma unroll
    for (int it = 0; it < 4; ++it) {
        int f = it * 256 + t;                        // 0..1023 float4s
        int c = f >> 5, rem = f & 31, j = rem >> 1, wq = rem & 1;
        float4 v = *(const float4*)(xb + (size_t)c * DHW_ + (size_t)(2 * j + par) * AS + wq * 4);
        int sl = (((c >> 2) ^ (j & 7)) << 2) + (c & 3);
        int rb = (wq * 4) * RS + j * 32 + sl;
        L[rb] = v.x; L[rb + RS] = v.y; L[rb + 2*RS] = v.z; L[rb + 3*RS] = v.w;
    }
    __syncthreads();
    int ln = t & 63, wave = t >> 6;
    int pos = ln >> 2, c2 = ln & 3;
    int wl = wave * 2 + (c2 >> 1), hf = c2 & 1;
    const float* Lr = L + wl * RS;
    int qb = hf * 4;
    float col[16], nb[16];
#pragma unroll
    for (int k = 0; k < 4; ++k) {
        float4 cv = *(const float4*)(Lr + pos * 32 + (((qb + k) ^ (pos & 7)) << 2));
        col[4*k] = cv.x; col[4*k+1] = cv.y; col[4*k+2] = cv.z; col[4*k+3] = cv.w;
    }
    unsigned fmask = 0, bmask = 0;
#pragma unroll 1
    for (int s = 1; s <= 8; ++s) {                   // forward: dist + mask bits only
        int jj = (pos - s) & 15;
        LOAD_NB(Lr, jj);
        float dh = dist16(col, nb);
        float ds = dh + xor1_f(dh);                  // DPP lane^1 — same value both paired lanes
        fmask |= (unsigned)(ds < tmf) << s;
        bmask |= (unsigned)((ds >= tlo) & (ds <= thi)) << s;
    }
    if (__ballot(bmask != 0)) {                      // rare fp64 fixup, wave-uniform
#pragma unroll 1
        for (int s = 1; s <= 8; ++s) {
            if (__ballot((bmask >> s) & 1)) {
                int jj = (pos - s) & 15;
                LOAD_NB(Lr, jj);
                double d64h = 0.0;
#pragma unroll
                for (int c = 0; c < 16; ++c) d64h += fabs((double)col[c] - (double)nb[c]);
                double other = __shfl_xor(d64h, 1, 64);
                unsigned cc = (unsigned)((d64h + other) < thr);
                if ((bmask >> s) & 1) fmask = (fmask & ~(1u << s)) | (cc << s);
            }
        }
    }
    unsigned rmask = 0;                              // reverse bits via ballot (no bpermute)
#pragma unroll 1
    for (int s = 9; s <= 15; ++s) {
        int kbit = 16 - s;
        unsigned long long bal = __ballot((fmask >> kbit) & 1);
        int pl = ((pos - s) & 15) * 4 + c2;          // partner lane (same wl/half, pos-s)
        rmask |= (unsigned)((bal >> pl) & 1ull) << s;
    }
    float Mv[16];
#pragma unroll
    for (int c = 0; c < 16; ++c) Mv[c] = col[c];
    unsigned allm = (fmask & 0x1FEu) | rmask;        // bits 1..8 fwd, 9..15 rev
    while (allm) {                                   // lazy merge of SELECTED shifts only
        int s = __ffs(allm) - 1;
        allm &= allm - 1;
        int jj = (pos - s) & 15;
        LOAD_NB(Lr, jj);
#pragma unroll
        for (int c = 0; c < 16; ++c) Mv[c] = fmaxf(Mv[c], nb[c]);
    }
    size_t p = (size_t)F * FS + (size_t)(2 * pos + par) * AS + w0 + wl;
    store_m16(M + ((size_t)b * 65536 + p) * 32 + hf * 16, Mv);
}

// ---------------- unified passes kernel: type-striped (bid%3) for XCD balance ----------------
__global__ __launch_bounds__(256) void k_passes(const float* __restrict__ x, const double2* __restrict__ npart,
                                                __half* __restrict__ Mw, __half* __restrict__ Mh,
                                                __half* __restrict__ Md) {
    __shared__ __align__(16) float L[4128];
    __shared__ double ls[4], lq[4], thrs[2];
    __shared__ float fb[8];
    int t = threadIdx.x;
    thr_reduce(npart, thrs, fb, ls, lq, t);
    int type = blockIdx.x % 3;                       // W/H/D interleaved across XCDs (gcd(8,3)=1)
    int u = blockIdx.x / 3;                          // 0..1023
    if (type == 0) {
        // ---- W-axis: 4 rings (2 lines x 2 parities); one wave per ring ----
        int blk = u;
#pragma unroll
        for (int it = 0; it < 4; ++it) {
            int f = it * 256 + t;
            int ll = f >> 9;
            int l = blk * 2 + ll;
            int c = (f >> 4) & 31, wq = f & 15;
            const float* lb = x + (size_t)(l >> 10) * CDHW_ + ((l >> 5) & 31) * HW_ + (l & 31) * W_;
            float4 v = *(const float4*)(lb + (size_t)c * DHW_ + wq * 4);
            int cq = c >> 2, cr = c & 3;
            const float* ve = (const float*)&v;
#pragma unroll
            for (int e = 0; e < 4; ++e) {
                int wv2 = wq * 4 + e;
                int p = wv2 >> 1, par = wv2 & 1;
                L[(ll * 2 + par) * 1024 + p * 32 + (((cq ^ WSLOT(p)) << 2) | cr)] = ve[e];
            }
        }
        __syncthreads();
        int ring = t >> 6, ln = t & 63;
        int pos = ln >> 1, hf = ln & 1;
        int ll = ring >> 1, par = ring & 1;
        int l = blk * 2 + ll;
        int b = l >> 10, d = (l >> 5) & 31, h = l & 31;
        double thr = thrs[b];
        float tlo = fb[b*4], thi = fb[b*4+1], tmf = fb[b*4+2];
        const float* Lr = L + ring * 1024;
        int qb = hf * 4;
        float col[16], nb[16];
#pragma unroll
        for (int k = 0; k < 4; ++k) {
            float4 cv = *(const float4*)(Lr + pos * 32 + (((qb + k) ^ WSLOT(pos)) << 2));
            col[4*k] = cv.x; col[4*k+1] = cv.y; col[4*k+2] = cv.z; col[4*k+3] = cv.w;
        }
        unsigned fmask = 0, bmask = 0;
#pragma unroll 1
        for (int s = 1; s <= 16; ++s) {              // forward (incl s=16 self-pair): dist + mask only
            int jf = (pos - s) & 31;
            LOAD_NBW(Lr, jf);
            float dh = dist16(col, nb);
            float ds = dh + xor1_f(dh);              // DPP lane^1 (= ln^1 half partner)
            fmask |= (unsigned)(ds < tmf) << s;
            bmask |= (unsigned)((ds >= tlo) & (ds <= thi)) << s;
        }
        if (__ballot(bmask != 0)) {                  // rare fp64 fixup, wave-uniform
#pragma unroll 1
            for (int s = 1; s <= 16; ++s) {
                if (__ballot((bmask >> s) & 1)) {
                    int jf = (pos - s) & 31;
                    LOAD_NBW(Lr, jf);
                    double d64h = 0.0;
#pragma unroll
                    for (int c = 0; c < 16; ++c) d64h += fabs((double)col[c] - (double)nb[c]);
                    double other = __shfl_xor(d64h, 1, 64);
                    unsigned cc = (unsigned)((d64h + other) < thr);
                    if ((bmask >> s) & 1) fmask = (fmask & ~(1u << s)) | (cc << s);
                }
            }
        }
        unsigned rmask = 0;                          // reverse rs=32-s via ballot
#pragma unroll 1
        for (int s = 1; s <= 15; ++s) {
            unsigned long long bal = __ballot((fmask >> s) & 1);
            int pl2 = (((pos + s) & 31) << 1) + hf;  // partner lane (same half, pos+s)
            rmask |= (unsigned)((bal >> pl2) & 1ull) << (32 - s);
        }
        float Mv[16];
#pragma unroll
        for (int c = 0; c < 16; ++c) Mv[c] = col[c];
        unsigned allm = (fmask & 0x1FFFEu) | rmask;  // bits 1..16 fwd, 17..31 rev
        while (allm) {                               // lazy merge of SELECTED shifts only
            int s = __ffs(allm) - 1;
            allm &= allm - 1;
            int jj = (pos - s) & 31;
            LOAD_NBW(Lr, jj);
#pragma unroll
            for (int c = 0; c < 16; ++c) Mv[c] = fmaxf(Mv[c], nb[c]);
        }
        size_t ppt = (size_t)d * HW_ + h * W_ + 2 * pos + par;
        store_m16(Mw + ((size_t)b * 65536 + ppt) * 32 + hf * 16, Mv);
    } else if (type == 1) {
        hd_ring<W_, HW_>(x, Mh, thrs, fb, L, u, t);   // H pass (F = d)
    } else {
        hd_ring<HW_, W_>(x, Md, thrs, fb, L, u, t);   // D pass (F = h)
    }
}

// ---------------- conv (64->32) + fused BN partial stats; fp16 M, max3 inline ----------------
__global__ __launch_bounds__(256, 4) void k_conv(const float* __restrict__ x,
                                                 const __half* __restrict__ Mw, const __half* __restrict__ Mh,
                                                 const __half* __restrict__ Md,
                                                 const float* __restrict__ w, const float* __restrict__ bias,
                                                 float* __restrict__ y, float2* __restrict__ spart) {
    int t = threadIdx.x;
    int blk = (blockIdx.x & 7) * 256 + (blockIdx.x >> 3);   // bijective XCD swizzle (2048 = 8*256)
    int b = blk >> 10;
    int p0 = (blk & 1023) * 64;
    int og = __builtin_amdgcn_readfirstlane(t >> 6);
    int pl = t & 63;
    const float* xb = x + (size_t)b * CDHW_ + p0 + pl;
    size_t moff = ((size_t)b * 65536 + p0 + pl) * 32;
    const int4* mw4 = (const int4*)(Mw + moff);
    const int4* mh4 = (const int4*)(Mh + moff);
    const int4* md4 = (const int4*)(Md + moff);
    const float* wo = w + og * 512;
    const float* bo = bias + og * 8;
    float a[8], xv[32];
#pragma unroll
    for (int k = 0; k < 8; ++k) a[k] = bo[k];
#pragma unroll
    for (int c = 0; c < 32; c += 4) {
        xv[c+0] = xb[(size_t)(c+0) * DHW_];
        xv[c+1] = xb[(size_t)(c+1) * DHW_];
        xv[c+2] = xb[(size_t)(c+2) * DHW_];
        xv[c+3] = xb[(size_t)(c+3) * DHW_];
#pragma unroll
        for (int k = 0; k < 8; ++k) {
            a[k] = fmaf(wo[k*64 + c+0], xv[c+0], a[k]);
            a[k] = fmaf(wo[k*64 + c+1], xv[c+1], a[k]);
            a[k] = fmaf(wo[k*64 + c+2], xv[c+2], a[k]);
            a[k] = fmaf(wo[k*64 + c+3], xv[c+3], a[k]);
        }
    }
#pragma unroll
    for (int i = 0; i < 4; ++i) {                    // 8 channels per int4 (fp16-packed)
        int4 aw = mw4[i], ah = mh4[i], ad = md4[i];
        const __half2* hw = (const __half2*)&aw;
        const __half2* hh = (const __half2*)&ah;
        const __half2* hd = (const __half2*)&ad;
#pragma unroll
        for (int j = 0; j < 4; ++j) {
            float2 fw = __half22float2(hw[j]);
            float2 fh = __half22float2(hh[j]);
            float2 fd = __half22float2(hd[j]);
            int c = i * 8 + j * 2;
            float z0 = fmaxf(fmaxf(fmaxf(fw.x, fh.x), fd.x) - xv[c+0], 0.f);
            float z1 = fmaxf(fmaxf(fmaxf(fw.y, fh.y), fd.y) - xv[c+1], 0.f);
#pragma unroll
            for (int k = 0; k < 8; ++k) {
                a[k] = fmaf(wo[k*64 + 32 + c+0], z0, a[k]);
                a[k] = fmaf(wo[k*64 + 32 + c+1], z1, a[k]);
            }
        }
    }
    float* yb = y + (size_t)b * CDHW_ + p0 + pl;
#pragma unroll
    for (int k = 0; k < 8; ++k) {
        yb[(size_t)(og * 8 + k) * DHW_] = a[k];
        float s = a[k], q = a[k] * a[k];
        for (int off = 32; off; off >>= 1) {
            s += __shfl_down(s, off, 64);
            q += __shfl_down(q, off, 64);
        }
        if (pl == 0) spart[(og * 8 + k) * 2048 + blk] = make_float2(s, q);
    }
}

// ---------------- BN finalize + exact GELU, in-place ----------------
__global__ __launch_bounds__(256) void k_out(float* __restrict__ y, const float2* __restrict__ spart,
                                             const float* __restrict__ gamma, const float* __restrict__ beta) {
    int t = threadIdx.x;
    int o = (blockIdx.x >> 6) & 31;                  // block-uniform channel
    __shared__ double ls[4], lq[4];
    __shared__ float bnp[2];
    {
        const float2* sp = spart + o * 2048;
        double s = 0.0, q = 0.0;
#pragma unroll
        for (int i = 0; i < 8; ++i) {
            float2 v = sp[i * 256 + t];
            s += (double)v.x; q += (double)v.y;
        }
        for (int off = 32; off; off >>= 1) {
            s += __shfl_down(s, off, 64);
            q += __shfl_down(q, off, 64);
        }
        if ((t & 63) == 0) { ls[t >> 6] = s; lq[t >> 6] = q; }
    }
    __syncthreads();
    if (t == 0) {
        double sm = (ls[0] + ls[1]) + (ls[2] + ls[3]);
        double sq = (lq[0] + lq[1]) + (lq[2] + lq[3]);
        double mu = sm / (double)BN_N_;
        double var = sq / (double)BN_N_ - mu * mu;
        bnp[0] = (float)mu;
        bnp[1] = (float)(1.0 / sqrt(var + 1e-5));
    }
    __syncthreads();
    float mu_f = bnp[0], rstd = bnp[1];
    float g = gamma[o], be = beta[o];
    int idx = blockIdx.x * 256 + t;                  // over 1,048,576 float4
    float4 v = ((const float4*)y)[idx];
    float* vv = (float*)&v;
#pragma unroll
    for (int j = 0; j < 4; ++j) {
        float tt = (vv[j] - mu_f) * rstd * g + be;
        vv[j] = 0.5f * tt * (1.f + erff(tt * 0.70710678118654752f));
    }
    ((float4*)y)[idx] = v;
}

extern "C" void kernel_launch(void* const* d_in, const int* in_sizes, int n_in,
                              void* d_out, int out_size, void* d_ws, size_t ws_size,
                              hipStream_t stream) {
    const float* x     = (const float*)d_in[0];
    const float* w     = (const float*)d_in[1];
    const float* bias  = (const float*)d_in[2];
    const float* gamma = (const float*)d_in[3];
    const float* beta  = (const float*)d_in[4];
    float* out = (float*)d_out;
    __half* Mw = (__half*)d_ws;
    __half* Mh = (__half*)((char*)d_ws + MH_OFF);
    __half* Md = (__half*)((char*)d_ws + MD_OFF);
    double2* npart = (double2*)((char*)d_ws + RED_OFF + 256);
    float2*  spart = (float2*)((char*)d_ws + RED_OFF + 256 + 16384);

    k_norm  <<<512, 256, 0, stream>>>(x, npart);
    k_passes<<<3072, 256, 0, stream>>>(x, npart, Mw, Mh, Md);
    k_conv  <<<2048, 256, 0, stream>>>(x, Mw, Mh, Md, w, bias, out, spart);
    k_out   <<<4096, 256, 0, stream>>>(out, spart, gamma, beta);
}

// Round 18
// 86.112 us; speedup vs baseline: 1.3648x; 1.0827x over previous
//
#include <hip/hip_runtime.h>
#include <hip/hip_fp16.h>
#include <math.h>

#define B_ 2
#define C_ 32
#define D_ 32
#define H_ 32
#define W_ 64
#define HW_ (H_*W_)         // 2048
#define DHW_ (D_*H_*W_)     // 65536
#define CDHW_ (C_*DHW_)     // 2097152
#define NSP_ DHW_           // spatial points per batch
#define BN_N_ (B_*DHW_)     // 131072
#define BORDER 1e-3
#define RS 516              // padded LDS ring stride (floats)

// ws layout (fp16 M): Mw @0 (8MB), Mh @8MB, Md @16MB  — each [b][p][c] __half.
// reduction @48MB: npart[512] double2 @ +256, spart[32][2048] float2 @ +256+16384.
#define MH_OFF  (8u<<20)
#define MD_OFF  (16u<<20)
#define RED_OFF (48u<<20)

// lane^1 exchange on the VALU (DPP quad_perm [1,0,3,2]) — no LDS pipe, no latency.
__device__ __forceinline__ float xor1_f(float v) {
#if __has_builtin(__builtin_amdgcn_mov_dpp)
    return __int_as_float(__builtin_amdgcn_mov_dpp(__float_as_int(v), 0xB1, 0xF, 0xF, true));
#else
    return __shfl_xor(v, 1, 64);
#endif
}

// ---------------- threshold stats: involution-halved (only d<16; norm[p]==norm[pf] exactly) ----------------
__global__ __launch_bounds__(256) void k_norm(const float* __restrict__ x, double2* __restrict__ npart) {
    int tid = blockIdx.x * 256 + threadIdx.x;       // 131072 threads
    int ln = threadIdx.x & 63;
    int hf = ln >> 5, lp = ln & 31;
    int ph = (tid >> 6) * 32 + lp;                  // 0..65535 half-space points (2x lane coverage)
    int b = ph >> 15;
    int pp = ph & 32767;                            // (d<<11)|(h<<6)|w with d in 0..15
    int d = pp >> 11, h = (pp >> 6) & 31, w = pp & 63;
    int pf = ((d ^ 16) << 11) | ((h ^ 16) << 6) | (w ^ 32);
    const float* xb = x + (size_t)b * CDHW_ + (size_t)hf * 16 * DHW_;
    double s = 0.0;
#pragma unroll
    for (int c = 0; c < 16; ++c) {
        float a  = xb[c * DHW_ + pp];
        float bb = xb[c * DHW_ + pf];
        s += fabs((double)a - (double)bb);
    }
    double st = s + __shfl_xor(s, 32, 64);          // full 32-ch sum (both halves hold it)
    double s2 = st * st;
    for (int off = 32; off; off >>= 1) {
        st += __shfl_down(st, off, 64);
        s2 += __shfl_down(s2, off, 64);
    }
    __shared__ double ls[4], ls2[4];
    int wv = threadIdx.x >> 6;
    if (ln == 0) { ls[wv] = st; ls2[wv] = s2; }
    __syncthreads();
    if (threadIdx.x == 0) {
        double2 o;                                   // 2-lane dup == involution doubling
        o.x = (ls[0] + ls[1]) + (ls[2] + ls[3]);
        o.y = (ls2[0] + ls2[1]) + (ls2[2] + ls2[3]);
        npart[blockIdx.x] = o;
    }
}

// ---------------- per-block redundant thr reduce + f32 gate bounds ----------------
__device__ __forceinline__ void thr_reduce(const double2* __restrict__ npart, double* thrs, float* fb,
                                           double* ls, double* lq, int t) {
    {
        double s = 0.0, q = 0.0;
#pragma unroll
        for (int i = 0; i < 2; ++i) {
            double2 v = npart[t * 2 + i];
            s += v.x; q += v.y;
        }
        for (int off = 32; off; off >>= 1) {
            s += __shfl_down(s, off, 64);
            q += __shfl_down(q, off, 64);
        }
        if ((t & 63) == 0) { ls[t >> 6] = s; lq[t >> 6] = q; }
    }
    __syncthreads();
    if (t < 2) {
        double sum = ls[2 * t] + ls[2 * t + 1];
        double sq  = lq[2 * t] + lq[2 * t + 1];
        double n = (double)NSP_;
        double mean = sum / n;
        double var = (sq - sum * sum / n) / (n - 1.0);   // ddof=1
        if (var < 0.0) var = 0.0;
        double thrv = mean - sqrt(var);
        thrs[t] = thrv;
        fb[t * 4 + 0] = (float)(thrv - BORDER * 1.01);
        fb[t * 4 + 1] = (float)(thrv + BORDER * 1.01);
        fb[t * 4 + 2] = (float)thrv;
    }
    __syncthreads();
}

__device__ __forceinline__ float dist16(const float* col, const float* nb) {
    float d0 = 0.f, d1 = 0.f, d2 = 0.f, d3 = 0.f;
#pragma unroll
    for (int c = 0; c < 16; c += 4) {
        d0 += fabsf(col[c+0] - nb[c+0]);
        d1 += fabsf(col[c+1] - nb[c+1]);
        d2 += fabsf(col[c+2] - nb[c+2]);
        d3 += fabsf(col[c+3] - nb[c+3]);
    }
    return (d0 + d1) + (d2 + d3);
}

__device__ __forceinline__ void store_m16(__half* mp, const float* Mv) {
    __half2 tmp[8];
#pragma unroll
    for (int k = 0; k < 8; ++k) tmp[k] = __floats2half2_rn(Mv[2*k], Mv[2*k+1]);
    *(int4*)mp       = *(int4*)&tmp[0];
    *(int4*)(mp + 8) = *(int4*)&tmp[4];
}

#define LOAD_NB(LRP, JJ) \
    { _Pragma("unroll") for (int k = 0; k < 4; ++k) { \
        float4 nv = *(const float4*)((LRP) + (JJ) * 32 + (((qb + k) ^ ((JJ) & 7)) << 2)); \
        nb[4*k] = nv.x; nb[4*k+1] = nv.y; nb[4*k+2] = nv.z; nb[4*k+3] = nv.w; } }

// W-pass hash: include high pos bits so pos, pos+8, pos+16, pos+24 get distinct slots.
#define WSLOT(JJ) (((JJ) + ((JJ) >> 3)) & 7)
#define LOAD_NBW(LRP, JJ) \
    { _Pragma("unroll") for (int k = 0; k < 4; ++k) { \
        float4 nv = *(const float4*)((LRP) + (JJ) * 32 + (((qb + k) ^ WSLOT(JJ)) << 2)); \
        nb[4*k] = nv.x; nb[4*k+1] = nv.y; nb[4*k+2] = nv.z; nb[4*k+3] = nv.w; } }

// H/D ring body. 256 threads, 8 rings (one parity). Forward loop: dist+mask only,
// DPP for lane^1 sum; partner bits gathered via ballot; merges lazy.
template<int AS, int FS>
__device__ __forceinline__ void hd_ring(const float* __restrict__ x, __half* __restrict__ M,
                                        const double* thrs, const float* fb, float* L, int local, int t) {
    int par = local & 1, wt = (local >> 1) & 7, F = (local >> 4) & 31, b = local >> 9;
    int w0 = wt * 8;
    double thr = thrs[b];
    float tlo = fb[b*4], thi = fb[b*4+1], tmf = fb[b*4+2];
    const float* xb = x + (size_t)b * CDHW_ + (size_t)F * FS + w0;
#pragma unroll
    for (int it = 0; it < 4; ++it) {
        int f = it * 256 + t;                        // 0..1023 float4s
        int c = f >> 5, rem = f & 31, j = rem >> 1, wq = rem & 1;
        float4 v = *(const float4*)(xb + (size_t)c * DHW_ + (size_t)(2 * j + par) * AS + wq * 4);
        int sl = (((c >> 2) ^ (j & 7)) << 2) + (c & 3);
        int rb = (wq * 4) * RS + j * 32 + sl;
        L[rb] = v.x; L[rb + RS] = v.y; L[rb + 2*RS] = v.z; L[rb + 3*RS] = v.w;
    }
    __syncthreads();
    int ln = t & 63, wave = t >> 6;
    int pos = ln >> 2, c2 = ln & 3;
    int wl = wave * 2 + (c2 >> 1), hf = c2 & 1;
    const float* Lr = L + wl * RS;
    int qb = hf * 4;
    float col[16], nb[16];
#pragma unroll
    for (int k = 0; k < 4; ++k) {
        float4 cv = *(const float4*)(Lr + pos * 32 + (((qb + k) ^ (pos & 7)) << 2));
        col[4*k] = cv.x; col[4*k+1] = cv.y; col[4*k+2] = cv.z; col[4*k+3] = cv.w;
    }
    unsigned fmask = 0, bmask = 0;
#pragma unroll 1
    for (int s = 1; s <= 8; ++s) {                   // forward: dist + mask bits only
        int jj = (pos - s) & 15;
        LOAD_NB(Lr, jj);
        float dh = dist16(col, nb);
        float ds = dh + xor1_f(dh);                  // DPP lane^1 — same value both paired lanes
        fmask |= (unsigned)(ds < tmf) << s;
        bmask |= (unsigned)((ds >= tlo) & (ds <= thi)) << s;
    }
    if (__ballot(bmask != 0)) {                      // rare fp64 fixup, wave-uniform
#pragma unroll 1
        for (int s = 1; s <= 8; ++s) {
            if (__ballot((bmask >> s) & 1)) {
                int jj = (pos - s) & 15;
                LOAD_NB(Lr, jj);
                double d64h = 0.0;
#pragma unroll
                for (int c = 0; c < 16; ++c) d64h += fabs((double)col[c] - (double)nb[c]);
                double other = __shfl_xor(d64h, 1, 64);
                unsigned cc = (unsigned)((d64h + other) < thr);
                if ((bmask >> s) & 1) fmask = (fmask & ~(1u << s)) | (cc << s);
            }
        }
    }
    unsigned rmask = 0;                              // reverse bits via ballot (no bpermute)
#pragma unroll 1
    for (int s = 9; s <= 15; ++s) {
        int kbit = 16 - s;
        unsigned long long bal = __ballot((fmask >> kbit) & 1);
        int pl = ((pos - s) & 15) * 4 + c2;          // partner lane (same wl/half, pos-s)
        rmask |= (unsigned)((bal >> pl) & 1ull) << s;
    }
    float Mv[16];
#pragma unroll
    for (int c = 0; c < 16; ++c) Mv[c] = col[c];
    unsigned allm = (fmask & 0x1FEu) | rmask;        // bits 1..8 fwd, 9..15 rev
    while (allm) {                                   // lazy merge of SELECTED shifts only
        int s = __ffs(allm) - 1;
        allm &= allm - 1;
        int jj = (pos - s) & 15;
        LOAD_NB(Lr, jj);
#pragma unroll
        for (int c = 0; c < 16; ++c) Mv[c] = fmaxf(Mv[c], nb[c]);
    }
    size_t p = (size_t)F * FS + (size_t)(2 * pos + par) * AS + w0 + wl;
    store_m16(M + ((size_t)b * 65536 + p) * 32 + hf * 16, Mv);
}

// ---------------- unified passes kernel: balanced + local swizzle ----------------
// xcd = bid&7 (dispatch round-robin). Each XCD gets 128 W + 128 H + 128 D blocks,
// phases aligned across XCDs; per-type unit range contiguous per XCD (~2MB, fits L2).
__global__ __launch_bounds__(256) void k_passes(const float* __restrict__ x, const double2* __restrict__ npart,
                                                __half* __restrict__ Mw, __half* __restrict__ Mh,
                                                __half* __restrict__ Md) {
    __shared__ __align__(16) float L[4128];
    __shared__ double ls[4], lq[4], thrs[2];
    __shared__ float fb[8];
    int t = threadIdx.x;
    thr_reduce(npart, thrs, fb, ls, lq, t);
    int xcd = blockIdx.x & 7;
    int i = blockIdx.x >> 3;                         // 0..383
    int type = i >> 7;                               // 0:W 1:H 2:D (128 each per XCD)
    int u = xcd * 128 + (i & 127);                   // contiguous unit range per XCD
    if (type == 0) {
        // ---- W-axis: 4 rings (2 lines x 2 parities); one wave per ring ----
        int blk = u;
#pragma unroll
        for (int it = 0; it < 4; ++it) {
            int f = it * 256 + t;
            int ll = f >> 9;
            int l = blk * 2 + ll;
            int c = (f >> 4) & 31, wq = f & 15;
            const float* lb = x + (size_t)(l >> 10) * CDHW_ + ((l >> 5) & 31) * HW_ + (l & 31) * W_;
            float4 v = *(const float4*)(lb + (size_t)c * DHW_ + wq * 4);
            int cq = c >> 2, cr = c & 3;
            const float* ve = (const float*)&v;
#pragma unroll
            for (int e = 0; e < 4; ++e) {
                int wv2 = wq * 4 + e;
                int p = wv2 >> 1, par = wv2 & 1;
                L[(ll * 2 + par) * 1024 + p * 32 + (((cq ^ WSLOT(p)) << 2) | cr)] = ve[e];
            }
        }
        __syncthreads();
        int ring = t >> 6, ln = t & 63;
        int pos = ln >> 1, hf = ln & 1;
        int ll = ring >> 1, par = ring & 1;
        int l = blk * 2 + ll;
        int b = l >> 10, d = (l >> 5) & 31, h = l & 31;
        double thr = thrs[b];
        float tlo = fb[b*4], thi = fb[b*4+1], tmf = fb[b*4+2];
        const float* Lr = L + ring * 1024;
        int qb = hf * 4;
        float col[16], nb[16];
#pragma unroll
        for (int k = 0; k < 4; ++k) {
            float4 cv = *(const float4*)(Lr + pos * 32 + (((qb + k) ^ WSLOT(pos)) << 2));
            col[4*k] = cv.x; col[4*k+1] = cv.y; col[4*k+2] = cv.z; col[4*k+3] = cv.w;
        }
        unsigned fmask = 0, bmask = 0;
#pragma unroll 1
        for (int s = 1; s <= 16; ++s) {              // forward (incl s=16 self-pair): dist + mask only
            int jf = (pos - s) & 31;
            LOAD_NBW(Lr, jf);
            float dh = dist16(col, nb);
            float ds = dh + xor1_f(dh);              // DPP lane^1 (= ln^1 half partner)
            fmask |= (unsigned)(ds < tmf) << s;
            bmask |= (unsigned)((ds >= tlo) & (ds <= thi)) << s;
        }
        if (__ballot(bmask != 0)) {                  // rare fp64 fixup, wave-uniform
#pragma unroll 1
            for (int s = 1; s <= 16; ++s) {
                if (__ballot((bmask >> s) & 1)) {
                    int jf = (pos - s) & 31;
                    LOAD_NBW(Lr, jf);
                    double d64h = 0.0;
#pragma unroll
                    for (int c = 0; c < 16; ++c) d64h += fabs((double)col[c] - (double)nb[c]);
                    double other = __shfl_xor(d64h, 1, 64);
                    unsigned cc = (unsigned)((d64h + other) < thr);
                    if ((bmask >> s) & 1) fmask = (fmask & ~(1u << s)) | (cc << s);
                }
            }
        }
        unsigned rmask = 0;                          // reverse rs=32-s via ballot
#pragma unroll 1
        for (int s = 1; s <= 15; ++s) {
            unsigned long long bal = __ballot((fmask >> s) & 1);
            int pl2 = (((pos + s) & 31) << 1) + hf;  // partner lane (same half, pos+s)
            rmask |= (unsigned)((bal >> pl2) & 1ull) << (32 - s);
        }
        float Mv[16];
#pragma unroll
        for (int c = 0; c < 16; ++c) Mv[c] = col[c];
        unsigned allm = (fmask & 0x1FFFEu) | rmask;  // bits 1..16 fwd, 17..31 rev
        while (allm) {                               // lazy merge of SELECTED shifts only
            int s = __ffs(allm) - 1;
            allm &= allm - 1;
            int jj = (pos - s) & 31;
            LOAD_NBW(Lr, jj);
#pragma unroll
            for (int c = 0; c < 16; ++c) Mv[c] = fmaxf(Mv[c], nb[c]);
        }
        size_t ppt = (size_t)d * HW_ + h * W_ + 2 * pos + par;
        store_m16(Mw + ((size_t)b * 65536 + ppt) * 32 + hf * 16, Mv);
    } else if (type == 1) {
        hd_ring<W_, HW_>(x, Mh, thrs, fb, L, u, t);   // H pass (F = d)
    } else {
        hd_ring<HW_, W_>(x, Md, thrs, fb, L, u, t);   // D pass (F = h)
    }
}

// ---------------- conv (64->32) + fused BN partial stats; fp16 M, max3 inline ----------------
__global__ __launch_bounds__(256, 4) void k_conv(const float* __restrict__ x,
                                                 const __half* __restrict__ Mw, const __half* __restrict__ Mh,
                                                 const __half* __restrict__ Md,
                                                 const float* __restrict__ w, const float* __restrict__ bias,
                                                 float* __restrict__ y, float2* __restrict__ spart) {
    int t = threadIdx.x;
    int blk = (blockIdx.x & 7) * 256 + (blockIdx.x >> 3);   // bijective XCD swizzle (2048 = 8*256)
    int b = blk >> 10;
    int p0 = (blk & 1023) * 64;
    int og = __builtin_amdgcn_readfirstlane(t >> 6);
    int pl = t & 63;
    const float* xb = x + (size_t)b * CDHW_ + p0 + pl;
    size_t moff = ((size_t)b * 65536 + p0 + pl) * 32;
    const int4* mw4 = (const int4*)(Mw + moff);
    const int4* mh4 = (const int4*)(Mh + moff);
    const int4* md4 = (const int4*)(Md + moff);
    const float* wo = w + og * 512;
    const float* bo = bias + og * 8;
    float a[8], xv[32];
#pragma unroll
    for (int k = 0; k < 8; ++k) a[k] = bo[k];
#pragma unroll
    for (int c = 0; c < 32; c += 4) {
        xv[c+0] = xb[(size_t)(c+0) * DHW_];
        xv[c+1] = xb[(size_t)(c+1) * DHW_];
        xv[c+2] = xb[(size_t)(c+2) * DHW_];
        xv[c+3] = xb[(size_t)(c+3) * DHW_];
#pragma unroll
        for (int k = 0; k < 8; ++k) {
            a[k] = fmaf(wo[k*64 + c+0], xv[c+0], a[k]);
            a[k] = fmaf(wo[k*64 + c+1], xv[c+1], a[k]);
            a[k] = fmaf(wo[k*64 + c+2], xv[c+2], a[k]);
            a[k] = fmaf(wo[k*64 + c+3], xv[c+3], a[k]);
        }
    }
#pragma unroll
    for (int i = 0; i < 4; ++i) {                    // 8 channels per int4 (fp16-packed)
        int4 aw = mw4[i], ah = mh4[i], ad = md4[i];
        const __half2* hw = (const __half2*)&aw;
        const __half2* hh = (const __half2*)&ah;
        const __half2* hd = (const __half2*)&ad;
#pragma unroll
        for (int j = 0; j < 4; ++j) {
            float2 fw = __half22float2(hw[j]);
            float2 fh = __half22float2(hh[j]);
            float2 fd = __half22float2(hd[j]);
            int c = i * 8 + j * 2;
            float z0 = fmaxf(fmaxf(fmaxf(fw.x, fh.x), fd.x) - xv[c+0], 0.f);
            float z1 = fmaxf(fmaxf(fmaxf(fw.y, fh.y), fd.y) - xv[c+1], 0.f);
#pragma unroll
            for (int k = 0; k < 8; ++k) {
                a[k] = fmaf(wo[k*64 + 32 + c+0], z0, a[k]);
                a[k] = fmaf(wo[k*64 + 32 + c+1], z1, a[k]);
            }
        }
    }
    float* yb = y + (size_t)b * CDHW_ + p0 + pl;
#pragma unroll
    for (int k = 0; k < 8; ++k) {
        yb[(size_t)(og * 8 + k) * DHW_] = a[k];
        float s = a[k], q = a[k] * a[k];
        for (int off = 32; off; off >>= 1) {
            s += __shfl_down(s, off, 64);
            q += __shfl_down(q, off, 64);
        }
        if (pl == 0) spart[(og * 8 + k) * 2048 + blk] = make_float2(s, q);
    }
}

// ---------------- BN finalize + exact GELU, in-place ----------------
__global__ __launch_bounds__(256) void k_out(float* __restrict__ y, const float2* __restrict__ spart,
                                             const float* __restrict__ gamma, const float* __restrict__ beta) {
    int t = threadIdx.x;
    int o = (blockIdx.x >> 6) & 31;                  // block-uniform channel
    __shared__ double ls[4], lq[4];
    __shared__ float bnp[2];
    {
        const float2* sp = spart + o * 2048;
        double s = 0.0, q = 0.0;
#pragma unroll
        for (int i = 0; i < 8; ++i) {
            float2 v = sp[i * 256 + t];
            s += (double)v.x; q += (double)v.y;
        }
        for (int off = 32; off; off >>= 1) {
            s += __shfl_down(s, off, 64);
            q += __shfl_down(q, off, 64);
        }
        if ((t & 63) == 0) { ls[t >> 6] = s; lq[t >> 6] = q; }
    }
    __syncthreads();
    if (t == 0) {
        double sm = (ls[0] + ls[1]) + (ls[2] + ls[3]);
        double sq = (lq[0] + lq[1]) + (lq[2] + lq[3]);
        double mu = sm / (double)BN_N_;
        double var = sq / (double)BN_N_ - mu * mu;
        bnp[0] = (float)mu;
        bnp[1] = (float)(1.0 / sqrt(var + 1e-5));
    }
    __syncthreads();
    float mu_f = bnp[0], rstd = bnp[1];
    float g = gamma[o], be = beta[o];
    int idx = blockIdx.x * 256 + t;                  // over 1,048,576 float4
    float4 v = ((const float4*)y)[idx];
    float* vv = (float*)&v;
#pragma unroll
    for (int j = 0; j < 4; ++j) {
        float tt = (vv[j] - mu_f) * rstd * g + be;
        vv[j] = 0.5f * tt * (1.f + erff(tt * 0.70710678118654752f));
    }
    ((float4*)y)[idx] = v;
}

extern "C" void kernel_launch(void* const* d_in, const int* in_sizes, int n_in,
                              void* d_out, int out_size, void* d_ws, size_t ws_size,
                              hipStream_t stream) {
    const float* x     = (const float*)d_in[0];
    const float* w     = (const float*)d_in[1];
    const float* bias  = (const float*)d_in[2];
    const float* gamma = (const float*)d_in[3];
    const float* beta  = (const float*)d_in[4];
    float* out = (float*)d_out;
    __half* Mw = (__half*)d_ws;
    __half* Mh = (__half*)((char*)d_ws + MH_OFF);
    __half* Md = (__half*)((char*)d_ws + MD_OFF);
    double2* npart = (double2*)((char*)d_ws + RED_OFF + 256);
    float2*  spart = (float2*)((char*)d_ws + RED_OFF + 256 + 16384);

    k_norm  <<<512, 256, 0, stream>>>(x, npart);
    k_passes<<<3072, 256, 0, stream>>>(x, npart, Mw, Mh, Md);
    k_conv  <<<2048, 256, 0, stream>>>(x, Mw, Mh, Md, w, bias, out, spart);
    k_out   <<<4096, 256, 0, stream>>>(out, spart, gamma, beta);
}

// Round 20
// 85.500 us; speedup vs baseline: 1.3746x; 1.0072x over previous
//
#include <hip/hip_runtime.h>
#include <hip/hip_fp16.h>
#include <math.h>

#define B_ 2
#define C_ 32
#define D_ 32
#define H_ 32
#define W_ 64
#define HW_ (H_*W_)         // 2048
#define DHW_ (D_*H_*W_)     // 65536
#define CDHW_ (C_*DHW_)     // 2097152
#define NSP_ DHW_           // spatial points per batch
#define BN_N_ (B_*DHW_)     // 131072
#define BORDER 1e-4         // f32 dist err bound ~2e-5; 5x margin (was 1e-3, 50x -> fixup too hot)
#define RS 516              // padded LDS ring stride (floats)

// ws layout (fp16 M): Mw @0 (8MB), Mh @8MB, Md @16MB  — each [b][p][c] __half.
// reduction @48MB: npart[512] double2 @ +256, spart[32][2048] float2 @ +256+16384.
#define MH_OFF  (8u<<20)
#define MD_OFF  (16u<<20)
#define RED_OFF (48u<<20)

// lane^1 exchange on the VALU (DPP quad_perm [1,0,3,2]) — no LDS pipe, no latency.
__device__ __forceinline__ float xor1_f(float v) {
#if __has_builtin(__builtin_amdgcn_mov_dpp)
    return __int_as_float(__builtin_amdgcn_mov_dpp(__float_as_int(v), 0xB1, 0xF, 0xF, true));
#else
    return __shfl_xor(v, 1, 64);
#endif
}

// DPP wave-64 f32 add-reduce: after these 6 steps lane 63 holds the full sum.
// ctrl/rmask MUST be compile-time constants -> template parameters.
#if __has_builtin(__builtin_amdgcn_update_dpp)
template<int CTRL, int RMASK>
__device__ __forceinline__ float dpp_add_step(float v) {
    int s = __builtin_amdgcn_update_dpp(0, __float_as_int(v), CTRL, RMASK, 0xF, true);
    return v + __int_as_float(s);
}
__device__ __forceinline__ float wave_sum63(float v) {
    v = dpp_add_step<0x111, 0xF>(v);   // row_shr:1
    v = dpp_add_step<0x112, 0xF>(v);   // row_shr:2
    v = dpp_add_step<0x114, 0xF>(v);   // row_shr:4
    v = dpp_add_step<0x118, 0xF>(v);   // row_shr:8  -> lane15/31/47/63 = row sums
    v = dpp_add_step<0x142, 0xA>(v);   // row_bcast:15 into rows 1,3
    v = dpp_add_step<0x143, 0xC>(v);   // row_bcast:31 into rows 2,3 -> lane63 = total
    return v;
}
#define STATS_LANE 63
#else
__device__ __forceinline__ float wave_sum63(float v) {
    for (int off = 32; off; off >>= 1) v += __shfl_down(v, off, 64);
    return v;
}
#define STATS_LANE 0
#endif

// ---------------- threshold stats: involution-halved (only d<16; norm[p]==norm[pf] exactly) ----------------
__global__ __launch_bounds__(256) void k_norm(const float* __restrict__ x, double2* __restrict__ npart) {
    int tid = blockIdx.x * 256 + threadIdx.x;       // 131072 threads
    int ln = threadIdx.x & 63;
    int hf = ln >> 5, lp = ln & 31;
    int ph = (tid >> 6) * 32 + lp;                  // 0..65535 half-space points (2x lane coverage)
    int b = ph >> 15;
    int pp = ph & 32767;                            // (d<<11)|(h<<6)|w with d in 0..15
    int d = pp >> 11, h = (pp >> 6) & 31, w = pp & 63;
    int pf = ((d ^ 16) << 11) | ((h ^ 16) << 6) | (w ^ 32);
    const float* xb = x + (size_t)b * CDHW_ + (size_t)hf * 16 * DHW_;
    double s = 0.0;
#pragma unroll
    for (int c = 0; c < 16; ++c) {
        float a  = xb[c * DHW_ + pp];
        float bb = xb[c * DHW_ + pf];
        s += fabs((double)a - (double)bb);
    }
    double st = s + __shfl_xor(s, 32, 64);          // full 32-ch sum (both halves hold it)
    double s2 = st * st;
    for (int off = 32; off; off >>= 1) {
        st += __shfl_down(st, off, 64);
        s2 += __shfl_down(s2, off, 64);
    }
    __shared__ double ls[4], ls2[4];
    int wv = threadIdx.x >> 6;
    if (ln == 0) { ls[wv] = st; ls2[wv] = s2; }
    __syncthreads();
    if (threadIdx.x == 0) {
        double2 o;                                   // 2-lane dup == involution doubling
        o.x = (ls[0] + ls[1]) + (ls[2] + ls[3]);
        o.y = (ls2[0] + ls2[1]) + (ls2[2] + ls2[3]);
        npart[blockIdx.x] = o;
    }
}

// ---------------- per-block redundant thr reduce + f32 gate bounds ----------------
__device__ __forceinline__ void thr_reduce(const double2* __restrict__ npart, double* thrs, float* fb,
                                           double* ls, double* lq, int t) {
    {
        double s = 0.0, q = 0.0;
#pragma unroll
        for (int i = 0; i < 2; ++i) {
            double2 v = npart[t * 2 + i];
            s += v.x; q += v.y;
        }
        for (int off = 32; off; off >>= 1) {
            s += __shfl_down(s, off, 64);
            q += __shfl_down(q, off, 64);
        }
        if ((t & 63) == 0) { ls[t >> 6] = s; lq[t >> 6] = q; }
    }
    __syncthreads();
    if (t < 2) {
        double sum = ls[2 * t] + ls[2 * t + 1];
        double sq  = lq[2 * t] + lq[2 * t + 1];
        double n = (double)NSP_;
        double mean = sum / n;
        double var = (sq - sum * sum / n) / (n - 1.0);   // ddof=1
        if (var < 0.0) var = 0.0;
        double thrv = mean - sqrt(var);
        thrs[t] = thrv;
        fb[t * 4 + 0] = (float)(thrv - BORDER * 1.01);
        fb[t * 4 + 1] = (float)(thrv + BORDER * 1.01);
        fb[t * 4 + 2] = (float)thrv;
    }
    __syncthreads();
}

__device__ __forceinline__ float dist16(const float* col, const float* nb) {
    float d0 = 0.f, d1 = 0.f, d2 = 0.f, d3 = 0.f;
#pragma unroll
    for (int c = 0; c < 16; c += 4) {
        d0 += fabsf(col[c+0] - nb[c+0]);
        d1 += fabsf(col[c+1] - nb[c+1]);
        d2 += fabsf(col[c+2] - nb[c+2]);
        d3 += fabsf(col[c+3] - nb[c+3]);
    }
    return (d0 + d1) + (d2 + d3);
}

__device__ __forceinline__ void store_m16(__half* mp, const float* Mv) {
    __half2 tmp[8];
#pragma unroll
    for (int k = 0; k < 8; ++k) tmp[k] = __floats2half2_rn(Mv[2*k], Mv[2*k+1]);
    *(int4*)mp       = *(int4*)&tmp[0];
    *(int4*)(mp + 8) = *(int4*)&tmp[4];
}

#define LOAD_NB(LRP, JJ) \
    { _Pragma("unroll") for (int k = 0; k < 4; ++k) { \
        float4 nv = *(const float4*)((LRP) + (JJ) * 32 + (((qb + k) ^ ((JJ) & 7)) << 2)); \
        nb[4*k] = nv.x; nb[4*k+1] = nv.y; nb[4*k+2] = nv.z; nb[4*k+3] = nv.w; } }

// W-pass hash: include high pos bits so pos, pos+8, pos+16, pos+24 get distinct slots.
#define WSLOT(JJ) (((JJ) + ((JJ) >> 3)) & 7)
#define LOAD_NBW(LRP, JJ) \
    { _Pragma("unroll") for (int k = 0; k < 4; ++k) { \
        float4 nv = *(const float4*)((LRP) + (JJ) * 32 + (((qb + k) ^ WSLOT(JJ)) << 2)); \
        nb[4*k] = nv.x; nb[4*k+1] = nv.y; nb[4*k+2] = nv.z; nb[4*k+3] = nv.w; } }

// H/D ring body. 256 threads, 8 rings (one parity). Forward loop: dist+mask only,
// DPP for lane^1 sum; partner bits gathered via ballot; merges lazy.
template<int AS, int FS>
__device__ __forceinline__ void hd_ring(const float* __restrict__ x, __half* __restrict__ M,
                                        const double* thrs, const float* fb, float* L, int local, int t) {
    int par = local & 1, wt = (local >> 1) & 7, F = (local >> 4) & 31, b = local >> 9;
    int w0 = wt * 8;
    double thr = thrs[b];
    float tlo = fb[b*4], thi = fb[b*4+1], tmf = fb[b*4+2];
    const float* xb = x + (size_t)b * CDHW_ + (size_t)F * FS + w0;
#pragma unroll
    for (int it = 0; it < 4; ++it) {
        int f = it * 256 + t;                        // 0..1023 float4s
        int c = f >> 5, rem = f & 31, j = rem >> 1, wq = rem & 1;
        float4 v = *(const float4*)(xb + (size_t)c * DHW_ + (size_t)(2 * j + par) * AS + wq * 4);
        int sl = (((c >> 2) ^ (j & 7)) << 2) + (c & 3);
        int rb = (wq * 4) * RS + j * 32 + sl;
        L[rb] = v.x; L[rb + RS] = v.y; L[rb + 2*RS] = v.z; L[rb + 3*RS] = v.w;
    }
    __syncthreads();
    int ln = t & 63, wave = t >> 6;
    int pos = ln >> 2, c2 = ln & 3;
    int wl = wave * 2 + (c2 >> 1), hf = c2 & 1;
    const float* Lr = L + wl * RS;
    int qb = hf * 4;
    float col[16], nb[16];
#pragma unroll
    for (int k = 0; k < 4; ++k) {
        float4 cv = *(const float4*)(Lr + pos * 32 + (((qb + k) ^ (pos & 7)) << 2));
        col[4*k] = cv.x; col[4*k+1] = cv.y; col[4*k+2] = cv.z; col[4*k+3] = cv.w;
    }
    unsigned fmask = 0, bmask = 0;
#pragma unroll 1
    for (int s = 1; s <= 8; ++s) {                   // forward: dist + mask bits only
        int jj = (pos - s) & 15;
        LOAD_NB(Lr, jj);
        float dh = dist16(col, nb);
        float ds = dh + xor1_f(dh);                  // DPP lane^1 — same value both paired lanes
        fmask |= (unsigned)(ds < tmf) << s;
        bmask |= (unsigned)((ds >= tlo) & (ds <= thi)) << s;
    }
    if (__ballot(bmask != 0)) {                      // rare fp64 fixup, wave-uniform
#pragma unroll 1
        for (int s = 1; s <= 8; ++s) {
            if (__ballot((bmask >> s) & 1)) {
                int jj = (pos - s) & 15;
                LOAD_NB(Lr, jj);
                double d64h = 0.0;
#pragma unroll
                for (int c = 0; c < 16; ++c) d64h += fabs((double)col[c] - (double)nb[c]);
                double other = __shfl_xor(d64h, 1, 64);
                unsigned cc = (unsigned)((d64h + other) < thr);
                if ((bmask >> s) & 1) fmask = (fmask & ~(1u << s)) | (cc << s);
            }
        }
    }
    unsigned rmask = 0;                              // reverse bits via ballot (no bpermute)
#pragma unroll 1
    for (int s = 9; s <= 15; ++s) {
        int kbit = 16 - s;
        unsigned long long bal = __ballot((fmask >> kbit) & 1);
        int pl = ((pos - s) & 15) * 4 + c2;          // partner lane (same wl/half, pos-s)
        rmask |= (unsigned)((bal >> pl) & 1ull) << s;
    }
    float Mv[16];
#pragma unroll
    for (int c = 0; c < 16; ++c) Mv[c] = col[c];
    unsigned allm = (fmask & 0x1FEu) | rmask;        // bits 1..8 fwd, 9..15 rev
    while (allm) {                                   // lazy merge of SELECTED shifts only
        int s = __ffs(allm) - 1;
        allm &= allm - 1;
        int jj = (pos - s) & 15;
        LOAD_NB(Lr, jj);
#pragma unroll
        for (int c = 0; c < 16; ++c) Mv[c] = fmaxf(Mv[c], nb[c]);
    }
    size_t p = (size_t)F * FS + (size_t)(2 * pos + par) * AS + w0 + wl;
    store_m16(M + ((size_t)b * 65536 + p) * 32 + hf * 16, Mv);
}

// ---------------- unified passes kernel: balanced + local swizzle ----------------
// xcd = bid&7 (dispatch round-robin). Each XCD gets 128 W + 128 H + 128 D blocks,
// phases aligned across XCDs; per-type unit range contiguous per XCD (~2MB, fits L2).
__global__ __launch_bounds__(256) void k_passes(const float* __restrict__ x, const double2* __restrict__ npart,
                                                __half* __restrict__ Mw, __half* __restrict__ Mh,
                                                __half* __restrict__ Md) {
    __shared__ __align__(16) float L[4128];
    __shared__ double ls[4], lq[4], thrs[2];
    __shared__ float fb[8];
    int t = threadIdx.x;
    thr_reduce(npart, thrs, fb, ls, lq, t);
    int xcd = blockIdx.x & 7;
    int i = blockIdx.x >> 3;                         // 0..383
    int type = i >> 7;                               // 0:W 1:H 2:D (128 each per XCD)
    int u = xcd * 128 + (i & 127);                   // contiguous unit range per XCD
    if (type == 0) {
        // ---- W-axis: 4 rings (2 lines x 2 parities); one wave per ring ----
        int blk = u;
#pragma unroll
        for (int it = 0; it < 4; ++it) {
            int f = it * 256 + t;
            int ll = f >> 9;
            int l = blk * 2 + ll;
            int c = (f >> 4) & 31, wq = f & 15;
            const float* lb = x + (size_t)(l >> 10) * CDHW_ + ((l >> 5) & 31) * HW_ + (l & 31) * W_;
            float4 v = *(const float4*)(lb + (size_t)c * DHW_ + wq * 4);
            int cq = c >> 2, cr = c & 3;
            const float* ve = (const float*)&v;
#pragma unroll
            for (int e = 0; e < 4; ++e) {
                int wv2 = wq * 4 + e;
                int p = wv2 >> 1, par = wv2 & 1;
                L[(ll * 2 + par) * 1024 + p * 32 + (((cq ^ WSLOT(p)) << 2) | cr)] = ve[e];
            }
        }
        __syncthreads();
        int ring = t >> 6, ln = t & 63;
        int pos = ln >> 1, hf = ln & 1;
        int ll = ring >> 1, par = ring & 1;
        int l = blk * 2 + ll;
        int b = l >> 10, d = (l >> 5) & 31, h = l & 31;
        double thr = thrs[b];
        float tlo = fb[b*4], thi = fb[b*4+1], tmf = fb[b*4+2];
        const float* Lr = L + ring * 1024;
        int qb = hf * 4;
        float col[16], nb[16];
#pragma unroll
        for (int k = 0; k < 4; ++k) {
            float4 cv = *(const float4*)(Lr + pos * 32 + (((qb + k) ^ WSLOT(pos)) << 2));
            col[4*k] = cv.x; col[4*k+1] = cv.y; col[4*k+2] = cv.z; col[4*k+3] = cv.w;
        }
        unsigned fmask = 0, bmask = 0;
#pragma unroll 1
        for (int s = 1; s <= 16; ++s) {              // forward (incl s=16 self-pair): dist + mask only
            int jf = (pos - s) & 31;
            LOAD_NBW(Lr, jf);
            float dh = dist16(col, nb);
            float ds = dh + xor1_f(dh);              // DPP lane^1 (= ln^1 half partner)
            fmask |= (unsigned)(ds < tmf) << s;
            bmask |= (unsigned)((ds >= tlo) & (ds <= thi)) << s;
        }
        if (__ballot(bmask != 0)) {                  // rare fp64 fixup, wave-uniform
#pragma unroll 1
            for (int s = 1; s <= 16; ++s) {
                if (__ballot((bmask >> s) & 1)) {
                    int jf = (pos - s) & 31;
                    LOAD_NBW(Lr, jf);
                    double d64h = 0.0;
#pragma unroll
                    for (int c = 0; c < 16; ++c) d64h += fabs((double)col[c] - (double)nb[c]);
                    double other = __shfl_xor(d64h, 1, 64);
                    unsigned cc = (unsigned)((d64h + other) < thr);
                    if ((bmask >> s) & 1) fmask = (fmask & ~(1u << s)) | (cc << s);
                }
            }
        }
        unsigned rmask = 0;                          // reverse rs=32-s via ballot
#pragma unroll 1
        for (int s = 1; s <= 15; ++s) {
            unsigned long long bal = __ballot((fmask >> s) & 1);
            int pl2 = (((pos + s) & 31) << 1) + hf;  // partner lane (same half, pos+s)
            rmask |= (unsigned)((bal >> pl2) & 1ull) << (32 - s);
        }
        float Mv[16];
#pragma unroll
        for (int c = 0; c < 16; ++c) Mv[c] = col[c];
        unsigned allm = (fmask & 0x1FFFEu) | rmask;  // bits 1..16 fwd, 17..31 rev
        while (allm) {                               // lazy merge of SELECTED shifts only
            int s = __ffs(allm) - 1;
            allm &= allm - 1;
            int jj = (pos - s) & 31;
            LOAD_NBW(Lr, jj);
#pragma unroll
            for (int c = 0; c < 16; ++c) Mv[c] = fmaxf(Mv[c], nb[c]);
        }
        size_t ppt = (size_t)d * HW_ + h * W_ + 2 * pos + par;
        store_m16(Mw + ((size_t)b * 65536 + ppt) * 32 + hf * 16, Mv);
    } else if (type == 1) {
        hd_ring<W_, HW_>(x, Mh, thrs, fb, L, u, t);   // H pass (F = d)
    } else {
        hd_ring<HW_, W_>(x, Md, thrs, fb, L, u, t);   // D pass (F = h)
    }
}

// ---------------- conv (64->32) + fused BN partial stats; fp16 M, DPP stats reduce ----------------
__global__ __launch_bounds__(256, 4) void k_conv(const float* __restrict__ x,
                                                 const __half* __restrict__ Mw, const __half* __restrict__ Mh,
                                                 const __half* __restrict__ Md,
                                                 const float* __restrict__ w, const float* __restrict__ bias,
                                                 float* __restrict__ y, float2* __restrict__ spart) {
    int t = threadIdx.x;
    int blk = (blockIdx.x & 7) * 256 + (blockIdx.x >> 3);   // bijective XCD swizzle (2048 = 8*256)
    int b = blk >> 10;
    int p0 = (blk & 1023) * 64;
    int og = __builtin_amdgcn_readfirstlane(t >> 6);
    int pl = t & 63;
    const float* xb = x + (size_t)b * CDHW_ + p0 + pl;
    size_t moff = ((size_t)b * 65536 + p0 + pl) * 32;
    const int4* mw4 = (const int4*)(Mw + moff);
    const int4* mh4 = (const int4*)(Mh + moff);
    const int4* md4 = (const int4*)(Md + moff);
    const float* wo = w + og * 512;
    const float* bo = bias + og * 8;
    float a[8], xv[32];
#pragma unroll
    for (int k = 0; k < 8; ++k) a[k] = bo[k];
#pragma unroll
    for (int c = 0; c < 32; c += 4) {
        xv[c+0] = xb[(size_t)(c+0) * DHW_];
        xv[c+1] = xb[(size_t)(c+1) * DHW_];
        xv[c+2] = xb[(size_t)(c+2) * DHW_];
        xv[c+3] = xb[(size_t)(c+3) * DHW_];
#pragma unroll
        for (int k = 0; k < 8; ++k) {
            a[k] = fmaf(wo[k*64 + c+0], xv[c+0], a[k]);
            a[k] = fmaf(wo[k*64 + c+1], xv[c+1], a[k]);
            a[k] = fmaf(wo[k*64 + c+2], xv[c+2], a[k]);
            a[k] = fmaf(wo[k*64 + c+3], xv[c+3], a[k]);
        }
    }
#pragma unroll
    for (int i = 0; i < 4; ++i) {                    // 8 channels per int4 (fp16-packed)
        int4 aw = mw4[i], ah = mh4[i], ad = md4[i];
        const __half2* hw = (const __half2*)&aw;
        const __half2* hh = (const __half2*)&ah;
        const __half2* hd = (const __half2*)&ad;
#pragma unroll
        for (int j = 0; j < 4; ++j) {
            float2 fw = __half22float2(hw[j]);
            float2 fh = __half22float2(hh[j]);
            float2 fd = __half22float2(hd[j]);
            int c = i * 8 + j * 2;
            float z0 = fmaxf(fmaxf(fmaxf(fw.x, fh.x), fd.x) - xv[c+0], 0.f);
            float z1 = fmaxf(fmaxf(fmaxf(fw.y, fh.y), fd.y) - xv[c+1], 0.f);
#pragma unroll
            for (int k = 0; k < 8; ++k) {
                a[k] = fmaf(wo[k*64 + 32 + c+0], z0, a[k]);
                a[k] = fmaf(wo[k*64 + 32 + c+1], z1, a[k]);
            }
        }
    }
    float* yb = y + (size_t)b * CDHW_ + p0 + pl;
#pragma unroll
    for (int k = 0; k < 8; ++k) {
        yb[(size_t)(og * 8 + k) * DHW_] = a[k];
        float s = wave_sum63(a[k]);
        float q = wave_sum63(a[k] * a[k]);
        if (pl == STATS_LANE) spart[(og * 8 + k) * 2048 + blk] = make_float2(s, q);
    }
}

// ---------------- BN finalize + exact GELU, in-place ----------------
__global__ __launch_bounds__(256) void k_out(float* __restrict__ y, const float2* __restrict__ spart,
                                             const float* __restrict__ gamma, const float* __restrict__ beta) {
    int t = threadIdx.x;
    int o = (blockIdx.x >> 6) & 31;                  // block-uniform channel
    __shared__ double ls[4], lq[4];
    __shared__ float bnp[2];
    {
        const float2* sp = spart + o * 2048;
        double s = 0.0, q = 0.0;
#pragma unroll
        for (int i = 0; i < 8; ++i) {
            float2 v = sp[i * 256 + t];
            s += (double)v.x; q += (double)v.y;
        }
        for (int off = 32; off; off >>= 1) {
            s += __shfl_down(s, off, 64);
            q += __shfl_down(q, off, 64);
        }
        if ((t & 63) == 0) { ls[t >> 6] = s; lq[t >> 6] = q; }
    }
    __syncthreads();
    if (t == 0) {
        double sm = (ls[0] + ls[1]) + (ls[2] + ls[3]);
        double sq = (lq[0] + lq[1]) + (lq[2] + lq[3]);
        double mu = sm / (double)BN_N_;
        double var = sq / (double)BN_N_ - mu * mu;
        bnp[0] = (float)mu;
        bnp[1] = (float)(1.0 / sqrt(var + 1e-5));
    }
    __syncthreads();
    float mu_f = bnp[0], rstd = bnp[1];
    float g = gamma[o], be = beta[o];
    int idx = blockIdx.x * 256 + t;                  // over 1,048,576 float4
    float4 v = ((const float4*)y)[idx];
    float* vv = (float*)&v;
#pragma unroll
    for (int j = 0; j < 4; ++j) {
        float tt = (vv[j] - mu_f) * rstd * g + be;
        vv[j] = 0.5f * tt * (1.f + erff(tt * 0.70710678118654752f));
    }
    ((float4*)y)[idx] = v;
}

extern "C" void kernel_launch(void* const* d_in, const int* in_sizes, int n_in,
                              void* d_out, int out_size, void* d_ws, size_t ws_size,
                              hipStream_t stream) {
    const float* x     = (const float*)d_in[0];
    const float* w     = (const float*)d_in[1];
    const float* bias  = (const float*)d_in[2];
    const float* gamma = (const float*)d_in[3];
    const float* beta  = (const float*)d_in[4];
    float* out = (float*)d_out;
    __half* Mw = (__half*)d_ws;
    __half* Mh = (__half*)((char*)d_ws + MH_OFF);
    __half* Md = (__half*)((char*)d_ws + MD_OFF);
    double2* npart = (double2*)((char*)d_ws + RED_OFF + 256);
    float2*  spart = (float2*)((char*)d_ws + RED_OFF + 256 + 16384);

    k_norm  <<<512, 256, 0, stream>>>(x, npart);
    k_passes<<<3072, 256, 0, stream>>>(x, npart, Mw, Mh, Md);
    k_conv  <<<2048, 256, 0, stream>>>(x, Mw, Mh, Md, w, bias, out, spart);
    k_out   <<<4096, 256, 0, stream>>>(out, spart, gamma, beta);
}

// Round 21
// 85.212 us; speedup vs baseline: 1.3792x; 1.0034x over previous
//
#include <hip/hip_runtime.h>
#include <hip/hip_fp16.h>
#include <math.h>

#define B_ 2
#define C_ 32
#define D_ 32
#define H_ 32
#define W_ 64
#define HW_ (H_*W_)         // 2048
#define DHW_ (D_*H_*W_)     // 65536
#define CDHW_ (C_*DHW_)     // 2097152
#define NSP_ DHW_           // spatial points per batch
#define BN_N_ (B_*DHW_)     // 131072
#define BORDER 1e-4         // f32 dist err bound ~2e-5; 5x margin
#define RS 516              // padded LDS ring stride (floats)

// ws layout (fp16 M): Mw @0 (8MB), Mh @8MB, Md @16MB  — each [b][p][c] __half.
// reduction @48MB: npart[512] double2 @ +256, spart[32][2048] float2 @ +256+16384.
#define MH_OFF  (8u<<20)
#define MD_OFF  (16u<<20)
#define RED_OFF (48u<<20)

// lane^1 exchange on the VALU (DPP quad_perm [1,0,3,2]) — no LDS pipe, no latency.
__device__ __forceinline__ float xor1_f(float v) {
#if __has_builtin(__builtin_amdgcn_mov_dpp)
    return __int_as_float(__builtin_amdgcn_mov_dpp(__float_as_int(v), 0xB1, 0xF, 0xF, true));
#else
    return __shfl_xor(v, 1, 64);
#endif
}

// DPP wave-64 f32 add-reduce: lane 63 holds the full sum. ctrl/rmask are template consts.
#if __has_builtin(__builtin_amdgcn_update_dpp)
template<int CTRL, int RMASK>
__device__ __forceinline__ float dpp_add_step(float v) {
    int s = __builtin_amdgcn_update_dpp(0, __float_as_int(v), CTRL, RMASK, 0xF, true);
    return v + __int_as_float(s);
}
__device__ __forceinline__ float wave_sum63(float v) {
    v = dpp_add_step<0x111, 0xF>(v);   // row_shr:1
    v = dpp_add_step<0x112, 0xF>(v);   // row_shr:2
    v = dpp_add_step<0x114, 0xF>(v);   // row_shr:4
    v = dpp_add_step<0x118, 0xF>(v);   // row_shr:8  -> lane15/31/47/63 = row sums
    v = dpp_add_step<0x142, 0xA>(v);   // row_bcast:15 into rows 1,3
    v = dpp_add_step<0x143, 0xC>(v);   // row_bcast:31 into rows 2,3 -> lane63 = total
    return v;
}
#define STATS_LANE 63
#else
__device__ __forceinline__ float wave_sum63(float v) {
    for (int off = 32; off; off >>= 1) v += __shfl_down(v, off, 64);
    return v;
}
#define STATS_LANE 0
#endif

// ---------------- threshold stats: involution-halved, XCD-local swizzle ----------------
__global__ __launch_bounds__(256) void k_norm(const float* __restrict__ x, double2* __restrict__ npart) {
    int u = (blockIdx.x & 7) * 64 + (blockIdx.x >> 3);   // contiguous logical units per XCD
    int tid = u * 256 + threadIdx.x;
    int ln = threadIdx.x & 63;
    int hf = ln >> 5, lp = ln & 31;
    int ph = (tid >> 6) * 32 + lp;                  // 0..65535 half-space points (2x lane coverage)
    int b = ph >> 15;
    int pp = ph & 32767;                            // (d<<11)|(h<<6)|w with d in 0..15
    int d = pp >> 11, h = (pp >> 6) & 31, w = pp & 63;
    int pf = ((d ^ 16) << 11) | ((h ^ 16) << 6) | (w ^ 32);
    const float* xb = x + (size_t)b * CDHW_ + (size_t)hf * 16 * DHW_;
    double s = 0.0;
#pragma unroll
    for (int c = 0; c < 16; ++c) {
        float a  = xb[c * DHW_ + pp];
        float bb = xb[c * DHW_ + pf];
        s += fabs((double)a - (double)bb);
    }
    double st = s + __shfl_xor(s, 32, 64);          // full 32-ch sum (both halves hold it)
    double s2 = st * st;
    for (int off = 32; off; off >>= 1) {
        st += __shfl_down(st, off, 64);
        s2 += __shfl_down(s2, off, 64);
    }
    __shared__ double ls[4], ls2[4];
    int wv = threadIdx.x >> 6;
    if (ln == 0) { ls[wv] = st; ls2[wv] = s2; }
    __syncthreads();
    if (threadIdx.x == 0) {
        double2 o;                                   // 2-lane dup == involution doubling
        o.x = (ls[0] + ls[1]) + (ls[2] + ls[3]);
        o.y = (ls2[0] + ls2[1]) + (ls2[2] + ls2[3]);
        npart[u] = o;                                // same slot/value as unswizzled
    }
}

// ---------------- per-block redundant thr reduce + f32 gate bounds ----------------
__device__ __forceinline__ void thr_reduce(const double2* __restrict__ npart, double* thrs, float* fb,
                                           double* ls, double* lq, int t) {
    {
        double s = 0.0, q = 0.0;
#pragma unroll
        for (int i = 0; i < 2; ++i) {
            double2 v = npart[t * 2 + i];
            s += v.x; q += v.y;
        }
        for (int off = 32; off; off >>= 1) {
            s += __shfl_down(s, off, 64);
            q += __shfl_down(q, off, 64);
        }
        if ((t & 63) == 0) { ls[t >> 6] = s; lq[t >> 6] = q; }
    }
    __syncthreads();
    if (t < 2) {
        double sum = ls[2 * t] + ls[2 * t + 1];
        double sq  = lq[2 * t] + lq[2 * t + 1];
        double n = (double)NSP_;
        double mean = sum / n;
        double var = (sq - sum * sum / n) / (n - 1.0);   // ddof=1
        if (var < 0.0) var = 0.0;
        double thrv = mean - sqrt(var);
        thrs[t] = thrv;
        fb[t * 4 + 0] = (float)(thrv - BORDER * 1.01);
        fb[t * 4 + 1] = (float)(thrv + BORDER * 1.01);
        fb[t * 4 + 2] = (float)thrv;
    }
    __syncthreads();
}

__device__ __forceinline__ float dist16(const float* col, const float* nb) {
    float d0 = 0.f, d1 = 0.f, d2 = 0.f, d3 = 0.f;
#pragma unroll
    for (int c = 0; c < 16; c += 4) {
        d0 += fabsf(col[c+0] - nb[c+0]);
        d1 += fabsf(col[c+1] - nb[c+1]);
        d2 += fabsf(col[c+2] - nb[c+2]);
        d3 += fabsf(col[c+3] - nb[c+3]);
    }
    return (d0 + d1) + (d2 + d3);
}

__device__ __forceinline__ void store_m16(__half* mp, const float* Mv) {
    __half2 tmp[8];
#pragma unroll
    for (int k = 0; k < 8; ++k) tmp[k] = __floats2half2_rn(Mv[2*k], Mv[2*k+1]);
    *(int4*)mp       = *(int4*)&tmp[0];
    *(int4*)(mp + 8) = *(int4*)&tmp[4];
}

#define LOAD_NB(LRP, JJ) \
    { _Pragma("unroll") for (int k = 0; k < 4; ++k) { \
        float4 nv = *(const float4*)((LRP) + (JJ) * 32 + (((qb + k) ^ ((JJ) & 7)) << 2)); \
        nb[4*k] = nv.x; nb[4*k+1] = nv.y; nb[4*k+2] = nv.z; nb[4*k+3] = nv.w; } }

// W-pass hash: include high pos bits so pos, pos+8, pos+16, pos+24 get distinct slots.
#define WSLOT(JJ) (((JJ) + ((JJ) >> 3)) & 7)
#define LOAD_NBW(LRP, JJ) \
    { _Pragma("unroll") for (int k = 0; k < 4; ++k) { \
        float4 nv = *(const float4*)((LRP) + (JJ) * 32 + (((qb + k) ^ WSLOT(JJ)) << 2)); \
        nb[4*k] = nv.x; nb[4*k+1] = nv.y; nb[4*k+2] = nv.z; nb[4*k+3] = nv.w; } }

// H/D ring body. 256 threads, 8 rings (one parity). Forward loop (unroll 2 for ILP):
// dist+mask only, DPP lane^1 sum; partner bits via ballot; merges lazy.
template<int AS, int FS>
__device__ __forceinline__ void hd_ring(const float* __restrict__ x, __half* __restrict__ M,
                                        const double* thrs, const float* fb, float* L, int local, int t) {
    int par = local & 1, wt = (local >> 1) & 7, F = (local >> 4) & 31, b = local >> 9;
    int w0 = wt * 8;
    double thr = thrs[b];
    float tlo = fb[b*4], thi = fb[b*4+1], tmf = fb[b*4+2];
    const float* xb = x + (size_t)b * CDHW_ + (size_t)F * FS + w0;
#pragma unroll
    for (int it = 0; it < 4; ++it) {
        int f = it * 256 + t;                        // 0..1023 float4s
        int c = f >> 5, rem = f & 31, j = rem >> 1, wq = rem & 1;
        float4 v = *(const float4*)(xb + (size_t)c * DHW_ + (size_t)(2 * j + par) * AS + wq * 4);
        int sl = (((c >> 2) ^ (j & 7)) << 2) + (c & 3);
        int rb = (wq * 4) * RS + j * 32 + sl;
        L[rb] = v.x; L[rb + RS] = v.y; L[rb + 2*RS] = v.z; L[rb + 3*RS] = v.w;
    }
    __syncthreads();
    int ln = t & 63, wave = t >> 6;
    int pos = ln >> 2, c2 = ln & 3;
    int wl = wave * 2 + (c2 >> 1), hf = c2 & 1;
    const float* Lr = L + wl * RS;
    int qb = hf * 4;
    float col[16], nb[16];
#pragma unroll
    for (int k = 0; k < 4; ++k) {
        float4 cv = *(const float4*)(Lr + pos * 32 + (((qb + k) ^ (pos & 7)) << 2));
        col[4*k] = cv.x; col[4*k+1] = cv.y; col[4*k+2] = cv.z; col[4*k+3] = cv.w;
    }
    unsigned fmask = 0, bmask = 0;
#pragma unroll 2
    for (int s = 1; s <= 8; ++s) {                   // forward: dist + mask bits only
        int jj = (pos - s) & 15;
        LOAD_NB(Lr, jj);
        float dh = dist16(col, nb);
        float ds = dh + xor1_f(dh);                  // DPP lane^1 — same value both paired lanes
        fmask |= (unsigned)(ds < tmf) << s;
        bmask |= (unsigned)((ds >= tlo) & (ds <= thi)) << s;
    }
    if (__ballot(bmask != 0)) {                      // rare fp64 fixup, wave-uniform
#pragma unroll 1
        for (int s = 1; s <= 8; ++s) {
            if (__ballot((bmask >> s) & 1)) {
                int jj = (pos - s) & 15;
                LOAD_NB(Lr, jj);
                double d64h = 0.0;
#pragma unroll
                for (int c = 0; c < 16; ++c) d64h += fabs((double)col[c] - (double)nb[c]);
                double other = __shfl_xor(d64h, 1, 64);
                unsigned cc = (unsigned)((d64h + other) < thr);
                if ((bmask >> s) & 1) fmask = (fmask & ~(1u << s)) | (cc << s);
            }
        }
    }
    unsigned rmask = 0;                              // reverse bits via ballot (no bpermute)
#pragma unroll 1
    for (int s = 9; s <= 15; ++s) {
        int kbit = 16 - s;
        unsigned long long bal = __ballot((fmask >> kbit) & 1);
        int pl = ((pos - s) & 15) * 4 + c2;          // partner lane (same wl/half, pos-s)
        rmask |= (unsigned)((bal >> pl) & 1ull) << s;
    }
    float Mv[16];
#pragma unroll
    for (int c = 0; c < 16; ++c) Mv[c] = col[c];
    unsigned allm = (fmask & 0x1FEu) | rmask;        // bits 1..8 fwd, 9..15 rev
    while (allm) {                                   // lazy merge of SELECTED shifts only
        int s = __ffs(allm) - 1;
        allm &= allm - 1;
        int jj = (pos - s) & 15;
        LOAD_NB(Lr, jj);
#pragma unroll
        for (int c = 0; c < 16; ++c) Mv[c] = fmaxf(Mv[c], nb[c]);
    }
    size_t p = (size_t)F * FS + (size_t)(2 * pos + par) * AS + w0 + wl;
    store_m16(M + ((size_t)b * 65536 + p) * 32 + hf * 16, Mv);
}

// ---------------- unified passes kernel: balanced + local swizzle ----------------
__global__ __launch_bounds__(256) void k_passes(const float* __restrict__ x, const double2* __restrict__ npart,
                                                __half* __restrict__ Mw, __half* __restrict__ Mh,
                                                __half* __restrict__ Md) {
    __shared__ __align__(16) float L[4128];
    __shared__ double ls[4], lq[4], thrs[2];
    __shared__ float fb[8];
    int t = threadIdx.x;
    thr_reduce(npart, thrs, fb, ls, lq, t);
    int xcd = blockIdx.x & 7;
    int i = blockIdx.x >> 3;                         // 0..383
    int type = i >> 7;                               // 0:W 1:H 2:D (128 each per XCD)
    int u = xcd * 128 + (i & 127);                   // contiguous unit range per XCD
    if (type == 0) {
        // ---- W-axis: 4 rings (2 lines x 2 parities); one wave per ring ----
        int blk = u;
#pragma unroll
        for (int it = 0; it < 4; ++it) {
            int f = it * 256 + t;
            int ll = f >> 9;
            int l = blk * 2 + ll;
            int c = (f >> 4) & 31, wq = f & 15;
            const float* lb = x + (size_t)(l >> 10) * CDHW_ + ((l >> 5) & 31) * HW_ + (l & 31) * W_;
            float4 v = *(const float4*)(lb + (size_t)c * DHW_ + wq * 4);
            int cq = c >> 2, cr = c & 3;
            const float* ve = (const float*)&v;
#pragma unroll
            for (int e = 0; e < 4; ++e) {
                int wv2 = wq * 4 + e;
                int p = wv2 >> 1, par = wv2 & 1;
                L[(ll * 2 + par) * 1024 + p * 32 + (((cq ^ WSLOT(p)) << 2) | cr)] = ve[e];
            }
        }
        __syncthreads();
        int ring = t >> 6, ln = t & 63;
        int pos = ln >> 1, hf = ln & 1;
        int ll = ring >> 1, par = ring & 1;
        int l = blk * 2 + ll;
        int b = l >> 10, d = (l >> 5) & 31, h = l & 31;
        double thr = thrs[b];
        float tlo = fb[b*4], thi = fb[b*4+1], tmf = fb[b*4+2];
        const float* Lr = L + ring * 1024;
        int qb = hf * 4;
        float col[16], nb[16];
#pragma unroll
        for (int k = 0; k < 4; ++k) {
            float4 cv = *(const float4*)(Lr + pos * 32 + (((qb + k) ^ WSLOT(pos)) << 2));
            col[4*k] = cv.x; col[4*k+1] = cv.y; col[4*k+2] = cv.z; col[4*k+3] = cv.w;
        }
        unsigned fmask = 0, bmask = 0;
#pragma unroll 2
        for (int s = 1; s <= 16; ++s) {              // forward (incl s=16 self-pair): dist + mask only
            int jf = (pos - s) & 31;
            LOAD_NBW(Lr, jf);
            float dh = dist16(col, nb);
            float ds = dh + xor1_f(dh);              // DPP lane^1 (= ln^1 half partner)
            fmask |= (unsigned)(ds < tmf) << s;
            bmask |= (unsigned)((ds >= tlo) & (ds <= thi)) << s;
        }
        if (__ballot(bmask != 0)) {                  // rare fp64 fixup, wave-uniform
#pragma unroll 1
            for (int s = 1; s <= 16; ++s) {
                if (__ballot((bmask >> s) & 1)) {
                    int jf = (pos - s) & 31;
                    LOAD_NBW(Lr, jf);
                    double d64h = 0.0;
#pragma unroll
                    for (int c = 0; c < 16; ++c) d64h += fabs((double)col[c] - (double)nb[c]);
                    double other = __shfl_xor(d64h, 1, 64);
                    unsigned cc = (unsigned)((d64h + other) < thr);
                    if ((bmask >> s) & 1) fmask = (fmask & ~(1u << s)) | (cc << s);
                }
            }
        }
        unsigned rmask = 0;                          // reverse rs=32-s via ballot
#pragma unroll 1
        for (int s = 1; s <= 15; ++s) {
            unsigned long long bal = __ballot((fmask >> s) & 1);
            int pl2 = (((pos + s) & 31) << 1) + hf;  // partner lane (same half, pos+s)
            rmask |= (unsigned)((bal >> pl2) & 1ull) << (32 - s);
        }
        float Mv[16];
#pragma unroll
        for (int c = 0; c < 16; ++c) Mv[c] = col[c];
        unsigned allm = (fmask & 0x1FFFEu) | rmask;  // bits 1..16 fwd, 17..31 rev
        while (allm) {                               // lazy merge of SELECTED shifts only
            int s = __ffs(allm) - 1;
            allm &= allm - 1;
            int jj = (pos - s) & 31;
            LOAD_NBW(Lr, jj);
#pragma unroll
            for (int c = 0; c < 16; ++c) Mv[c] = fmaxf(Mv[c], nb[c]);
        }
        size_t ppt = (size_t)d * HW_ + h * W_ + 2 * pos + par;
        store_m16(Mw + ((size_t)b * 65536 + ppt) * 32 + hf * 16, Mv);
    } else if (type == 1) {
        hd_ring<W_, HW_>(x, Mh, thrs, fb, L, u, t);   // H pass (F = d)
    } else {
        hd_ring<HW_, W_>(x, Md, thrs, fb, L, u, t);   // D pass (F = h)
    }
}

// ---------------- conv (64->32) + fused BN partial stats; fp16 M, DPP stats reduce ----------------
__global__ __launch_bounds__(256, 4) void k_conv(const float* __restrict__ x,
                                                 const __half* __restrict__ Mw, const __half* __restrict__ Mh,
                                                 const __half* __restrict__ Md,
                                                 const float* __restrict__ w, const float* __restrict__ bias,
                                                 float* __restrict__ y, float2* __restrict__ spart) {
    int t = threadIdx.x;
    int blk = (blockIdx.x & 7) * 256 + (blockIdx.x >> 3);   // bijective XCD swizzle (2048 = 8*256)
    int b = blk >> 10;
    int p0 = (blk & 1023) * 64;
    int og = __builtin_amdgcn_readfirstlane(t >> 6);
    int pl = t & 63;
    const float* xb = x + (size_t)b * CDHW_ + p0 + pl;
    size_t moff = ((size_t)b * 65536 + p0 + pl) * 32;
    const int4* mw4 = (const int4*)(Mw + moff);
    const int4* mh4 = (const int4*)(Mh + moff);
    const int4* md4 = (const int4*)(Md + moff);
    const float* wo = w + og * 512;
    const float* bo = bias + og * 8;
    float a[8], xv[32];
#pragma unroll
    for (int k = 0; k < 8; ++k) a[k] = bo[k];
#pragma unroll
    for (int c = 0; c < 32; c += 4) {
        xv[c+0] = xb[(size_t)(c+0) * DHW_];
        xv[c+1] = xb[(size_t)(c+1) * DHW_];
        xv[c+2] = xb[(size_t)(c+2) * DHW_];
        xv[c+3] = xb[(size_t)(c+3) * DHW_];
#pragma unroll
        for (int k = 0; k < 8; ++k) {
            a[k] = fmaf(wo[k*64 + c+0], xv[c+0], a[k]);
            a[k] = fmaf(wo[k*64 + c+1], xv[c+1], a[k]);
            a[k] = fmaf(wo[k*64 + c+2], xv[c+2], a[k]);
            a[k] = fmaf(wo[k*64 + c+3], xv[c+3], a[k]);
        }
    }
#pragma unroll
    for (int i = 0; i < 4; ++i) {                    // 8 channels per int4 (fp16-packed)
        int4 aw = mw4[i], ah = mh4[i], ad = md4[i];
        const __half2* hw = (const __half2*)&aw;
        const __half2* hh = (const __half2*)&ah;
        const __half2* hd = (const __half2*)&ad;
#pragma unroll
        for (int j = 0; j < 4; ++j) {
            float2 fw = __half22float2(hw[j]);
            float2 fh = __half22float2(hh[j]);
            float2 fd = __half22float2(hd[j]);
            int c = i * 8 + j * 2;
            float z0 = fmaxf(fmaxf(fmaxf(fw.x, fh.x), fd.x) - xv[c+0], 0.f);
            float z1 = fmaxf(fmaxf(fmaxf(fw.y, fh.y), fd.y) - xv[c+1], 0.f);
#pragma unroll
            for (int k = 0; k < 8; ++k) {
                a[k] = fmaf(wo[k*64 + 32 + c+0], z0, a[k]);
                a[k] = fmaf(wo[k*64 + 32 + c+1], z1, a[k]);
            }
        }
    }
    float* yb = y + (size_t)b * CDHW_ + p0 + pl;
#pragma unroll
    for (int k = 0; k < 8; ++k) {
        yb[(size_t)(og * 8 + k) * DHW_] = a[k];
        float s = wave_sum63(a[k]);
        float q = wave_sum63(a[k] * a[k]);
        if (pl == STATS_LANE) spart[(og * 8 + k) * 2048 + blk] = make_float2(s, q);
    }
}

// ---------------- BN finalize + exact GELU, in-place ----------------
__global__ __launch_bounds__(256) void k_out(float* __restrict__ y, const float2* __restrict__ spart,
                                             const float* __restrict__ gamma, const float* __restrict__ beta) {
    int t = threadIdx.x;
    int o = (blockIdx.x >> 6) & 31;                  // block-uniform channel
    __shared__ double ls[4], lq[4];
    __shared__ float bnp[2];
    {
        const float2* sp = spart + o * 2048;
        double s = 0.0, q = 0.0;
#pragma unroll
        for (int i = 0; i < 8; ++i) {
            float2 v = sp[i * 256 + t];
            s += (double)v.x; q += (double)v.y;
        }
        for (int off = 32; off; off >>= 1) {
            s += __shfl_down(s, off, 64);
            q += __shfl_down(q, off, 64);
        }
        if ((t & 63) == 0) { ls[t >> 6] = s; lq[t >> 6] = q; }
    }
    __syncthreads();
    if (t == 0) {
        double sm = (ls[0] + ls[1]) + (ls[2] + ls[3]);
        double sq = (lq[0] + lq[1]) + (lq[2] + lq[3]);
        double mu = sm / (double)BN_N_;
        double var = sq / (double)BN_N_ - mu * mu;
        bnp[0] = (float)mu;
        bnp[1] = (float)(1.0 / sqrt(var + 1e-5));
    }
    __syncthreads();
    float mu_f = bnp[0], rstd = bnp[1];
    float g = gamma[o], be = beta[o];
    int idx = blockIdx.x * 256 + t;                  // over 1,048,576 float4
    float4 v = ((const float4*)y)[idx];
    float* vv = (float*)&v;
#pragma unroll
    for (int j = 0; j < 4; ++j) {
        float tt = (vv[j] - mu_f) * rstd * g + be;
        vv[j] = 0.5f * tt * (1.f + erff(tt * 0.70710678118654752f));
    }
    ((float4*)y)[idx] = v;
}

extern "C" void kernel_launch(void* const* d_in, const int* in_sizes, int n_in,
                              void* d_out, int out_size, void* d_ws, size_t ws_size,
                              hipStream_t stream) {
    const float* x     = (const float*)d_in[0];
    const float* w     = (const float*)d_in[1];
    const float* bias  = (const float*)d_in[2];
    const float* gamma = (const float*)d_in[3];
    const float* beta  = (const float*)d_in[4];
    float* out = (float*)d_out;
    __half* Mw = (__half*)d_ws;
    __half* Mh = (__half*)((char*)d_ws + MH_OFF);
    __half* Md = (__half*)((char*)d_ws + MD_OFF);
    double2* npart = (double2*)((char*)d_ws + RED_OFF + 256);
    float2*  spart = (float2*)((char*)d_ws + RED_OFF + 256 + 16384);

    k_norm  <<<512, 256, 0, stream>>>(x, npart);
    k_passes<<<3072, 256, 0, stream>>>(x, npart, Mw, Mh, Md);
    k_conv  <<<2048, 256, 0, stream>>>(x, Mw, Mh, Md, w, bias, out, spart);
    k_out   <<<4096, 256, 0, stream>>>(out, spart, gamma, beta);
}

// Round 22
// 84.482 us; speedup vs baseline: 1.3911x; 1.0086x over previous
//
#include <hip/hip_runtime.h>
#include <hip/hip_fp16.h>
#include <math.h>

#define B_ 2
#define C_ 32
#define D_ 32
#define H_ 32
#define W_ 64
#define HW_ (H_*W_)         // 2048
#define DHW_ (D_*H_*W_)     // 65536
#define CDHW_ (C_*DHW_)     // 2097152
#define NSP_ DHW_           // spatial points per batch
#define BN_N_ (B_*DHW_)     // 131072
#define BORDER 1e-4         // f32 dist err bound ~2e-5; 5x margin
#define RS 516              // padded LDS ring stride (floats)

// ws layout (fp16 M): Mw @0 (8MB), Mh @8MB, Md @16MB  — each [b][p][c] __half.
// reduction @48MB: npart[512] double2 @ +256, spart[32][2048] float2 @ +256+16384.
#define MH_OFF  (8u<<20)
#define MD_OFF  (16u<<20)
#define RED_OFF (48u<<20)

// lane^1 exchange on the VALU (DPP quad_perm [1,0,3,2]) — no LDS pipe, no latency.
__device__ __forceinline__ float xor1_f(float v) {
#if __has_builtin(__builtin_amdgcn_mov_dpp)
    return __int_as_float(__builtin_amdgcn_mov_dpp(__float_as_int(v), 0xB1, 0xF, 0xF, true));
#else
    return __shfl_xor(v, 1, 64);
#endif
}

// DPP wave-64 f32 add-reduce: lane 63 holds the full sum. ctrl/rmask are template consts.
#if __has_builtin(__builtin_amdgcn_update_dpp)
template<int CTRL, int RMASK>
__device__ __forceinline__ float dpp_add_step(float v) {
    int s = __builtin_amdgcn_update_dpp(0, __float_as_int(v), CTRL, RMASK, 0xF, true);
    return v + __int_as_float(s);
}
__device__ __forceinline__ float wave_sum63(float v) {
    v = dpp_add_step<0x111, 0xF>(v);   // row_shr:1
    v = dpp_add_step<0x112, 0xF>(v);   // row_shr:2
    v = dpp_add_step<0x114, 0xF>(v);   // row_shr:4
    v = dpp_add_step<0x118, 0xF>(v);   // row_shr:8  -> lane15/31/47/63 = row sums
    v = dpp_add_step<0x142, 0xA>(v);   // row_bcast:15 into rows 1,3
    v = dpp_add_step<0x143, 0xC>(v);   // row_bcast:31 into rows 2,3 -> lane63 = total
    return v;
}
#define STATS_LANE 63
#else
__device__ __forceinline__ float wave_sum63(float v) {
    for (int off = 32; off; off >>= 1) v += __shfl_down(v, off, 64);
    return v;
}
#define STATS_LANE 0
#endif

// ---------------- threshold stats: involution-halved, XCD-local swizzle ----------------
__global__ __launch_bounds__(256) void k_norm(const float* __restrict__ x, double2* __restrict__ npart) {
    int u = (blockIdx.x & 7) * 64 + (blockIdx.x >> 3);   // contiguous logical units per XCD
    int tid = u * 256 + threadIdx.x;
    int ln = threadIdx.x & 63;
    int hf = ln >> 5, lp = ln & 31;
    int ph = (tid >> 6) * 32 + lp;                  // 0..65535 half-space points (2x lane coverage)
    int b = ph >> 15;
    int pp = ph & 32767;                            // (d<<11)|(h<<6)|w with d in 0..15
    int d = pp >> 11, h = (pp >> 6) & 31, w = pp & 63;
    int pf = ((d ^ 16) << 11) | ((h ^ 16) << 6) | (w ^ 32);
    const float* xb = x + (size_t)b * CDHW_ + (size_t)hf * 16 * DHW_;
    double s = 0.0;
#pragma unroll
    for (int c = 0; c < 16; ++c) {
        float a  = xb[c * DHW_ + pp];
        float bb = xb[c * DHW_ + pf];
        s += fabs((double)a - (double)bb);
    }
    double st = s + __shfl_xor(s, 32, 64);          // full 32-ch sum (both halves hold it)
    double s2 = st * st;
    for (int off = 32; off; off >>= 1) {
        st += __shfl_down(st, off, 64);
        s2 += __shfl_down(s2, off, 64);
    }
    __shared__ double ls[4], ls2[4];
    int wv = threadIdx.x >> 6;
    if (ln == 0) { ls[wv] = st; ls2[wv] = s2; }
    __syncthreads();
    if (threadIdx.x == 0) {
        double2 o;                                   // 2-lane dup == involution doubling
        o.x = (ls[0] + ls[1]) + (ls[2] + ls[3]);
        o.y = (ls2[0] + ls2[1]) + (ls2[2] + ls2[3]);
        npart[u] = o;                                // same slot/value as unswizzled
    }
}

// ---------------- per-block redundant thr reduce + f32 gate bounds ----------------
__device__ __forceinline__ void thr_reduce(const double2* __restrict__ npart, double* thrs, float* fb,
                                           double* ls, double* lq, int t) {
    {
        double s = 0.0, q = 0.0;
#pragma unroll
        for (int i = 0; i < 2; ++i) {
            double2 v = npart[t * 2 + i];
            s += v.x; q += v.y;
        }
        for (int off = 32; off; off >>= 1) {
            s += __shfl_down(s, off, 64);
            q += __shfl_down(q, off, 64);
        }
        if ((t & 63) == 0) { ls[t >> 6] = s; lq[t >> 6] = q; }
    }
    __syncthreads();
    if (t < 2) {
        double sum = ls[2 * t] + ls[2 * t + 1];
        double sq  = lq[2 * t] + lq[2 * t + 1];
        double n = (double)NSP_;
        double mean = sum / n;
        double var = (sq - sum * sum / n) / (n - 1.0);   // ddof=1
        if (var < 0.0) var = 0.0;
        double thrv = mean - sqrt(var);
        thrs[t] = thrv;
        fb[t * 4 + 0] = (float)(thrv - BORDER * 1.01);
        fb[t * 4 + 1] = (float)(thrv + BORDER * 1.01);
        fb[t * 4 + 2] = (float)thrv;
    }
    __syncthreads();
}

// float4-native dist over 16 channels; summation order identical to scalar version:
// d0 sums .x over k=0..3 (c = 0,4,8,12), etc.; final (d0+d1)+(d2+d3).
__device__ __forceinline__ float dist16v(const float4* a, const float4* b) {
    float d0 = 0.f, d1 = 0.f, d2 = 0.f, d3 = 0.f;
#pragma unroll
    for (int k = 0; k < 4; ++k) {
        d0 += fabsf(a[k].x - b[k].x);
        d1 += fabsf(a[k].y - b[k].y);
        d2 += fabsf(a[k].z - b[k].z);
        d3 += fabsf(a[k].w - b[k].w);
    }
    return (d0 + d1) + (d2 + d3);
}

__device__ __forceinline__ void store_m16v(__half* mp, const float4* Mv4) {
    __half2 tmp[8];
#pragma unroll
    for (int q = 0; q < 4; ++q) {
        tmp[2*q]   = __floats2half2_rn(Mv4[q].x, Mv4[q].y);
        tmp[2*q+1] = __floats2half2_rn(Mv4[q].z, Mv4[q].w);
    }
    *(int4*)mp       = *(int4*)&tmp[0];
    *(int4*)(mp + 8) = *(int4*)&tmp[4];
}

#define LOAD_NB4(LRP, JJ) \
    { _Pragma("unroll") for (int k = 0; k < 4; ++k) \
        nv4[k] = *(const float4*)((LRP) + (JJ) * 32 + (((qb + k) ^ ((JJ) & 7)) << 2)); }

// W-pass hash: include high pos bits so pos, pos+8, pos+16, pos+24 get distinct slots.
#define WSLOT(JJ) (((JJ) + ((JJ) >> 3)) & 7)
#define LOAD_NB4W(LRP, JJ) \
    { _Pragma("unroll") for (int k = 0; k < 4; ++k) \
        nv4[k] = *(const float4*)((LRP) + (JJ) * 32 + (((qb + k) ^ WSLOT(JJ)) << 2)); }

// f64 fixup sum in the original c=0..15 order (k outer, xyzw inner)
#define D64_ACC(A, B, ACC) \
    { _Pragma("unroll") for (int k = 0; k < 4; ++k) { \
        ACC += fabs((double)(A)[k].x - (double)(B)[k].x); \
        ACC += fabs((double)(A)[k].y - (double)(B)[k].y); \
        ACC += fabs((double)(A)[k].z - (double)(B)[k].z); \
        ACC += fabs((double)(A)[k].w - (double)(B)[k].w); } }

#define MERGE_MAX4(MV, NV) \
    { _Pragma("unroll") for (int k = 0; k < 4; ++k) { \
        (MV)[k].x = fmaxf((MV)[k].x, (NV)[k].x); (MV)[k].y = fmaxf((MV)[k].y, (NV)[k].y); \
        (MV)[k].z = fmaxf((MV)[k].z, (NV)[k].z); (MV)[k].w = fmaxf((MV)[k].w, (NV)[k].w); } }

// H/D ring body. 256 threads, 8 rings (one parity). float4-native hot path.
template<int AS, int FS>
__device__ __forceinline__ void hd_ring(const float* __restrict__ x, __half* __restrict__ M,
                                        const double* thrs, const float* fb, float* L, int local, int t) {
    int par = local & 1, wt = (local >> 1) & 7, F = (local >> 4) & 31, b = local >> 9;
    int w0 = wt * 8;
    double thr = thrs[b];
    float tlo = fb[b*4], thi = fb[b*4+1], tmf = fb[b*4+2];
    const float* xb = x + (size_t)b * CDHW_ + (size_t)F * FS + w0;
#pragma unroll
    for (int it = 0; it < 4; ++it) {
        int f = it * 256 + t;                        // 0..1023 float4s
        int c = f >> 5, rem = f & 31, j = rem >> 1, wq = rem & 1;
        float4 v = *(const float4*)(xb + (size_t)c * DHW_ + (size_t)(2 * j + par) * AS + wq * 4);
        int sl = (((c >> 2) ^ (j & 7)) << 2) + (c & 3);
        int rb = (wq * 4) * RS + j * 32 + sl;
        L[rb] = v.x; L[rb + RS] = v.y; L[rb + 2*RS] = v.z; L[rb + 3*RS] = v.w;
    }
    __syncthreads();
    int ln = t & 63, wave = t >> 6;
    int pos = ln >> 2, c2 = ln & 3;
    int wl = wave * 2 + (c2 >> 1), hf = c2 & 1;
    const float* Lr = L + wl * RS;
    int qb = hf * 4;
    float4 col4[4], nv4[4];
#pragma unroll
    for (int k = 0; k < 4; ++k)
        col4[k] = *(const float4*)(Lr + pos * 32 + (((qb + k) ^ (pos & 7)) << 2));
    unsigned fmask = 0, bmask = 0;
#pragma unroll 2
    for (int s = 1; s <= 8; ++s) {                   // forward: dist + mask bits only
        int jj = (pos - s) & 15;
        LOAD_NB4(Lr, jj);
        float dh = dist16v(col4, nv4);
        float ds = dh + xor1_f(dh);                  // DPP lane^1 — same value both paired lanes
        fmask |= (unsigned)(ds < tmf) << s;
        bmask |= (unsigned)((ds >= tlo) & (ds <= thi)) << s;
    }
    if (__ballot(bmask != 0)) {                      // rare fp64 fixup, wave-uniform
#pragma unroll 1
        for (int s = 1; s <= 8; ++s) {
            if (__ballot((bmask >> s) & 1)) {
                int jj = (pos - s) & 15;
                LOAD_NB4(Lr, jj);
                double d64h = 0.0;
                D64_ACC(col4, nv4, d64h);
                double other = __shfl_xor(d64h, 1, 64);
                unsigned cc = (unsigned)((d64h + other) < thr);
                if ((bmask >> s) & 1) fmask = (fmask & ~(1u << s)) | (cc << s);
            }
        }
    }
    unsigned rmask = 0;                              // reverse bits via ballot (no bpermute)
#pragma unroll 1
    for (int s = 9; s <= 15; ++s) {
        int kbit = 16 - s;
        unsigned long long bal = __ballot((fmask >> kbit) & 1);
        int pl = ((pos - s) & 15) * 4 + c2;          // partner lane (same wl/half, pos-s)
        rmask |= (unsigned)((bal >> pl) & 1ull) << s;
    }
    float4 Mv4[4];
#pragma unroll
    for (int k = 0; k < 4; ++k) Mv4[k] = col4[k];
    unsigned allm = (fmask & 0x1FEu) | rmask;        // bits 1..8 fwd, 9..15 rev
    while (allm) {                                   // lazy merge of SELECTED shifts only
        int s = __ffs(allm) - 1;
        allm &= allm - 1;
        int jj = (pos - s) & 15;
        LOAD_NB4(Lr, jj);
        MERGE_MAX4(Mv4, nv4);
    }
    size_t p = (size_t)F * FS + (size_t)(2 * pos + par) * AS + w0 + wl;
    store_m16v(M + ((size_t)b * 65536 + p) * 32 + hf * 16, Mv4);
}

// ---------------- unified passes kernel: balanced + local swizzle ----------------
__global__ __launch_bounds__(256) void k_passes(const float* __restrict__ x, const double2* __restrict__ npart,
                                                __half* __restrict__ Mw, __half* __restrict__ Mh,
                                                __half* __restrict__ Md) {
    __shared__ __align__(16) float L[4128];
    __shared__ double ls[4], lq[4], thrs[2];
    __shared__ float fb[8];
    int t = threadIdx.x;
    thr_reduce(npart, thrs, fb, ls, lq, t);
    int xcd = blockIdx.x & 7;
    int i = blockIdx.x >> 3;                         // 0..383
    int type = i >> 7;                               // 0:W 1:H 2:D (128 each per XCD)
    int u = xcd * 128 + (i & 127);                   // contiguous unit range per XCD
    if (type == 0) {
        // ---- W-axis: 4 rings (2 lines x 2 parities); one wave per ring ----
        int blk = u;
#pragma unroll
        for (int it = 0; it < 4; ++it) {
            int f = it * 256 + t;
            int ll = f >> 9;
            int l = blk * 2 + ll;
            int c = (f >> 4) & 31, wq = f & 15;
            const float* lb = x + (size_t)(l >> 10) * CDHW_ + ((l >> 5) & 31) * HW_ + (l & 31) * W_;
            float4 v = *(const float4*)(lb + (size_t)c * DHW_ + wq * 4);
            int cq = c >> 2, cr = c & 3;
            const float* ve = (const float*)&v;
#pragma unroll
            for (int e = 0; e < 4; ++e) {
                int wv2 = wq * 4 + e;
                int p = wv2 >> 1, par = wv2 & 1;
                L[(ll * 2 + par) * 1024 + p * 32 + (((cq ^ WSLOT(p)) << 2) | cr)] = ve[e];
            }
        }
        __syncthreads();
        int ring = t >> 6, ln = t & 63;
        int pos = ln >> 1, hf = ln & 1;
        int ll = ring >> 1, par = ring & 1;
        int l = blk * 2 + ll;
        int b = l >> 10, d = (l >> 5) & 31, h = l & 31;
        double thr = thrs[b];
        float tlo = fb[b*4], thi = fb[b*4+1], tmf = fb[b*4+2];
        const float* Lr = L + ring * 1024;
        int qb = hf * 4;
        float4 col4[4], nv4[4];
#pragma unroll
        for (int k = 0; k < 4; ++k)
            col4[k] = *(const float4*)(Lr + pos * 32 + (((qb + k) ^ WSLOT(pos)) << 2));
        unsigned fmask = 0, bmask = 0;
#pragma unroll 2
        for (int s = 1; s <= 16; ++s) {              // forward (incl s=16 self-pair): dist + mask only
            int jf = (pos - s) & 31;
            LOAD_NB4W(Lr, jf);
            float dh = dist16v(col4, nv4);
            float ds = dh + xor1_f(dh);              // DPP lane^1 (= ln^1 half partner)
            fmask |= (unsigned)(ds < tmf) << s;
            bmask |= (unsigned)((ds >= tlo) & (ds <= thi)) << s;
        }
        if (__ballot(bmask != 0)) {                  // rare fp64 fixup, wave-uniform
#pragma unroll 1
            for (int s = 1; s <= 16; ++s) {
                if (__ballot((bmask >> s) & 1)) {
                    int jf = (pos - s) & 31;
                    LOAD_NB4W(Lr, jf);
                    double d64h = 0.0;
                    D64_ACC(col4, nv4, d64h);
                    double other = __shfl_xor(d64h, 1, 64);
                    unsigned cc = (unsigned)((d64h + other) < thr);
                    if ((bmask >> s) & 1) fmask = (fmask & ~(1u << s)) | (cc << s);
                }
            }
        }
        unsigned rmask = 0;                          // reverse rs=32-s via ballot
#pragma unroll 1
        for (int s = 1; s <= 15; ++s) {
            unsigned long long bal = __ballot((fmask >> s) & 1);
            int pl2 = (((pos + s) & 31) << 1) + hf;  // partner lane (same half, pos+s)
            rmask |= (unsigned)((bal >> pl2) & 1ull) << (32 - s);
        }
        float4 Mv4[4];
#pragma unroll
        for (int k = 0; k < 4; ++k) Mv4[k] = col4[k];
        unsigned allm = (fmask & 0x1FFFEu) | rmask;  // bits 1..16 fwd, 17..31 rev
        while (allm) {                               // lazy merge of SELECTED shifts only
            int s = __ffs(allm) - 1;
            allm &= allm - 1;
            int jj = (pos - s) & 31;
            LOAD_NB4W(Lr, jj);
            MERGE_MAX4(Mv4, nv4);
        }
        size_t ppt = (size_t)d * HW_ + h * W_ + 2 * pos + par;
        store_m16v(Mw + ((size_t)b * 65536 + ppt) * 32 + hf * 16, Mv4);
    } else if (type == 1) {
        hd_ring<W_, HW_>(x, Mh, thrs, fb, L, u, t);   // H pass (F = d)
    } else {
        hd_ring<HW_, W_>(x, Md, thrs, fb, L, u, t);   // D pass (F = h)
    }
}

// ---------------- conv (64->32) + fused BN partial stats; fp16 M, DPP stats reduce ----------------
__global__ __launch_bounds__(256, 4) void k_conv(const float* __restrict__ x,
                                                 const __half* __restrict__ Mw, const __half* __restrict__ Mh,
                                                 const __half* __restrict__ Md,
                                                 const float* __restrict__ w, const float* __restrict__ bias,
                                                 float* __restrict__ y, float2* __restrict__ spart) {
    int t = threadIdx.x;
    int blk = (blockIdx.x & 7) * 256 + (blockIdx.x >> 3);   // bijective XCD swizzle (2048 = 8*256)
    int b = blk >> 10;
    int p0 = (blk & 1023) * 64;
    int og = __builtin_amdgcn_readfirstlane(t >> 6);
    int pl = t & 63;
    const float* xb = x + (size_t)b * CDHW_ + p0 + pl;
    size_t moff = ((size_t)b * 65536 + p0 + pl) * 32;
    const int4* mw4 = (const int4*)(Mw + moff);
    const int4* mh4 = (const int4*)(Mh + moff);
    const int4* md4 = (const int4*)(Md + moff);
    const float* wo = w + og * 512;
    const float* bo = bias + og * 8;
    float a[8], xv[32];
#pragma unroll
    for (int k = 0; k < 8; ++k) a[k] = bo[k];
#pragma unroll
    for (int c = 0; c < 32; c += 4) {
        xv[c+0] = xb[(size_t)(c+0) * DHW_];
        xv[c+1] = xb[(size_t)(c+1) * DHW_];
        xv[c+2] = xb[(size_t)(c+2) * DHW_];
        xv[c+3] = xb[(size_t)(c+3) * DHW_];
#pragma unroll
        for (int k = 0; k < 8; ++k) {
            a[k] = fmaf(wo[k*64 + c+0], xv[c+0], a[k]);
            a[k] = fmaf(wo[k*64 + c+1], xv[c+1], a[k]);
            a[k] = fmaf(wo[k*64 + c+2], xv[c+2], a[k]);
            a[k] = fmaf(wo[k*64 + c+3], xv[c+3], a[k]);
        }
    }
#pragma unroll
    for (int i = 0; i < 4; ++i) {                    // 8 channels per int4 (fp16-packed)
        int4 aw = mw4[i], ah = mh4[i], ad = md4[i];
        const __half2* hw = (const __half2*)&aw;
        const __half2* hh = (const __half2*)&ah;
        const __half2* hd = (const __half2*)&ad;
#pragma unroll
        for (int j = 0; j < 4; ++j) {
            float2 fw = __half22float2(hw[j]);
            float2 fh = __half22float2(hh[j]);
            float2 fd = __half22float2(hd[j]);
            int c = i * 8 + j * 2;
            float z0 = fmaxf(fmaxf(fmaxf(fw.x, fh.x), fd.x) - xv[c+0], 0.f);
            float z1 = fmaxf(fmaxf(fmaxf(fw.y, fh.y), fd.y) - xv[c+1], 0.f);
#pragma unroll
            for (int k = 0; k < 8; ++k) {
                a[k] = fmaf(wo[k*64 + 32 + c+0], z0, a[k]);
                a[k] = fmaf(wo[k*64 + 32 + c+1], z1, a[k]);
            }
        }
    }
    float* yb = y + (size_t)b * CDHW_ + p0 + pl;
#pragma unroll
    for (int k = 0; k < 8; ++k) {
        yb[(size_t)(og * 8 + k) * DHW_] = a[k];
        float s = wave_sum63(a[k]);
        float q = wave_sum63(a[k] * a[k]);
        if (pl == STATS_LANE) spart[(og * 8 + k) * 2048 + blk] = make_float2(s, q);
    }
}

// ---------------- BN finalize + exact GELU, in-place; 1024 blocks x 4 float4/thread ----------------
__global__ __launch_bounds__(256) void k_out(float* __restrict__ y, const float2* __restrict__ spart,
                                             const float* __restrict__ gamma, const float* __restrict__ beta) {
    int t = threadIdx.x;
    int o = (blockIdx.x >> 4) & 31;                  // block-uniform channel (1024-f4 slab per block)
    __shared__ double ls[4], lq[4];
    __shared__ float bnp[2];
    {
        const float2* sp = spart + o * 2048;
        double s = 0.0, q = 0.0;
#pragma unroll
        for (int i = 0; i < 8; ++i) {
            float2 v = sp[i * 256 + t];
            s += (double)v.x; q += (double)v.y;
        }
        for (int off = 32; off; off >>= 1) {
            s += __shfl_down(s, off, 64);
            q += __shfl_down(q, off, 64);
        }
        if ((t & 63) == 0) { ls[t >> 6] = s; lq[t >> 6] = q; }
    }
    __syncthreads();
    if (t == 0) {
        double sm = (ls[0] + ls[1]) + (ls[2] + ls[3]);
        double sq = (lq[0] + lq[1]) + (lq[2] + lq[3]);
        double mu = sm / (double)BN_N_;
        double var = sq / (double)BN_N_ - mu * mu;
        bnp[0] = (float)mu;
        bnp[1] = (float)(1.0 / sqrt(var + 1e-5));
    }
    __syncthreads();
    float mu_f = bnp[0], rstd = bnp[1];
    float g = gamma[o], be = beta[o];
    float4* yv = (float4*)y;
#pragma unroll
    for (int i = 0; i < 4; ++i) {
        int idx = blockIdx.x * 1024 + i * 256 + t;   // over 1,048,576 float4
        float4 v = yv[idx];
        float* vv = (float*)&v;
#pragma unroll
        for (int j = 0; j < 4; ++j) {
            float tt = (vv[j] - mu_f) * rstd * g + be;
            vv[j] = 0.5f * tt * (1.f + erff(tt * 0.70710678118654752f));
        }
        yv[idx] = v;
    }
}

extern "C" void kernel_launch(void* const* d_in, const int* in_sizes, int n_in,
                              void* d_out, int out_size, void* d_ws, size_t ws_size,
                              hipStream_t stream) {
    const float* x     = (const float*)d_in[0];
    const float* w     = (const float*)d_in[1];
    const float* bias  = (const float*)d_in[2];
    const float* gamma = (const float*)d_in[3];
    const float* beta  = (const float*)d_in[4];
    float* out = (float*)d_out;
    __half* Mw = (__half*)d_ws;
    __half* Mh = (__half*)((char*)d_ws + MH_OFF);
    __half* Md = (__half*)((char*)d_ws + MD_OFF);
    double2* npart = (double2*)((char*)d_ws + RED_OFF + 256);
    float2*  spart = (float2*)((char*)d_ws + RED_OFF + 256 + 16384);

    k_norm  <<<512, 256, 0, stream>>>(x, npart);
    k_passes<<<3072, 256, 0, stream>>>(x, npart, Mw, Mh, Md);
    k_conv  <<<2048, 256, 0, stream>>>(x, Mw, Mh, Md, w, bias, out, spart);
    k_out   <<<1024, 256, 0, stream>>>(out, spart, gamma, beta);
}

// Round 23
// 84.282 us; speedup vs baseline: 1.3944x; 1.0024x over previous
//
#include <hip/hip_runtime.h>
#include <hip/hip_fp16.h>
#include <math.h>

#define B_ 2
#define C_ 32
#define D_ 32
#define H_ 32
#define W_ 64
#define HW_ (H_*W_)         // 2048
#define DHW_ (D_*H_*W_)     // 65536
#define CDHW_ (C_*DHW_)     // 2097152
#define NSP_ DHW_           // spatial points per batch
#define BN_N_ (B_*DHW_)     // 131072
#define BORDER 1e-4         // f32 dist err bound ~2e-5; 5x margin
#define RS 516              // padded LDS ring stride (floats)

// ws layout (fp16 M): Mw @0 (8MB), Mh @8MB, Md @16MB  — each [b][p][c] __half.
// reduction @48MB: npart[64] double2 @ +256, spart[32][2048] float2 @ +256+16384.
#define MH_OFF  (8u<<20)
#define MD_OFF  (16u<<20)
#define RED_OFF (48u<<20)

// lane^1 exchange on the VALU (DPP quad_perm [1,0,3,2]) — no LDS pipe, no latency.
__device__ __forceinline__ float xor1_f(float v) {
#if __has_builtin(__builtin_amdgcn_mov_dpp)
    return __int_as_float(__builtin_amdgcn_mov_dpp(__float_as_int(v), 0xB1, 0xF, 0xF, true));
#else
    return __shfl_xor(v, 1, 64);
#endif
}

// DPP wave-64 f32 add-reduce: lane 63 holds the full sum. ctrl/rmask are template consts.
#if __has_builtin(__builtin_amdgcn_update_dpp)
template<int CTRL, int RMASK>
__device__ __forceinline__ float dpp_add_step(float v) {
    int s = __builtin_amdgcn_update_dpp(0, __float_as_int(v), CTRL, RMASK, 0xF, true);
    return v + __int_as_float(s);
}
__device__ __forceinline__ float wave_sum63(float v) {
    v = dpp_add_step<0x111, 0xF>(v);   // row_shr:1
    v = dpp_add_step<0x112, 0xF>(v);   // row_shr:2
    v = dpp_add_step<0x114, 0xF>(v);   // row_shr:4
    v = dpp_add_step<0x118, 0xF>(v);   // row_shr:8  -> lane15/31/47/63 = row sums
    v = dpp_add_step<0x142, 0xA>(v);   // row_bcast:15 into rows 1,3
    v = dpp_add_step<0x143, 0xC>(v);   // row_bcast:31 into rows 2,3 -> lane63 = total
    return v;
}
#define STATS_LANE 63
#else
__device__ __forceinline__ float wave_sum63(float v) {
    for (int off = 32; off; off >>= 1) v += __shfl_down(v, off, 64);
    return v;
}
#define STATS_LANE 0
#endif

// ---------------- threshold stats: involution-halved; 64 blocks x 1024 thr -> npart[64] ----------------
__global__ __launch_bounds__(1024) void k_norm(const float* __restrict__ x, double2* __restrict__ npart) {
    int nb = (blockIdx.x & 7) * 8 + (blockIdx.x >> 3);   // contiguous logical units per XCD
    int t = threadIdx.x;
    int ln = t & 63;
    int hf = ln >> 5, lp = ln & 31;
    double sum_st = 0.0, sum_sq = 0.0;
#pragma unroll
    for (int it = 0; it < 2; ++it) {
        int uold = nb * 8 + it * 4 + (t >> 8);       // old 256-thread unit
        int tid = uold * 256 + (t & 255);
        int ph = (tid >> 6) * 32 + lp;               // half-space points (2x lane coverage)
        int b = ph >> 15;
        int pp = ph & 32767;                         // (d<<11)|(h<<6)|w with d in 0..15
        int d = pp >> 11, h = (pp >> 6) & 31, w = pp & 63;
        int pf = ((d ^ 16) << 11) | ((h ^ 16) << 6) | (w ^ 32);
        const float* xb = x + (size_t)b * CDHW_ + (size_t)hf * 16 * DHW_;
        double s = 0.0;
#pragma unroll
        for (int c = 0; c < 16; ++c) {
            float a  = xb[c * DHW_ + pp];
            float bb = xb[c * DHW_ + pf];
            s += fabs((double)a - (double)bb);
        }
        double st = s + __shfl_xor(s, 32, 64);       // full 32-ch sum (both halves hold it)
        sum_st += st;
        sum_sq += st * st;                           // squared per POINT
    }
    for (int off = 32; off; off >>= 1) {
        sum_st += __shfl_down(sum_st, off, 64);
        sum_sq += __shfl_down(sum_sq, off, 64);
    }
    __shared__ double ls[16], ls2[16];
    int wv = t >> 6;
    if (ln == 0) { ls[wv] = sum_st; ls2[wv] = sum_sq; }
    __syncthreads();
    if (t == 0) {
        double a = 0.0, b2 = 0.0;
#pragma unroll
        for (int i = 0; i < 16; ++i) { a += ls[i]; b2 += ls2[i]; }
        double2 o; o.x = a; o.y = b2;                // 2-lane dup == involution doubling
        npart[nb] = o;                               // nb<32 -> batch 0, nb>=32 -> batch 1
    }
}

// ---------------- slim per-block thr reduce: single wave, 64 partials ----------------
__device__ __forceinline__ void thr_reduce(const double2* __restrict__ npart, double* thrs, float* fb, int t) {
    if (t < 64) {
        double2 v = npart[t];
        double s = v.x, q = v.y;
        for (int off = 16; off; off >>= 1) {         // XOR keeps lanes within 32-aligned batch group
            s += __shfl_xor(s, off, 64);
            q += __shfl_xor(q, off, 64);
        }
        if ((t & 31) == 0) {                         // lane 0 -> b0, lane 32 -> b1
            int b = t >> 5;
            double n = (double)NSP_;
            double mean = s / n;
            double var = (q - s * s / n) / (n - 1.0);   // ddof=1
            if (var < 0.0) var = 0.0;
            double thrv = mean - sqrt(var);
            thrs[b] = thrv;
            fb[b * 4 + 0] = (float)(thrv - BORDER * 1.01);
            fb[b * 4 + 1] = (float)(thrv + BORDER * 1.01);
            fb[b * 4 + 2] = (float)thrv;
        }
    }
    __syncthreads();
}

// float4-native dist over 16 channels; summation order identical to scalar version.
__device__ __forceinline__ float dist16v(const float4* a, const float4* b) {
    float d0 = 0.f, d1 = 0.f, d2 = 0.f, d3 = 0.f;
#pragma unroll
    for (int k = 0; k < 4; ++k) {
        d0 += fabsf(a[k].x - b[k].x);
        d1 += fabsf(a[k].y - b[k].y);
        d2 += fabsf(a[k].z - b[k].z);
        d3 += fabsf(a[k].w - b[k].w);
    }
    return (d0 + d1) + (d2 + d3);
}

__device__ __forceinline__ void store_m16v(__half* mp, const float4* Mv4) {
    __half2 tmp[8];
#pragma unroll
    for (int q = 0; q < 4; ++q) {
        tmp[2*q]   = __floats2half2_rn(Mv4[q].x, Mv4[q].y);
        tmp[2*q+1] = __floats2half2_rn(Mv4[q].z, Mv4[q].w);
    }
    *(int4*)mp       = *(int4*)&tmp[0];
    *(int4*)(mp + 8) = *(int4*)&tmp[4];
}

#define LOAD_NB4(LRP, JJ) \
    { _Pragma("unroll") for (int k = 0; k < 4; ++k) \
        nv4[k] = *(const float4*)((LRP) + (JJ) * 32 + (((qb + k) ^ ((JJ) & 7)) << 2)); }

// W-pass hash: include high pos bits so pos, pos+8, pos+16, pos+24 get distinct slots.
#define WSLOT(JJ) (((JJ) + ((JJ) >> 3)) & 7)
#define LOAD_NB4W(LRP, JJ) \
    { _Pragma("unroll") for (int k = 0; k < 4; ++k) \
        nv4[k] = *(const float4*)((LRP) + (JJ) * 32 + (((qb + k) ^ WSLOT(JJ)) << 2)); }

// f64 fixup sum in the original c=0..15 order (k outer, xyzw inner)
#define D64_ACC(A, B, ACC) \
    { _Pragma("unroll") for (int k = 0; k < 4; ++k) { \
        ACC += fabs((double)(A)[k].x - (double)(B)[k].x); \
        ACC += fabs((double)(A)[k].y - (double)(B)[k].y); \
        ACC += fabs((double)(A)[k].z - (double)(B)[k].z); \
        ACC += fabs((double)(A)[k].w - (double)(B)[k].w); } }

#define MERGE_MAX4(MV, NV) \
    { _Pragma("unroll") for (int k = 0; k < 4; ++k) { \
        (MV)[k].x = fmaxf((MV)[k].x, (NV)[k].x); (MV)[k].y = fmaxf((MV)[k].y, (NV)[k].y); \
        (MV)[k].z = fmaxf((MV)[k].z, (NV)[k].z); (MV)[k].w = fmaxf((MV)[k].w, (NV)[k].w); } }

// H/D ring body. 256 threads, 8 rings (one parity). float4-native hot path.
template<int AS, int FS>
__device__ __forceinline__ void hd_ring(const float* __restrict__ x, __half* __restrict__ M,
                                        const double* thrs, const float* fb, float* L, int local, int t) {
    int par = local & 1, wt = (local >> 1) & 7, F = (local >> 4) & 31, b = local >> 9;
    int w0 = wt * 8;
    double thr = thrs[b];
    float tlo = fb[b*4], thi = fb[b*4+1], tmf = fb[b*4+2];
    const float* xb = x + (size_t)b * CDHW_ + (size_t)F * FS + w0;
#pragma unroll
    for (int it = 0; it < 4; ++it) {
        int f = it * 256 + t;                        // 0..1023 float4s
        int c = f >> 5, rem = f & 31, j = rem >> 1, wq = rem & 1;
        float4 v = *(const float4*)(xb + (size_t)c * DHW_ + (size_t)(2 * j + par) * AS + wq * 4);
        int sl = (((c >> 2) ^ (j & 7)) << 2) + (c & 3);
        int rb = (wq * 4) * RS + j * 32 + sl;
        L[rb] = v.x; L[rb + RS] = v.y; L[rb + 2*RS] = v.z; L[rb + 3*RS] = v.w;
    }
    __syncthreads();
    int ln = t & 63, wave = t >> 6;
    int pos = ln >> 2, c2 = ln & 3;
    int wl = wave * 2 + (c2 >> 1), hf = c2 & 1;
    const float* Lr = L + wl * RS;
    int qb = hf * 4;
    float4 col4[4], nv4[4];
#pragma unroll
    for (int k = 0; k < 4; ++k)
        col4[k] = *(const float4*)(Lr + pos * 32 + (((qb + k) ^ (pos & 7)) << 2));
    unsigned fmask = 0, bmask = 0;
#pragma unroll 2
    for (int s = 1; s <= 8; ++s) {                   // forward: dist + mask bits only
        int jj = (pos - s) & 15;
        LOAD_NB4(Lr, jj);
        float dh = dist16v(col4, nv4);
        float ds = dh + xor1_f(dh);                  // DPP lane^1 — same value both paired lanes
        fmask |= (unsigned)(ds < tmf) << s;
        bmask |= (unsigned)((ds >= tlo) & (ds <= thi)) << s;
    }
    if (__ballot(bmask != 0)) {                      // rare fp64 fixup, wave-uniform
#pragma unroll 1
        for (int s = 1; s <= 8; ++s) {
            if (__ballot((bmask >> s) & 1)) {
                int jj = (pos - s) & 15;
                LOAD_NB4(Lr, jj);
                double d64h = 0.0;
                D64_ACC(col4, nv4, d64h);
                double other = __shfl_xor(d64h, 1, 64);
                unsigned cc = (unsigned)((d64h + other) < thr);
                if ((bmask >> s) & 1) fmask = (fmask & ~(1u << s)) | (cc << s);
            }
        }
    }
    unsigned rmask = 0;                              // reverse bits via ballot (no bpermute)
#pragma unroll 1
    for (int s = 9; s <= 15; ++s) {
        int kbit = 16 - s;
        unsigned long long bal = __ballot((fmask >> kbit) & 1);
        int pl = ((pos - s) & 15) * 4 + c2;          // partner lane (same wl/half, pos-s)
        rmask |= (unsigned)((bal >> pl) & 1ull) << s;
    }
    float4 Mv4[4];
#pragma unroll
    for (int k = 0; k < 4; ++k) Mv4[k] = col4[k];
    unsigned allm = (fmask & 0x1FEu) | rmask;        // bits 1..8 fwd, 9..15 rev
    while (allm) {                                   // lazy merge of SELECTED shifts only
        int s = __ffs(allm) - 1;
        allm &= allm - 1;
        int jj = (pos - s) & 15;
        LOAD_NB4(Lr, jj);
        MERGE_MAX4(Mv4, nv4);
    }
    size_t p = (size_t)F * FS + (size_t)(2 * pos + par) * AS + w0 + wl;
    store_m16v(M + ((size_t)b * 65536 + p) * 32 + hf * 16, Mv4);
}

// ---------------- unified passes kernel: balanced + local swizzle ----------------
__global__ __launch_bounds__(256) void k_passes(const float* __restrict__ x, const double2* __restrict__ npart,
                                                __half* __restrict__ Mw, __half* __restrict__ Mh,
                                                __half* __restrict__ Md) {
    __shared__ __align__(16) float L[4128];
    __shared__ double thrs[2];
    __shared__ float fb[8];
    int t = threadIdx.x;
    thr_reduce(npart, thrs, fb, t);
    int xcd = blockIdx.x & 7;
    int i = blockIdx.x >> 3;                         // 0..383
    int type = i >> 7;                               // 0:W 1:H 2:D (128 each per XCD)
    int u = xcd * 128 + (i & 127);                   // contiguous unit range per XCD
    if (type == 0) {
        // ---- W-axis: 4 rings (2 lines x 2 parities); one wave per ring ----
        int blk = u;
#pragma unroll
        for (int it = 0; it < 4; ++it) {
            int f = it * 256 + t;
            int ll = f >> 9;
            int l = blk * 2 + ll;
            int c = (f >> 4) & 31, wq = f & 15;
            const float* lb = x + (size_t)(l >> 10) * CDHW_ + ((l >> 5) & 31) * HW_ + (l & 31) * W_;
            float4 v = *(const float4*)(lb + (size_t)c * DHW_ + wq * 4);
            int cq = c >> 2, cr = c & 3;
            const float* ve = (const float*)&v;
#pragma unroll
            for (int e = 0; e < 4; ++e) {
                int wv2 = wq * 4 + e;
                int p = wv2 >> 1, par = wv2 & 1;
                L[(ll * 2 + par) * 1024 + p * 32 + (((cq ^ WSLOT(p)) << 2) | cr)] = ve[e];
            }
        }
        __syncthreads();
        int ring = t >> 6, ln = t & 63;
        int pos = ln >> 1, hf = ln & 1;
        int ll = ring >> 1, par = ring & 1;
        int l = blk * 2 + ll;
        int b = l >> 10, d = (l >> 5) & 31, h = l & 31;
        double thr = thrs[b];
        float tlo = fb[b*4], thi = fb[b*4+1], tmf = fb[b*4+2];
        const float* Lr = L + ring * 1024;
        int qb = hf * 4;
        float4 col4[4], nv4[4];
#pragma unroll
        for (int k = 0; k < 4; ++k)
            col4[k] = *(const float4*)(Lr + pos * 32 + (((qb + k) ^ WSLOT(pos)) << 2));
        unsigned fmask = 0, bmask = 0;
#pragma unroll 2
        for (int s = 1; s <= 16; ++s) {              // forward (incl s=16 self-pair): dist + mask only
            int jf = (pos - s) & 31;
            LOAD_NB4W(Lr, jf);
            float dh = dist16v(col4, nv4);
            float ds = dh + xor1_f(dh);              // DPP lane^1 (= ln^1 half partner)
            fmask |= (unsigned)(ds < tmf) << s;
            bmask |= (unsigned)((ds >= tlo) & (ds <= thi)) << s;
        }
        if (__ballot(bmask != 0)) {                  // rare fp64 fixup, wave-uniform
#pragma unroll 1
            for (int s = 1; s <= 16; ++s) {
                if (__ballot((bmask >> s) & 1)) {
                    int jf = (pos - s) & 31;
                    LOAD_NB4W(Lr, jf);
                    double d64h = 0.0;
                    D64_ACC(col4, nv4, d64h);
                    double other = __shfl_xor(d64h, 1, 64);
                    unsigned cc = (unsigned)((d64h + other) < thr);
                    if ((bmask >> s) & 1) fmask = (fmask & ~(1u << s)) | (cc << s);
                }
            }
        }
        unsigned rmask = 0;                          // reverse rs=32-s via ballot
#pragma unroll 1
        for (int s = 1; s <= 15; ++s) {
            unsigned long long bal = __ballot((fmask >> s) & 1);
            int pl2 = (((pos + s) & 31) << 1) + hf;  // partner lane (same half, pos+s)
            rmask |= (unsigned)((bal >> pl2) & 1ull) << (32 - s);
        }
        float4 Mv4[4];
#pragma unroll
        for (int k = 0; k < 4; ++k) Mv4[k] = col4[k];
        unsigned allm = (fmask & 0x1FFFEu) | rmask;  // bits 1..16 fwd, 17..31 rev
        while (allm) {                               // lazy merge of SELECTED shifts only
            int s = __ffs(allm) - 1;
            allm &= allm - 1;
            int jj = (pos - s) & 31;
            LOAD_NB4W(Lr, jj);
            MERGE_MAX4(Mv4, nv4);
        }
        size_t ppt = (size_t)d * HW_ + h * W_ + 2 * pos + par;
        store_m16v(Mw + ((size_t)b * 65536 + ppt) * 32 + hf * 16, Mv4);
    } else if (type == 1) {
        hd_ring<W_, HW_>(x, Mh, thrs, fb, L, u, t);   // H pass (F = d)
    } else {
        hd_ring<HW_, W_>(x, Md, thrs, fb, L, u, t);   // D pass (F = h)
    }
}

// ---------------- conv (64->32) + fused BN partial stats; fp16 M, DPP stats reduce ----------------
__global__ __launch_bounds__(256, 4) void k_conv(const float* __restrict__ x,
                                                 const __half* __restrict__ Mw, const __half* __restrict__ Mh,
                                                 const __half* __restrict__ Md,
                                                 const float* __restrict__ w, const float* __restrict__ bias,
                                                 float* __restrict__ y, float2* __restrict__ spart) {
    int t = threadIdx.x;
    int blk = (blockIdx.x & 7) * 256 + (blockIdx.x >> 3);   // bijective XCD swizzle (2048 = 8*256)
    int b = blk >> 10;
    int p0 = (blk & 1023) * 64;
    int og = __builtin_amdgcn_readfirstlane(t >> 6);
    int pl = t & 63;
    const float* xb = x + (size_t)b * CDHW_ + p0 + pl;
    size_t moff = ((size_t)b * 65536 + p0 + pl) * 32;
    const int4* mw4 = (const int4*)(Mw + moff);
    const int4* mh4 = (const int4*)(Mh + moff);
    const int4* md4 = (const int4*)(Md + moff);
    const float* wo = w + og * 512;
    const float* bo = bias + og * 8;
    float a[8], xv[32];
#pragma unroll
    for (int k = 0; k < 8; ++k) a[k] = bo[k];
#pragma unroll
    for (int c = 0; c < 32; c += 4) {
        xv[c+0] = xb[(size_t)(c+0) * DHW_];
        xv[c+1] = xb[(size_t)(c+1) * DHW_];
        xv[c+2] = xb[(size_t)(c+2) * DHW_];
        xv[c+3] = xb[(size_t)(c+3) * DHW_];
#pragma unroll
        for (int k = 0; k < 8; ++k) {
            a[k] = fmaf(wo[k*64 + c+0], xv[c+0], a[k]);
            a[k] = fmaf(wo[k*64 + c+1], xv[c+1], a[k]);
            a[k] = fmaf(wo[k*64 + c+2], xv[c+2], a[k]);
            a[k] = fmaf(wo[k*64 + c+3], xv[c+3], a[k]);
        }
    }
#pragma unroll
    for (int i = 0; i < 4; ++i) {                    // 8 channels per int4 (fp16-packed)
        int4 aw = mw4[i], ah = mh4[i], ad = md4[i];
        const __half2* hw = (const __half2*)&aw;
        const __half2* hh = (const __half2*)&ah;
        const __half2* hd = (const __half2*)&ad;
#pragma unroll
        for (int j = 0; j < 4; ++j) {
            float2 fw = __half22float2(hw[j]);
            float2 fh = __half22float2(hh[j]);
            float2 fd = __half22float2(hd[j]);
            int c = i * 8 + j * 2;
            float z0 = fmaxf(fmaxf(fmaxf(fw.x, fh.x), fd.x) - xv[c+0], 0.f);
            float z1 = fmaxf(fmaxf(fmaxf(fw.y, fh.y), fd.y) - xv[c+1], 0.f);
#pragma unroll
            for (int k = 0; k < 8; ++k) {
                a[k] = fmaf(wo[k*64 + 32 + c+0], z0, a[k]);
                a[k] = fmaf(wo[k*64 + 32 + c+1], z1, a[k]);
            }
        }
    }
    float* yb = y + (size_t)b * CDHW_ + p0 + pl;
#pragma unroll
    for (int k = 0; k < 8; ++k) {
        yb[(size_t)(og * 8 + k) * DHW_] = a[k];
        float s = wave_sum63(a[k]);
        float q = wave_sum63(a[k] * a[k]);
        if (pl == STATS_LANE) spart[(og * 8 + k) * 2048 + blk] = make_float2(s, q);
    }
}

// ---------------- BN finalize + exact GELU, in-place; 1024 blocks x 4 float4/thread ----------------
__global__ __launch_bounds__(256) void k_out(float* __restrict__ y, const float2* __restrict__ spart,
                                             const float* __restrict__ gamma, const float* __restrict__ beta) {
    int t = threadIdx.x;
    int o = (blockIdx.x >> 4) & 31;                  // block-uniform channel (1024-f4 slab per block)
    __shared__ double ls[4], lq[4];
    __shared__ float bnp[2];
    {
        const float2* sp = spart + o * 2048;
        double s = 0.0, q = 0.0;
#pragma unroll
        for (int i = 0; i < 8; ++i) {
            float2 v = sp[i * 256 + t];
            s += (double)v.x; q += (double)v.y;
        }
        for (int off = 32; off; off >>= 1) {
            s += __shfl_down(s, off, 64);
            q += __shfl_down(q, off, 64);
        }
        if ((t & 63) == 0) { ls[t >> 6] = s; lq[t >> 6] = q; }
    }
    __syncthreads();
    if (t == 0) {
        double sm = (ls[0] + ls[1]) + (ls[2] + ls[3]);
        double sq = (lq[0] + lq[1]) + (lq[2] + lq[3]);
        double mu = sm / (double)BN_N_;
        double var = sq / (double)BN_N_ - mu * mu;
        bnp[0] = (float)mu;
        bnp[1] = (float)(1.0 / sqrt(var + 1e-5));
    }
    __syncthreads();
    float mu_f = bnp[0], rstd = bnp[1];
    float g = gamma[o], be = beta[o];
    float4* yv = (float4*)y;
#pragma unroll
    for (int i = 0; i < 4; ++i) {
        int idx = blockIdx.x * 1024 + i * 256 + t;   // over 1,048,576 float4
        float4 v = yv[idx];
        float* vv = (float*)&v;
#pragma unroll
        for (int j = 0; j < 4; ++j) {
            float tt = (vv[j] - mu_f) * rstd * g + be;
            vv[j] = 0.5f * tt * (1.f + erff(tt * 0.70710678118654752f));
        }
        yv[idx] = v;
    }
}

extern "C" void kernel_launch(void* const* d_in, const int* in_sizes, int n_in,
                              void* d_out, int out_size, void* d_ws, size_t ws_size,
                              hipStream_t stream) {
    const float* x     = (const float*)d_in[0];
    const float* w     = (const float*)d_in[1];
    const float* bias  = (const float*)d_in[2];
    const float* gamma = (const float*)d_in[3];
    const float* beta  = (const float*)d_in[4];
    float* out = (float*)d_out;
    __half* Mw = (__half*)d_ws;
    __half* Mh = (__half*)((char*)d_ws + MH_OFF);
    __half* Md = (__half*)((char*)d_ws + MD_OFF);
    double2* npart = (double2*)((char*)d_ws + RED_OFF + 256);
    float2*  spart = (float2*)((char*)d_ws + RED_OFF + 256 + 16384);

    k_norm  <<<64, 1024, 0, stream>>>(x, npart);
    k_passes<<<3072, 256, 0, stream>>>(x, npart, Mw, Mh, Md);
    k_conv  <<<2048, 256, 0, stream>>>(x, Mw, Mh, Md, w, bias, out, spart);
    k_out   <<<1024, 256, 0, stream>>>(out, spart, gamma, beta);
}